// Round 1
// baseline (6753.757 us; speedup 1.0000x reference)
//
#include <hip/hip_runtime.h>
#include <cstddef>
#include <cstdint>

// ---------------- problem constants ----------------
constexpr int B_    = 128;
constexpr int NQ_   = 32;
constexpr int NC_   = 40;
constexpr int NMAX_ = 40;
constexpr int EQ_   = 160;
constexpr int EC_   = 240;
constexpr int EMAX_ = 256;
constexpr int D_    = 128;
constexpr int TD_   = 16;
constexpr int NPROP_ = 5;
constexpr int ITERS_ = 20;
constexpr float TEMP_ = 0.1f;
constexpr int NF_   = 32;
constexpr int EF_   = 16;
constexpr int NPB_  = NQ_ + NC_;   // 72 nodes / batch
constexpr int EPB_  = EQ_ + EC_;   // 400 edges / batch
constexpr int NTOT_ = B_ * NPB_;   // 9216
constexpr int ETOT_ = B_ * EPB_;   // 51200
constexpr int TILE_ = 16;          // edges per block in the message kernel

static_assert(ETOT_ % TILE_ == 0, "tile divides edges");
static_assert(NTOT_ % 8 == 0, "update tile");

// ---------------- index building ----------------
__global__ __launch_bounds__(256) void k_build_idx(
    const int* __restrict__ fq, const int* __restrict__ tq,
    const int* __restrict__ fc, const int* __restrict__ tc,
    int* __restrict__ from_idx, int* __restrict__ to_idx)
{
  int i = blockIdx.x * blockDim.x + threadIdx.x;
  if (i >= ETOT_) return;
  int b = i / EPB_, j = i - b * EPB_;
  int f, t;
  if (j < EQ_) {
    f = fq[b*EQ_ + j] + b*NPB_;
    t = tq[b*EQ_ + j] + b*NPB_;
  } else {
    int jj = j - EQ_;
    f = fc[b*EC_ + jj] + b*NPB_ + NQ_;
    t = tc[b*EC_ + jj] + b*NPB_ + NQ_;
  }
  from_idx[i] = f;
  to_idx[i]   = t;
}

// ---------------- encoders ----------------
__global__ __launch_bounds__(128) void k_node_enc(
    const float* __restrict__ nf, const float* __restrict__ Wn,
    const float* __restrict__ bn, float* __restrict__ h)
{
  int n = blockIdx.x, j = threadIdx.x;
  __shared__ float xs[NF_];
  if (j < NF_) xs[j] = nf[(size_t)n*NF_ + j];
  __syncthreads();
  float a = bn[j];
  #pragma unroll
  for (int k = 0; k < NF_; ++k) a = fmaf(xs[k], Wn[(size_t)k*D_ + j], a);
  h[(size_t)n*D_ + j] = a;
}

__global__ __launch_bounds__(128) void k_edge_enc(
    const float* __restrict__ ef, const float* __restrict__ We,
    const float* __restrict__ be, float* __restrict__ e)
{
  int i = blockIdx.x, j = threadIdx.x;
  __shared__ float xs[EF_];
  if (j < EF_) xs[j] = ef[(size_t)i*EF_ + j];
  __syncthreads();
  float a = be[j];
  #pragma unroll
  for (int k = 0; k < EF_; ++k) a = fmaf(xs[k], We[(size_t)k*D_ + j], a);
  e[(size_t)i*D_ + j] = a;
}

// helper: acc[t] += sum_k x[t][xoff+k] * W[(wrow0+k)][j]  (kcount multiple of 4)
template<int TILE>
__device__ __forceinline__ void acc_slab(float (&acc)[TILE],
    const float* xsbase, int xstride, int xoff,
    const float* __restrict__ W, int wrow0, int j, int kcount)
{
  for (int k = 0; k < kcount; k += 4) {
    const float w0 = W[(size_t)(wrow0 + k + 0) * (2*D_) + j];
    const float w1 = W[(size_t)(wrow0 + k + 1) * (2*D_) + j];
    const float w2 = W[(size_t)(wrow0 + k + 2) * (2*D_) + j];
    const float w3 = W[(size_t)(wrow0 + k + 3) * (2*D_) + j];
    #pragma unroll
    for (int t = 0; t < TILE; ++t) {
      const float4 xv = *reinterpret_cast<const float4*>(&xsbase[t*xstride + xoff + k]);
      acc[t] = fmaf(xv.w, w3, fmaf(xv.z, w2, fmaf(xv.y, w1, fmaf(xv.x, w0, acc[t]))));
    }
  }
}

// ---------------- edge message MLPs (prop: atomic agg; final: -> teq/tec) ----------------
template<bool FINAL>
__global__ __launch_bounds__(256) void k_edge_msg(
    const float* __restrict__ h, const float* __restrict__ e,
    const int* __restrict__ from_idx, const int* __restrict__ to_idx,
    const float* __restrict__ Wm1, const float* __restrict__ bm1,
    const float* __restrict__ Wm2, const float* __restrict__ bm2,
    const float* __restrict__ Wr1, const float* __restrict__ br1,
    const float* __restrict__ Wr2, const float* __restrict__ br2,
    const float* __restrict__ We1, const float* __restrict__ be1,
    const float* __restrict__ We2, const float* __restrict__ be2,
    float* __restrict__ agg, float* __restrict__ teq, float* __restrict__ tec)
{
  __shared__ float xs[TILE_][3*D_];                       // [src | dst | e]
  __shared__ float hs[TILE_][2*D_];                       // hidden
  __shared__ float es[FINAL ? TILE_ : 1][FINAL ? (2*D_ + 1) : 1];
  __shared__ float l1s[FINAL ? TILE_ : 1][FINAL ? TD_ : 1];
  __shared__ int sfrom[TILE_], sto[TILE_];

  const int e0 = blockIdx.x * TILE_;
  const int tid = threadIdx.x;

  if (tid < TILE_) { sfrom[tid] = from_idx[e0 + tid]; sto[tid] = to_idx[e0 + tid]; }
  __syncthreads();

  for (int idx = tid; idx < TILE_*3*D_; idx += 256) {
    int t = idx / (3*D_), k = idx - t*(3*D_);
    float v;
    if (k < D_)            v = h[(size_t)sfrom[t]*D_ + k];
    else if (k < 2*D_)     v = h[(size_t)sto[t]*D_ + (k - D_)];
    else                   v = e[(size_t)(e0 + t)*D_ + (k - 2*D_)];
    xs[t][k] = v;
  }
  __syncthreads();

  float acc[TILE_];

  // ---- forward MLP ([src,dst,e] @ Wm1 -> relu -> @ Wm2) ----
  {
    const float b0 = bm1[tid];
    #pragma unroll
    for (int t = 0; t < TILE_; ++t) acc[t] = b0;
    acc_slab<TILE_>(acc, &xs[0][0], 3*D_, 0, Wm1, 0, tid, 3*D_);
    #pragma unroll
    for (int t = 0; t < TILE_; ++t) hs[t][tid] = fmaxf(acc[t], 0.f);
  }
  __syncthreads();
  {
    const float b0 = bm2[tid];
    #pragma unroll
    for (int t = 0; t < TILE_; ++t) acc[t] = b0;
    acc_slab<TILE_>(acc, &hs[0][0], 2*D_, 0, Wm2, 0, tid, 2*D_);
  }
  if constexpr (!FINAL) {
    #pragma unroll
    for (int t = 0; t < TILE_; ++t)
      atomicAdd(&agg[(size_t)sto[t]*(2*D_) + tid], acc[t]);
  } else {
    #pragma unroll
    for (int t = 0; t < TILE_; ++t) es[t][tid] = acc[t];
  }
  __syncthreads();   // all reads of hs done; safe to overwrite

  // ---- reverse MLP ([dst,src,e] @ Wr1 -> relu -> @ Wr2) ----
  {
    const float b0 = br1[tid];
    #pragma unroll
    for (int t = 0; t < TILE_; ++t) acc[t] = b0;
    acc_slab<TILE_>(acc, &xs[0][0], 3*D_, D_,   Wr1, 0,     tid, D_);  // dst part
    acc_slab<TILE_>(acc, &xs[0][0], 3*D_, 0,    Wr1, D_,    tid, D_);  // src part
    acc_slab<TILE_>(acc, &xs[0][0], 3*D_, 2*D_, Wr1, 2*D_,  tid, D_);  // e part
    #pragma unroll
    for (int t = 0; t < TILE_; ++t) hs[t][tid] = fmaxf(acc[t], 0.f);
  }
  __syncthreads();
  {
    const float b0 = br2[tid];
    #pragma unroll
    for (int t = 0; t < TILE_; ++t) acc[t] = b0;
    acc_slab<TILE_>(acc, &hs[0][0], 2*D_, 0, Wr2, 0, tid, 2*D_);
  }

  if constexpr (!FINAL) {
    #pragma unroll
    for (int t = 0; t < TILE_; ++t)
      atomicAdd(&agg[(size_t)sfrom[t]*(2*D_) + tid], acc[t]);
  } else {
    #pragma unroll
    for (int t = 0; t < TILE_; ++t) es[t][tid] += acc[t];   // emsg = m + mr
    __syncthreads();
    // small MLP: 256 -> 16 (relu) -> 16 ; 256 threads = 16 edges x 16 outs
    const int t = tid >> 4, jj = tid & 15;
    float a = be1[jj];
    for (int k = 0; k < 2*D_; ++k) a = fmaf(es[t][k], We1[(size_t)k*TD_ + jj], a);
    l1s[t][jj] = fmaxf(a, 0.f);
    __syncthreads();
    float a2 = be2[jj];
    #pragma unroll
    for (int k = 0; k < TD_; ++k) a2 = fmaf(l1s[t][k], We2[(size_t)k*TD_ + jj], a2);
    const int ei = e0 + t;
    const int bb = ei / EPB_, jl = ei - bb*EPB_;
    if (jl < EQ_) teq[((size_t)bb*EMAX_ + jl)*TD_ + jj] = a2;
    else          tec[((size_t)bb*EMAX_ + (jl - EQ_))*TD_ + jj] = a2;
  }
}

// ---------------- node update: h = [h, agg] @ Wu + bu ----------------
__global__ __launch_bounds__(256) void k_update(
    const float* __restrict__ h, const float* __restrict__ agg,
    const float* __restrict__ Wu, const float* __restrict__ bu,
    float* __restrict__ hn)
{
  const int n0 = blockIdx.x * 8;
  const int j = threadIdx.x & 127, half = threadIdx.x >> 7;
  __shared__ float xs[8][3*D_];
  for (int idx = threadIdx.x; idx < 8*3*D_; idx += 256) {
    int t = idx / (3*D_), k = idx - t*(3*D_);
    xs[t][k] = (k < D_) ? h[(size_t)(n0 + t)*D_ + k]
                        : agg[(size_t)(n0 + t)*(2*D_) + (k - D_)];
  }
  __syncthreads();
  float acc[4];
  const float b0 = bu[j];
  #pragma unroll
  for (int t = 0; t < 4; ++t) acc[t] = b0;
  for (int k = 0; k < 3*D_; k += 4) {
    const float w0 = Wu[(size_t)(k+0)*D_ + j];
    const float w1 = Wu[(size_t)(k+1)*D_ + j];
    const float w2 = Wu[(size_t)(k+2)*D_ + j];
    const float w3 = Wu[(size_t)(k+3)*D_ + j];
    #pragma unroll
    for (int t = 0; t < 4; ++t) {
      const float4 xv = *reinterpret_cast<const float4*>(&xs[half*4 + t][k]);
      acc[t] = fmaf(xv.w, w3, fmaf(xv.z, w2, fmaf(xv.y, w1, fmaf(xv.x, w0, acc[t]))));
    }
  }
  #pragma unroll
  for (int t = 0; t < 4; ++t)
    hn[(size_t)(n0 + half*4 + t)*D_ + j] = acc[t];
}

// ---------------- node target embeddings (128 -> 16 relu -> 16) ----------------
__global__ __launch_bounds__(128) void k_node_emb(
    const float* __restrict__ h,
    const float* __restrict__ Wq1, const float* __restrict__ bq1,
    const float* __restrict__ Wq2, const float* __restrict__ bq2,
    float* __restrict__ tq_emb, float* __restrict__ tc_emb)
{
  const int bid = blockIdx.x;           // b*80 + s
  const int b = bid / (2*NMAX_), s = bid - b*(2*NMAX_);
  const bool isQ = s < NMAX_;
  const int r = isQ ? s : s - NMAX_;
  float* outp = (isQ ? tq_emb : tc_emb) + ((size_t)b*NMAX_ + r)*TD_;
  const int tid = threadIdx.x;
  if (isQ && r >= NQ_) {                // padded q rows -> masked to 0
    if (tid < TD_) outp[tid] = 0.f;
    return;
  }
  const int node = b*NPB_ + (isQ ? r : NQ_ + r);
  __shared__ float xs[D_];
  __shared__ float l1[TD_];
  xs[tid] = h[(size_t)node*D_ + tid];
  __syncthreads();
  if (tid < TD_) {
    float a = bq1[tid];
    for (int k = 0; k < D_; ++k) a = fmaf(xs[k], Wq1[(size_t)k*TD_ + tid], a);
    l1[tid] = fmaxf(a, 0.f);
  }
  __syncthreads();
  if (tid < TD_) {
    float a = bq2[tid];
    #pragma unroll
    for (int k = 0; k < TD_; ++k) a = fmaf(l1[k], Wq2[(size_t)k*TD_ + tid], a);
    outp[tid] = a;
  }
}

// ---------------- sinkhorn over 40x40 node plans (fully in LDS) ----------------
__global__ __launch_bounds__(256) void k_sinkhorn_n(
    const float* __restrict__ tq_emb, const float* __restrict__ tc_emb,
    float* __restrict__ plan_n)
{
  const int b = blockIdx.x, tid = threadIdx.x;
  __shared__ float la[NMAX_][NMAX_];
  __shared__ float qe[NMAX_][TD_], ce[NMAX_][TD_];
  for (int idx = tid; idx < NMAX_*TD_; idx += 256) {
    qe[idx / TD_][idx % TD_] = tq_emb[(size_t)b*NMAX_*TD_ + idx];
    ce[idx / TD_][idx % TD_] = tc_emb[(size_t)b*NMAX_*TD_ + idx];
  }
  __syncthreads();
  for (int idx = tid; idx < NMAX_*NMAX_; idx += 256) {
    int q = idx / NMAX_, c = idx - q*NMAX_;
    float a = 0.f;
    #pragma unroll
    for (int d = 0; d < TD_; ++d) a = fmaf(qe[q][d], ce[c][d], a);
    la[q][c] = a / TEMP_;
  }
  __syncthreads();
  for (int it = 0; it < ITERS_; ++it) {
    if (tid < NMAX_) {                   // axis=2 (over cols) first
      float m = -INFINITY;
      for (int c = 0; c < NMAX_; ++c) m = fmaxf(m, la[tid][c]);
      float s = 0.f;
      for (int c = 0; c < NMAX_; ++c) s += expf(la[tid][c] - m);
      const float lse = m + logf(s);
      for (int c = 0; c < NMAX_; ++c) la[tid][c] -= lse;
    }
    __syncthreads();
    if (tid < NMAX_) {                   // axis=1 (over rows)
      float m = -INFINITY;
      for (int q = 0; q < NMAX_; ++q) m = fmaxf(m, la[q][tid]);
      float s = 0.f;
      for (int q = 0; q < NMAX_; ++q) s += expf(la[q][tid] - m);
      const float lse = m + logf(s);
      for (int q = 0; q < NMAX_; ++q) la[q][tid] -= lse;
    }
    __syncthreads();
  }
  for (int idx = tid; idx < NMAX_*NMAX_; idx += 256)
    plan_n[(size_t)b*NMAX_*NMAX_ + idx] = expf(la[idx / NMAX_][idx % NMAX_]);
}

// ---------------- edge scores: S_e = teq . tec / TEMP ----------------
__global__ __launch_bounds__(256) void k_escore(
    const float* __restrict__ teq, const float* __restrict__ tec,
    float* __restrict__ la)
{
  const int b = blockIdx.x, q0 = blockIdx.y * 16;
  const int c = threadIdx.x;
  __shared__ float qs[16][TD_];
  for (int idx = threadIdx.x; idx < 16*TD_; idx += 256)
    qs[idx / TD_][idx % TD_] = teq[((size_t)b*EMAX_ + q0)*TD_ + idx];
  const float4* tp = reinterpret_cast<const float4*>(&tec[((size_t)b*EMAX_ + c)*TD_]);
  const float4 r0 = tp[0], r1 = tp[1], r2 = tp[2], r3 = tp[3];
  __syncthreads();
  for (int qq = 0; qq < 16; ++qq) {
    const float* q = qs[qq];
    float a = q[0]*r0.x + q[1]*r0.y + q[2]*r0.z + q[3]*r0.w
            + q[4]*r1.x + q[5]*r1.y + q[6]*r1.z + q[7]*r1.w
            + q[8]*r2.x + q[9]*r2.y + q[10]*r2.z + q[11]*r2.w
            + q[12]*r3.x + q[13]*r3.y + q[14]*r3.z + q[15]*r3.w;
    la[((size_t)b*EMAX_ + q0 + qq)*EMAX_ + c] = a / TEMP_;
  }
}

// ---------------- sinkhorn over 256x256 edge plans (persistent per batch) ----------------
__global__ __launch_bounds__(256) void k_sinkhorn_e(float* __restrict__ la)
{
  const int b = blockIdx.x, tid = threadIdx.x;
  float* A = la + (size_t)b * EMAX_ * EMAX_;
  const int wv = tid >> 6, ln = tid & 63;
  for (int it = 0; it < ITERS_; ++it) {
    // axis=2: per row LSE; one wave per row
    for (int r = wv; r < EMAX_; r += 4) {
      float4 v = *reinterpret_cast<float4*>(&A[r*EMAX_ + ln*4]);
      float m = fmaxf(fmaxf(v.x, v.y), fmaxf(v.z, v.w));
      #pragma unroll
      for (int off = 32; off; off >>= 1) m = fmaxf(m, __shfl_xor(m, off));
      float s = expf(v.x - m) + expf(v.y - m) + expf(v.z - m) + expf(v.w - m);
      #pragma unroll
      for (int off = 32; off; off >>= 1) s += __shfl_xor(s, off);
      const float lse = m + logf(s);
      v.x -= lse; v.y -= lse; v.z -= lse; v.w -= lse;
      *reinterpret_cast<float4*>(&A[r*EMAX_ + ln*4]) = v;
    }
    __syncthreads();
    // axis=1: per column LSE; one thread per column (online max/sum)
    {
      const int c = tid;
      float m = -INFINITY, s = 0.f;
      #pragma unroll 4
      for (int r = 0; r < EMAX_; ++r) {
        const float v = A[r*EMAX_ + c];
        const float m2 = fmaxf(m, v);
        s = s * expf(m - m2) + expf(v - m2);
        m = m2;
      }
      const float lse = m + logf(s);
      #pragma unroll 4
      for (int r = 0; r < EMAX_; ++r) A[r*EMAX_ + c] -= lse;
    }
    __syncthreads();
  }
  for (int idx = tid; idx < EMAX_*EMAX_; idx += 256) A[idx] = expf(A[idx]);
}

// ---------------- final: consistency + hinge + linear head ----------------
__global__ __launch_bounds__(256) void k_final(
    const float* __restrict__ plan_e, const float* __restrict__ plan_n,
    const float* __restrict__ tq_emb, const float* __restrict__ tc_emb,
    const int* __restrict__ fq, const int* __restrict__ tq,
    const int* __restrict__ fc, const int* __restrict__ tc,
    const float* __restrict__ Wa, const float* __restrict__ ba,
    float* __restrict__ out)
{
  const int b = blockIdx.x, tid = threadIdx.x;
  __shared__ float pn[NMAX_*NMAX_];
  __shared__ float qe[NMAX_*TD_], ce[NMAX_*TD_];
  __shared__ int sfq[EQ_], stq[EQ_], sfc[EC_], stc[EC_];
  __shared__ float redc[4], redh[4];
  for (int idx = tid; idx < NMAX_*NMAX_; idx += 256)
    pn[idx] = plan_n[(size_t)b*NMAX_*NMAX_ + idx];
  for (int idx = tid; idx < NMAX_*TD_; idx += 256) {
    qe[idx] = tq_emb[(size_t)b*NMAX_*TD_ + idx];
    ce[idx] = tc_emb[(size_t)b*NMAX_*TD_ + idx];
  }
  for (int idx = tid; idx < EQ_; idx += 256) { sfq[idx] = fq[b*EQ_ + idx]; stq[idx] = tq[b*EQ_ + idx]; }
  for (int idx = tid; idx < EC_; idx += 256) { sfc[idx] = fc[b*EC_ + idx]; stc[idx] = tc[b*EC_ + idx]; }
  __syncthreads();

  float csum = 0.f;
  for (int idx = tid; idx < EQ_*EC_; idx += 256) {
    const int q = idx / EC_, c = idx - q*EC_;
    const float pe = plan_e[((size_t)b*EMAX_ + q)*EMAX_ + c];
    const float a0 = pn[sfq[q]*NMAX_ + sfc[c]] * pn[stq[q]*NMAX_ + stc[c]];
    const float a1 = pn[sfq[q]*NMAX_ + stc[c]] * pn[stq[q]*NMAX_ + sfc[c]];
    csum += pe * fmaxf(a0, a1);
  }
  float hsum = 0.f;
  for (int idx = tid; idx < NMAX_*TD_; idx += 256) {
    const int q = idx / TD_, d2 = idx - q*TD_;
    float a = 0.f;
    for (int c = 0; c < NMAX_; ++c) a = fmaf(pn[q*NMAX_ + c], ce[c*TD_ + d2], a);
    hsum += fmaxf(qe[idx] - a, 0.f);
  }
  #pragma unroll
  for (int off = 32; off; off >>= 1) {
    csum += __shfl_xor(csum, off);
    hsum += __shfl_xor(hsum, off);
  }
  const int wv = tid >> 6, ln = tid & 63;
  if (ln == 0) { redc[wv] = csum; redh[wv] = hsum; }
  __syncthreads();
  if (tid == 0) {
    const float C = redc[0] + redc[1] + redc[2] + redc[3];
    const float H = -(redh[0] + redh[1] + redh[2] + redh[3]);
    out[b] = H * Wa[0] + C * Wa[1] + ba[0];
  }
}

// ---------------- host launcher ----------------
extern "C" void kernel_launch(void* const* d_in, const int* in_sizes, int n_in,
                              void* d_out, int out_size, void* d_ws, size_t ws_size,
                              hipStream_t stream) {
  const float* node_features = (const float*)d_in[0];
  const float* edge_features = (const float*)d_in[1];
  const float* Wn  = (const float*)d_in[2];
  const float* bn  = (const float*)d_in[3];
  const float* We  = (const float*)d_in[4];
  const float* be  = (const float*)d_in[5];
  const float* Wm1 = (const float*)d_in[6];
  const float* bm1 = (const float*)d_in[7];
  const float* Wm2 = (const float*)d_in[8];
  const float* bm2 = (const float*)d_in[9];
  const float* Wr1 = (const float*)d_in[10];
  const float* br1 = (const float*)d_in[11];
  const float* Wr2 = (const float*)d_in[12];
  const float* br2 = (const float*)d_in[13];
  const float* Wu  = (const float*)d_in[14];
  const float* bu  = (const float*)d_in[15];
  const float* Wq1 = (const float*)d_in[16];
  const float* bq1 = (const float*)d_in[17];
  const float* Wq2 = (const float*)d_in[18];
  const float* bq2 = (const float*)d_in[19];
  const float* We1 = (const float*)d_in[20];
  const float* be1 = (const float*)d_in[21];
  const float* We2 = (const float*)d_in[22];
  const float* be2 = (const float*)d_in[23];
  const float* Wa  = (const float*)d_in[24];
  const float* ba  = (const float*)d_in[25];
  const int* fq = (const int*)d_in[26];
  const int* tq = (const int*)d_in[27];
  const int* fc = (const int*)d_in[28];
  const int* tc = (const int*)d_in[29];
  (void)in_sizes; (void)n_in; (void)out_size; (void)ws_size;

  char* ws = (char*)d_ws;
  size_t off = 0;
  auto take = [&](size_t bytes) -> void* {
    void* p = ws + off;
    off = (off + bytes + 255) & ~(size_t)255;
    return p;
  };
  int*   from_idx = (int*)  take((size_t)ETOT_*4);
  int*   to_idx   = (int*)  take((size_t)ETOT_*4);
  float* h0       = (float*)take((size_t)NTOT_*D_*4);
  float* h1       = (float*)take((size_t)NTOT_*D_*4);
  float* eenc     = (float*)take((size_t)ETOT_*D_*4);
  float* agg      = (float*)take((size_t)NTOT_*2*D_*4);
  float* tq_emb   = (float*)take((size_t)B_*NMAX_*TD_*4);
  float* tc_emb   = (float*)take((size_t)B_*NMAX_*TD_*4);
  float* plan_n   = (float*)take((size_t)B_*NMAX_*NMAX_*4);
  float* teq      = (float*)take((size_t)B_*EMAX_*TD_*4);
  float* tec      = (float*)take((size_t)B_*EMAX_*TD_*4);
  float* plan_e   = (float*)take((size_t)B_*EMAX_*EMAX_*4);

  k_build_idx<<<(ETOT_ + 255)/256, 256, 0, stream>>>(fq, tq, fc, tc, from_idx, to_idx);
  k_node_enc<<<NTOT_, D_, 0, stream>>>(node_features, Wn, bn, h0);
  k_edge_enc<<<ETOT_, D_, 0, stream>>>(edge_features, We, be, eenc);

  float* hc = h0;
  float* hn = h1;
  for (int p = 0; p < NPROP_; ++p) {
    hipMemsetAsync(agg, 0, (size_t)NTOT_*2*D_*4, stream);
    k_edge_msg<false><<<ETOT_/TILE_, 256, 0, stream>>>(
        hc, eenc, from_idx, to_idx,
        Wm1, bm1, Wm2, bm2, Wr1, br1, Wr2, br2,
        We1, be1, We2, be2, agg, nullptr, nullptr);
    k_update<<<NTOT_/8, 256, 0, stream>>>(hc, agg, Wu, bu, hn);
    float* t_ = hc; hc = hn; hn = t_;
  }

  k_node_emb<<<B_*2*NMAX_, D_, 0, stream>>>(hc, Wq1, bq1, Wq2, bq2, tq_emb, tc_emb);
  k_sinkhorn_n<<<B_, 256, 0, stream>>>(tq_emb, tc_emb, plan_n);

  hipMemsetAsync(teq, 0, (size_t)B_*EMAX_*TD_*4, stream);
  hipMemsetAsync(tec, 0, (size_t)B_*EMAX_*TD_*4, stream);
  k_edge_msg<true><<<ETOT_/TILE_, 256, 0, stream>>>(
      hc, eenc, from_idx, to_idx,
      Wm1, bm1, Wm2, bm2, Wr1, br1, Wr2, br2,
      We1, be1, We2, be2, nullptr, teq, tec);

  dim3 g_es(B_, EMAX_/16);
  k_escore<<<g_es, 256, 0, stream>>>(teq, tec, plan_e);
  k_sinkhorn_e<<<B_, 256, 0, stream>>>(plan_e);
  k_final<<<B_, 256, 0, stream>>>(plan_e, plan_n, tq_emb, tc_emb,
                                  fq, tq, fc, tc, Wa, ba, (float*)d_out);
}

// Round 4
// 1589.828 us; speedup vs baseline: 4.2481x; 4.2481x over previous
//
#include <hip/hip_runtime.h>
#include <cstddef>
#include <cstdint>

// ---------------- problem constants ----------------
constexpr int B_    = 128;
constexpr int NQ_   = 32;
constexpr int NC_   = 40;
constexpr int NMAX_ = 40;
constexpr int EQ_   = 160;
constexpr int EC_   = 240;
constexpr int EMAX_ = 256;
constexpr int D_    = 128;
constexpr int TD_   = 16;
constexpr int NPROP_ = 5;
constexpr int ITERS_ = 20;
constexpr float TEMP_ = 0.1f;
constexpr int NF_   = 32;
constexpr int EF_   = 16;
constexpr int NPB_  = NQ_ + NC_;   // 72 nodes / batch
constexpr int EPB_  = EQ_ + EC_;   // 400 edges / batch
constexpr int NTOT_ = B_ * NPB_;   // 9216
constexpr int ETOT_ = B_ * EPB_;   // 51200
constexpr int DEGCAP_ = 64;        // max per-node degree (random graphs: ~6 avg)

typedef _Float16 f16x8 __attribute__((ext_vector_type(8)));
typedef _Float16 f16x4 __attribute__((ext_vector_type(4)));
typedef float f32x4 __attribute__((ext_vector_type(4)));

__device__ __forceinline__ void gload16(const void* g, void* l) {
  __builtin_amdgcn_global_load_lds(
      (const __attribute__((address_space(1))) unsigned int*)g,
      (__attribute__((address_space(3))) unsigned int*)l, 16, 0, 0);
}

// ---------------- index building ----------------
__global__ __launch_bounds__(256) void k_build_idx(
    const int* __restrict__ fq, const int* __restrict__ tq,
    const int* __restrict__ fc, const int* __restrict__ tc,
    int* __restrict__ from_idx, int* __restrict__ to_idx)
{
  int i = blockIdx.x * blockDim.x + threadIdx.x;
  if (i >= ETOT_) return;
  int b = i / EPB_, j = i - b * EPB_;
  int f, t;
  if (j < EQ_) {
    f = fq[b*EQ_ + j] + b*NPB_;
    t = tq[b*EQ_ + j] + b*NPB_;
  } else {
    int jj = j - EQ_;
    f = fc[b*EC_ + jj] + b*NPB_ + NQ_;
    t = tc[b*EC_ + jj] + b*NPB_ + NQ_;
  }
  from_idx[i] = f;
  to_idx[i]   = t;
}

// ---------------- per-node edge lists (deterministic ascending order) ----------------
__global__ __launch_bounds__(256) void k_build_lists(
    const int* __restrict__ fq, const int* __restrict__ tq,
    const int* __restrict__ fc, const int* __restrict__ tc,
    int* __restrict__ in_cnt, int* __restrict__ in_list,
    int* __restrict__ out_cnt, int* __restrict__ out_list)
{
  const int b = blockIdx.x, tid = threadIdx.x;
  __shared__ short sf[EPB_], st[EPB_];
  for (int j = tid; j < EPB_; j += 256) {
    int f, t;
    if (j < EQ_) { f = fq[b*EQ_ + j];              t = tq[b*EQ_ + j]; }
    else         { f = fc[b*EC_ + (j-EQ_)] + NQ_;  t = tc[b*EC_ + (j-EQ_)] + NQ_; }
    sf[j] = (short)f; st[j] = (short)t;
  }
  __syncthreads();
  if (tid < NPB_) {
    const int g = b*NPB_ + tid;
    int ic = 0, oc = 0;
    for (int j = 0; j < EPB_; ++j) {
      if ((int)st[j] == tid && ic < DEGCAP_) in_list[g*DEGCAP_ + (ic++)] = j;
      if ((int)sf[j] == tid && oc < DEGCAP_) out_list[g*DEGCAP_ + (oc++)] = j;
    }
    in_cnt[g] = ic; out_cnt[g] = oc;
  }
}

// ---------------- weight prep: fp16, transposed [n][k]; Wr1 rows permuted ----------------
__global__ __launch_bounds__(256) void k_prep_w(
    const float* __restrict__ Wm1, const float* __restrict__ Wr1,
    const float* __restrict__ Wm2, const float* __restrict__ Wr2,
    const float* __restrict__ bm1, const float* __restrict__ br1,
    const float* __restrict__ bm2, const float* __restrict__ br2,
    _Float16* __restrict__ W1T, _Float16* __restrict__ W2T,
    float* __restrict__ bcat1, float* __restrict__ bcat2)
{
  int i = blockIdx.x * 256 + threadIdx.x;
  if (i < 512 * 384) {                    // W1T[n][k], n<256: Wm1, else permuted Wr1
    int n = i / 384, k = i - n * 384;
    float v;
    if (n < 256) v = Wm1[(size_t)k * 256 + n];
    else {
      int kk = (k < 128) ? k + 128 : (k < 256 ? k - 128 : k);
      v = Wr1[(size_t)kk * 256 + (n - 256)];
    }
    W1T[i] = (_Float16)v;
  }
  int j = i - 512 * 384;
  if (j >= 0 && j < 512 * 256) {          // W2T[n][k]
    int n = j / 256, k = j - n * 256;
    float v = (n < 256) ? Wm2[(size_t)k * 256 + n] : Wr2[(size_t)k * 256 + (n - 256)];
    W2T[j] = (_Float16)v;
  }
  if (i < 512) bcat1[i] = (i < 256) ? bm1[i] : br1[i - 256];
  if (i >= 512 && i < 1024) {
    int n = i - 512;
    bcat2[n] = (n < 256) ? bm2[n] : br2[n - 256];
  }
}

// ---------------- encoders ----------------
__global__ __launch_bounds__(128) void k_node_enc(
    const float* __restrict__ nf, const float* __restrict__ Wn,
    const float* __restrict__ bn, float* __restrict__ h)
{
  int n = blockIdx.x, j = threadIdx.x;
  __shared__ float xs[NF_];
  if (j < NF_) xs[j] = nf[(size_t)n*NF_ + j];
  __syncthreads();
  float a = bn[j];
  #pragma unroll
  for (int k = 0; k < NF_; ++k) a = fmaf(xs[k], Wn[(size_t)k*D_ + j], a);
  h[(size_t)n*D_ + j] = a;
}

__global__ __launch_bounds__(128) void k_edge_enc(
    const float* __restrict__ ef, const float* __restrict__ We,
    const float* __restrict__ be, _Float16* __restrict__ eb)
{
  int i = blockIdx.x, j = threadIdx.x;
  __shared__ float xs[EF_];
  if (j < EF_) xs[j] = ef[(size_t)i*EF_ + j];
  __syncthreads();
  float a = be[j];
  #pragma unroll
  for (int k = 0; k < EF_; ++k) a = fmaf(xs[k], We[(size_t)k*D_ + j], a);
  eb[(size_t)i*D_ + j] = (_Float16)a;
}

// ---------------- fp32 -> fp16 convert (4-wide) ----------------
__global__ __launch_bounds__(256) void k_cvt(
    const float* __restrict__ in, _Float16* __restrict__ out, int n4)
{
  int i = blockIdx.x * 256 + threadIdx.x;
  if (i >= n4) return;
  float4 v = reinterpret_cast<const float4*>(in)[i];
  f16x4 o;
  o[0] = (_Float16)v.x; o[1] = (_Float16)v.y; o[2] = (_Float16)v.z; o[3] = (_Float16)v.w;
  *reinterpret_cast<f16x4*>(&out[(size_t)i*4]) = o;
}

// ---------------- GEMM1: X[51200x384] @ W1T -> relu -> hidden fp16 [51200x512] ----------------
// X row e = [h[from[e]] | h[to[e]] | eenc[e]] gathered on the fly (fp16).
__global__ __launch_bounds__(256) void k_gemm1(
    const _Float16* __restrict__ hb, const _Float16* __restrict__ eb,
    const int* __restrict__ from_idx, const int* __restrict__ to_idx,
    const _Float16* __restrict__ W1T, const float* __restrict__ bcat1,
    _Float16* __restrict__ hidden)
{
  const int m0 = blockIdx.x * 128;
  const int n0 = blockIdx.y * 128;
  __shared__ _Float16 As[128 * 64];   // [row][chunk] 16B-chunk XOR swizzled
  __shared__ _Float16 Bs[128 * 64];   // W1T rows n (128) x k (64), swizzled

  const int tid  = threadIdx.x;
  const int srow = tid >> 3, slot = tid & 7;

  int fi[4], ti[4];
  #pragma unroll
  for (int i = 0; i < 4; ++i) {
    int r = m0 + srow + 32*i;
    fi[i] = from_idx[r];
    ti[i] = to_idx[r];
  }

  const int wave = tid >> 6, lane = tid & 63;
  const int wm = wave >> 1, wn = wave & 1;
  const int lr = lane & 15, lk = lane >> 4;

  f32x4 acc[4][4] = {};

  for (int kt = 0; kt < 6; ++kt) {
    __syncthreads();
    // stage A (gather): rows srow+32i, 16B chunk slot; source holds logical chunk slot^(r&7)
    #pragma unroll
    for (int i = 0; i < 4; ++i) {
      const int r = srow + 32*i;
      const int sslot = slot ^ (r & 7);
      const _Float16* src;
      if (kt < 2)      src = hb + (size_t)fi[i]*128 + kt*64 + sslot*8;
      else if (kt < 4) src = hb + (size_t)ti[i]*128 + (kt-2)*64 + sslot*8;
      else             src = eb + (size_t)(m0 + r)*128 + (kt-4)*64 + sslot*8;
      gload16(src, &As[r*64 + slot*8]);
    }
    // stage B
    #pragma unroll
    for (int i = 0; i < 4; ++i) {
      const int n = srow + 32*i;
      const int sslot = slot ^ (n & 7);
      gload16(W1T + (size_t)(n0 + n)*384 + kt*64 + sslot*8, &Bs[n*64 + slot*8]);
    }
    __syncthreads();
    #pragma unroll
    for (int ks = 0; ks < 2; ++ks) {
      f16x8 af[4], bfr[4];
      #pragma unroll
      for (int mf = 0; mf < 4; ++mf) {
        const int r = wm*64 + mf*16 + lr;
        const int ch = (ks*4 + lk) ^ (r & 7);
        af[mf] = *(const f16x8*)&As[r*64 + ch*8];
      }
      #pragma unroll
      for (int nf = 0; nf < 4; ++nf) {
        const int n = wn*64 + nf*16 + lr;
        const int ch = (ks*4 + lk) ^ (n & 7);
        bfr[nf] = *(const f16x8*)&Bs[n*64 + ch*8];
      }
      #pragma unroll
      for (int mf = 0; mf < 4; ++mf)
        #pragma unroll
        for (int nf = 0; nf < 4; ++nf)
          acc[mf][nf] = __builtin_amdgcn_mfma_f32_16x16x32_f16(af[mf], bfr[nf], acc[mf][nf], 0, 0, 0);
    }
  }

  // epilogue: relu(acc + bias) -> fp16
  #pragma unroll
  for (int nf = 0; nf < 4; ++nf) {
    const int c = n0 + wn*64 + nf*16 + lr;
    const float bias = bcat1[c];
    #pragma unroll
    for (int mf = 0; mf < 4; ++mf) {
      #pragma unroll
      for (int v = 0; v < 4; ++v) {
        const int r = m0 + wm*64 + mf*16 + lk*4 + v;
        hidden[(size_t)r*512 + c] = (_Float16)fmaxf(acc[mf][nf][v] + bias, 0.f);
      }
    }
  }
}

// ---------------- GEMM2: hidden @ W2T (+bias) -> emsg[e][0..511] = [m | mr] ----------------
// Plain stores; aggregation is a separate deterministic gather (k_agg).
__global__ __launch_bounds__(256) void k_gemm2(
    const _Float16* __restrict__ hidden,
    const _Float16* __restrict__ W2T, const float* __restrict__ bcat2,
    _Float16* __restrict__ emsg)
{
  const int m0 = blockIdx.x * 128;
  const int by = blockIdx.y;
  const int n0 = by * 128;                  // within [0,512)
  const int aoff = (by < 2) ? 0 : 256;
  __shared__ _Float16 As[128 * 64];
  __shared__ _Float16 Bs[128 * 64];

  const int tid  = threadIdx.x;
  const int srow = tid >> 3, slot = tid & 7;
  const int wave = tid >> 6, lane = tid & 63;
  const int wm = wave >> 1, wn = wave & 1;
  const int lr = lane & 15, lk = lane >> 4;

  f32x4 acc[4][4] = {};

  for (int kt = 0; kt < 4; ++kt) {
    __syncthreads();
    #pragma unroll
    for (int i = 0; i < 4; ++i) {
      const int r = srow + 32*i;
      const int sslot = slot ^ (r & 7);
      gload16(hidden + (size_t)(m0 + r)*512 + aoff + kt*64 + sslot*8, &As[r*64 + slot*8]);
    }
    #pragma unroll
    for (int i = 0; i < 4; ++i) {
      const int n = srow + 32*i;
      const int sslot = slot ^ (n & 7);
      gload16(W2T + (size_t)(n0 + n)*256 + kt*64 + sslot*8, &Bs[n*64 + slot*8]);
    }
    __syncthreads();
    #pragma unroll
    for (int ks = 0; ks < 2; ++ks) {
      f16x8 af[4], bfr[4];
      #pragma unroll
      for (int mf = 0; mf < 4; ++mf) {
        const int r = wm*64 + mf*16 + lr;
        const int ch = (ks*4 + lk) ^ (r & 7);
        af[mf] = *(const f16x8*)&As[r*64 + ch*8];
      }
      #pragma unroll
      for (int nf = 0; nf < 4; ++nf) {
        const int n = wn*64 + nf*16 + lr;
        const int ch = (ks*4 + lk) ^ (n & 7);
        bfr[nf] = *(const f16x8*)&Bs[n*64 + ch*8];
      }
      #pragma unroll
      for (int mf = 0; mf < 4; ++mf)
        #pragma unroll
        for (int nf = 0; nf < 4; ++nf)
          acc[mf][nf] = __builtin_amdgcn_mfma_f32_16x16x32_f16(af[mf], bfr[nf], acc[mf][nf], 0, 0, 0);
    }
  }

  // epilogue: add bias, plain store
  #pragma unroll
  for (int nf = 0; nf < 4; ++nf) {
    const int c = n0 + wn*64 + nf*16 + lr;    // col within [0,512)
    const float bias = bcat2[c];
    #pragma unroll
    for (int mf = 0; mf < 4; ++mf) {
      #pragma unroll
      for (int v = 0; v < 4; ++v) {
        const int r = m0 + wm*64 + mf*16 + lk*4 + v;
        emsg[(size_t)r*512 + c] = (_Float16)(acc[mf][nf][v] + bias);
      }
    }
  }
}

// ---------------- deterministic segment-sum gather ----------------
// agg[n][c] = sum_{e: to[e]==n} m[e][c] + sum_{e: from[e]==n} mr[e][c]
__global__ __launch_bounds__(256) void k_agg(
    const _Float16* __restrict__ emsg,
    const int* __restrict__ in_cnt, const int* __restrict__ in_list,
    const int* __restrict__ out_cnt, const int* __restrict__ out_list,
    float* __restrict__ agg)
{
  const int g = blockIdx.x;            // global node id
  const int b = g / NPB_;
  const int c = threadIdx.x;           // 0..255
  const int ebase = b * EPB_;
  const int ic = in_cnt[g], oc = out_cnt[g];
  float a = 0.f;
  for (int i = 0; i < ic; ++i) {
    const int e = ebase + in_list[g*DEGCAP_ + i];
    a += (float)emsg[(size_t)e*512 + c];
  }
  for (int i = 0; i < oc; ++i) {
    const int e = ebase + out_list[g*DEGCAP_ + i];
    a += (float)emsg[(size_t)e*512 + 256 + c];
  }
  agg[(size_t)g*256 + c] = a;
}

// ---------------- final edge embed MLP: (m+mr)[256] -> 16 relu -> 16 ----------------
__global__ __launch_bounds__(256) void k_edge_emb(
    const _Float16* __restrict__ emsg,
    const float* __restrict__ We1, const float* __restrict__ be1,
    const float* __restrict__ We2, const float* __restrict__ be2,
    float* __restrict__ teq, float* __restrict__ tec)
{
  const int e0 = blockIdx.x * 16;
  const int tid = threadIdx.x;
  __shared__ float es[16][257];
  __shared__ float l1s[16][TD_];
  for (int idx = tid; idx < 16*256; idx += 256) {
    const int t = idx >> 8, k = idx & 255;
    const size_t base = (size_t)(e0 + t)*512;
    es[t][k] = (float)emsg[base + k] + (float)emsg[base + 256 + k];
  }
  __syncthreads();
  const int t = tid >> 4, jj = tid & 15;
  float a = be1[jj];
  for (int k = 0; k < 256; ++k) a = fmaf(es[t][k], We1[(size_t)k*TD_ + jj], a);
  l1s[t][jj] = fmaxf(a, 0.f);
  __syncthreads();
  float a2 = be2[jj];
  #pragma unroll
  for (int k = 0; k < TD_; ++k) a2 = fmaf(l1s[t][k], We2[(size_t)k*TD_ + jj], a2);
  const int ei = e0 + t;
  const int bb = ei / EPB_, jl = ei - bb*EPB_;
  if (jl < EQ_) teq[((size_t)bb*EMAX_ + jl)*TD_ + jj] = a2;
  else          tec[((size_t)bb*EMAX_ + (jl - EQ_))*TD_ + jj] = a2;
}

// ---------------- node update: h = [h, agg] @ Wu + bu ----------------
__global__ __launch_bounds__(256) void k_update(
    const float* __restrict__ h, const float* __restrict__ agg,
    const float* __restrict__ Wu, const float* __restrict__ bu,
    float* __restrict__ hn)
{
  const int n0 = blockIdx.x * 8;
  const int j = threadIdx.x & 127, half = threadIdx.x >> 7;
  __shared__ float xs[8][3*D_];
  for (int idx = threadIdx.x; idx < 8*3*D_; idx += 256) {
    int t = idx / (3*D_), k = idx - t*(3*D_);
    xs[t][k] = (k < D_) ? h[(size_t)(n0 + t)*D_ + k]
                        : agg[(size_t)(n0 + t)*(2*D_) + (k - D_)];
  }
  __syncthreads();
  float acc[4];
  const float b0 = bu[j];
  #pragma unroll
  for (int t = 0; t < 4; ++t) acc[t] = b0;
  for (int k = 0; k < 3*D_; k += 4) {
    const float w0 = Wu[(size_t)(k+0)*D_ + j];
    const float w1 = Wu[(size_t)(k+1)*D_ + j];
    const float w2 = Wu[(size_t)(k+2)*D_ + j];
    const float w3 = Wu[(size_t)(k+3)*D_ + j];
    #pragma unroll
    for (int t = 0; t < 4; ++t) {
      const float4 xv = *reinterpret_cast<const float4*>(&xs[half*4 + t][k]);
      acc[t] = fmaf(xv.w, w3, fmaf(xv.z, w2, fmaf(xv.y, w1, fmaf(xv.x, w0, acc[t]))));
    }
  }
  #pragma unroll
  for (int t = 0; t < 4; ++t)
    hn[(size_t)(n0 + half*4 + t)*D_ + j] = acc[t];
}

// ---------------- node target embeddings (128 -> 16 relu -> 16) ----------------
__global__ __launch_bounds__(128) void k_node_emb(
    const float* __restrict__ h,
    const float* __restrict__ Wq1, const float* __restrict__ bq1,
    const float* __restrict__ Wq2, const float* __restrict__ bq2,
    float* __restrict__ tq_emb, float* __restrict__ tc_emb)
{
  const int bid = blockIdx.x;
  const int b = bid / (2*NMAX_), s = bid - b*(2*NMAX_);
  const bool isQ = s < NMAX_;
  const int r = isQ ? s : s - NMAX_;
  float* outp = (isQ ? tq_emb : tc_emb) + ((size_t)b*NMAX_ + r)*TD_;
  const int tid = threadIdx.x;
  if (isQ && r >= NQ_) {
    if (tid < TD_) outp[tid] = 0.f;
    return;
  }
  const int node = b*NPB_ + (isQ ? r : NQ_ + r);
  __shared__ float xs[D_];
  __shared__ float l1[TD_];
  xs[tid] = h[(size_t)node*D_ + tid];
  __syncthreads();
  if (tid < TD_) {
    float a = bq1[tid];
    for (int k = 0; k < D_; ++k) a = fmaf(xs[k], Wq1[(size_t)k*TD_ + tid], a);
    l1[tid] = fmaxf(a, 0.f);
  }
  __syncthreads();
  if (tid < TD_) {
    float a = bq2[tid];
    #pragma unroll
    for (int k = 0; k < TD_; ++k) a = fmaf(l1[k], Wq2[(size_t)k*TD_ + tid], a);
    outp[tid] = a;
  }
}

// ---------------- sinkhorn over 40x40 node plans (LDS) ----------------
__global__ __launch_bounds__(256) void k_sinkhorn_n(
    const float* __restrict__ tq_emb, const float* __restrict__ tc_emb,
    float* __restrict__ plan_n)
{
  const int b = blockIdx.x, tid = threadIdx.x;
  __shared__ float la[NMAX_][NMAX_];
  __shared__ float qe[NMAX_][TD_], ce[NMAX_][TD_];
  for (int idx = tid; idx < NMAX_*TD_; idx += 256) {
    qe[idx / TD_][idx % TD_] = tq_emb[(size_t)b*NMAX_*TD_ + idx];
    ce[idx / TD_][idx % TD_] = tc_emb[(size_t)b*NMAX_*TD_ + idx];
  }
  __syncthreads();
  for (int idx = tid; idx < NMAX_*NMAX_; idx += 256) {
    int q = idx / NMAX_, c = idx - q*NMAX_;
    float a = 0.f;
    #pragma unroll
    for (int d = 0; d < TD_; ++d) a = fmaf(qe[q][d], ce[c][d], a);
    la[q][c] = a / TEMP_;
  }
  __syncthreads();
  for (int it = 0; it < ITERS_; ++it) {
    if (tid < NMAX_) {
      float m = -INFINITY;
      for (int c = 0; c < NMAX_; ++c) m = fmaxf(m, la[tid][c]);
      float s = 0.f;
      for (int c = 0; c < NMAX_; ++c) s += __expf(la[tid][c] - m);
      const float lse = m + __logf(s);
      for (int c = 0; c < NMAX_; ++c) la[tid][c] -= lse;
    }
    __syncthreads();
    if (tid < NMAX_) {
      float m = -INFINITY;
      for (int q = 0; q < NMAX_; ++q) m = fmaxf(m, la[q][tid]);
      float s = 0.f;
      for (int q = 0; q < NMAX_; ++q) s += __expf(la[q][tid] - m);
      const float lse = m + __logf(s);
      for (int q = 0; q < NMAX_; ++q) la[q][tid] -= lse;
    }
    __syncthreads();
  }
  for (int idx = tid; idx < NMAX_*NMAX_; idx += 256)
    plan_n[(size_t)b*NMAX_*NMAX_ + idx] = __expf(la[idx / NMAX_][idx % NMAX_]);
}

// ---------------- edge scores: S_e = teq . tec / TEMP ----------------
__global__ __launch_bounds__(256) void k_escore(
    const float* __restrict__ teq, const float* __restrict__ tec,
    float* __restrict__ la)
{
  const int b = blockIdx.x, q0 = blockIdx.y * 16;
  const int c = threadIdx.x;
  __shared__ float qs[16][TD_];
  for (int idx = threadIdx.x; idx < 16*TD_; idx += 256)
    qs[idx / TD_][idx % TD_] = teq[((size_t)b*EMAX_ + q0)*TD_ + idx];
  const float4* tp = reinterpret_cast<const float4*>(&tec[((size_t)b*EMAX_ + c)*TD_]);
  const float4 r0 = tp[0], r1 = tp[1], r2 = tp[2], r3 = tp[3];
  __syncthreads();
  for (int qq = 0; qq < 16; ++qq) {
    const float* q = qs[qq];
    float a = q[0]*r0.x + q[1]*r0.y + q[2]*r0.z + q[3]*r0.w
            + q[4]*r1.x + q[5]*r1.y + q[6]*r1.z + q[7]*r1.w
            + q[8]*r2.x + q[9]*r2.y + q[10]*r2.z + q[11]*r2.w
            + q[12]*r3.x + q[13]*r3.y + q[14]*r3.z + q[15]*r3.w;
    la[((size_t)b*EMAX_ + q0 + qq)*EMAX_ + c] = a / TEMP_;
  }
}

// ---------------- sinkhorn over 256x256 edge plans ----------------
// Fused: col-LSE of iter i is applied lazily during the row pass of iter i+1.
__global__ __launch_bounds__(512) void k_sinkhorn_e(float* __restrict__ la)
{
  const int b = blockIdx.x, tid = threadIdx.x;
  float* A = la + (size_t)b * EMAX_ * EMAX_;
  __shared__ float lsec[EMAX_];
  __shared__ float pm[2][EMAX_];
  __shared__ float ps[2][EMAX_];
  const int wv = tid >> 6, ln = tid & 63;
  const int c = tid & 255, hh = tid >> 8;
  if (tid < EMAX_) lsec[tid] = 0.f;
  __syncthreads();

  for (int it = 0; it < ITERS_; ++it) {
    // row pass (axis=2): v -= pending col lse; row logsumexp; v -= lse
    const float4 lc = *reinterpret_cast<const float4*>(&lsec[ln*4]);
    for (int r = wv; r < EMAX_; r += 8) {
      float4 v = *reinterpret_cast<float4*>(&A[r*EMAX_ + ln*4]);
      v.x -= lc.x; v.y -= lc.y; v.z -= lc.z; v.w -= lc.w;
      float m = fmaxf(fmaxf(v.x, v.y), fmaxf(v.z, v.w));
      #pragma unroll
      for (int off = 32; off; off >>= 1) m = fmaxf(m, __shfl_xor(m, off));
      float s = __expf(v.x - m) + __expf(v.y - m) + __expf(v.z - m) + __expf(v.w - m);
      #pragma unroll
      for (int off = 32; off; off >>= 1) s += __shfl_xor(s, off);
      const float lse = m + __logf(s);
      v.x -= lse; v.y -= lse; v.z -= lse; v.w -= lse;
      *reinterpret_cast<float4*>(&A[r*EMAX_ + ln*4]) = v;
    }
    __syncthreads();
    // col pass (axis=1): two sweeps, 4-way ILP, halves combined via LDS
    {
      const float* Ac = A + c;
      const int r0 = hh * 128;
      float m0 = -INFINITY, m1 = -INFINITY, m2 = -INFINITY, m3 = -INFINITY;
      for (int r = r0; r < r0 + 128; r += 4) {
        m0 = fmaxf(m0, Ac[(r+0)*EMAX_]);
        m1 = fmaxf(m1, Ac[(r+1)*EMAX_]);
        m2 = fmaxf(m2, Ac[(r+2)*EMAX_]);
        m3 = fmaxf(m3, Ac[(r+3)*EMAX_]);
      }
      pm[hh][c] = fmaxf(fmaxf(m0, m1), fmaxf(m2, m3));
    }
    __syncthreads();
    const float cm = fmaxf(pm[0][c], pm[1][c]);
    {
      const float* Ac = A + c;
      const int r0 = hh * 128;
      float s0 = 0.f, s1 = 0.f, s2 = 0.f, s3 = 0.f;
      for (int r = r0; r < r0 + 128; r += 4) {
        s0 += __expf(Ac[(r+0)*EMAX_] - cm);
        s1 += __expf(Ac[(r+1)*EMAX_] - cm);
        s2 += __expf(Ac[(r+2)*EMAX_] - cm);
        s3 += __expf(Ac[(r+3)*EMAX_] - cm);
      }
      ps[hh][c] = s0 + s1 + s2 + s3;
    }
    __syncthreads();
    if (hh == 0) lsec[c] = cm + __logf(ps[0][c] + ps[1][c]);
    __syncthreads();
  }
  // apply pending col lse and exponentiate
  for (int i = tid; i < EMAX_*EMAX_; i += 512)
    A[i] = __expf(A[i] - lsec[i & 255]);
}

// ---------------- final: consistency + hinge + linear head ----------------
__global__ __launch_bounds__(256) void k_final(
    const float* __restrict__ plan_e, const float* __restrict__ plan_n,
    const float* __restrict__ tq_emb, const float* __restrict__ tc_emb,
    const int* __restrict__ fq, const int* __restrict__ tq,
    const int* __restrict__ fc, const int* __restrict__ tc,
    const float* __restrict__ Wa, const float* __restrict__ ba,
    float* __restrict__ out)
{
  const int b = blockIdx.x, tid = threadIdx.x;
  __shared__ float pn[NMAX_*NMAX_];
  __shared__ float qe[NMAX_*TD_], ce[NMAX_*TD_];
  __shared__ int sfq[EQ_], stq[EQ_], sfc[EC_], stc[EC_];
  __shared__ float redc[4], redh[4];
  for (int idx = tid; idx < NMAX_*NMAX_; idx += 256)
    pn[idx] = plan_n[(size_t)b*NMAX_*NMAX_ + idx];
  for (int idx = tid; idx < NMAX_*TD_; idx += 256) {
    qe[idx] = tq_emb[(size_t)b*NMAX_*TD_ + idx];
    ce[idx] = tc_emb[(size_t)b*NMAX_*TD_ + idx];
  }
  for (int idx = tid; idx < EQ_; idx += 256) { sfq[idx] = fq[b*EQ_ + idx]; stq[idx] = tq[b*EQ_ + idx]; }
  for (int idx = tid; idx < EC_; idx += 256) { sfc[idx] = fc[b*EC_ + idx]; stc[idx] = tc[b*EC_ + idx]; }
  __syncthreads();

  float csum = 0.f;
  for (int idx = tid; idx < EQ_*EC_; idx += 256) {
    const int q = idx / EC_, c = idx - q*EC_;
    const float pe = plan_e[((size_t)b*EMAX_ + q)*EMAX_ + c];
    const float a0 = pn[sfq[q]*NMAX_ + sfc[c]] * pn[stq[q]*NMAX_ + stc[c]];
    const float a1 = pn[sfq[q]*NMAX_ + stc[c]] * pn[stq[q]*NMAX_ + sfc[c]];
    csum += pe * fmaxf(a0, a1);
  }
  float hsum = 0.f;
  for (int idx = tid; idx < NMAX_*TD_; idx += 256) {
    const int q = idx / TD_, d2 = idx - q*TD_;
    float a = 0.f;
    for (int c = 0; c < NMAX_; ++c) a = fmaf(pn[q*NMAX_ + c], ce[c*TD_ + d2], a);
    hsum += fmaxf(qe[idx] - a, 0.f);
  }
  #pragma unroll
  for (int off = 32; off; off >>= 1) {
    csum += __shfl_xor(csum, off);
    hsum += __shfl_xor(hsum, off);
  }
  const int wv = tid >> 6, ln = tid & 63;
  if (ln == 0) { redc[wv] = csum; redh[wv] = hsum; }
  __syncthreads();
  if (tid == 0) {
    const float C = redc[0] + redc[1] + redc[2] + redc[3];
    const float H = -(redh[0] + redh[1] + redh[2] + redh[3]);
    out[b] = H * Wa[0] + C * Wa[1] + ba[0];
  }
}

// ---------------- host launcher ----------------
extern "C" void kernel_launch(void* const* d_in, const int* in_sizes, int n_in,
                              void* d_out, int out_size, void* d_ws, size_t ws_size,
                              hipStream_t stream) {
  const float* node_features = (const float*)d_in[0];
  const float* edge_features = (const float*)d_in[1];
  const float* Wn  = (const float*)d_in[2];
  const float* bn  = (const float*)d_in[3];
  const float* We  = (const float*)d_in[4];
  const float* be  = (const float*)d_in[5];
  const float* Wm1 = (const float*)d_in[6];
  const float* bm1 = (const float*)d_in[7];
  const float* Wm2 = (const float*)d_in[8];
  const float* bm2 = (const float*)d_in[9];
  const float* Wr1 = (const float*)d_in[10];
  const float* br1 = (const float*)d_in[11];
  const float* Wr2 = (const float*)d_in[12];
  const float* br2 = (const float*)d_in[13];
  const float* Wu  = (const float*)d_in[14];
  const float* bu  = (const float*)d_in[15];
  const float* Wq1 = (const float*)d_in[16];
  const float* bq1 = (const float*)d_in[17];
  const float* Wq2 = (const float*)d_in[18];
  const float* bq2 = (const float*)d_in[19];
  const float* We1 = (const float*)d_in[20];
  const float* be1 = (const float*)d_in[21];
  const float* We2 = (const float*)d_in[22];
  const float* be2 = (const float*)d_in[23];
  const float* Wa  = (const float*)d_in[24];
  const float* ba  = (const float*)d_in[25];
  const int* fq = (const int*)d_in[26];
  const int* tq = (const int*)d_in[27];
  const int* fc = (const int*)d_in[28];
  const int* tc = (const int*)d_in[29];
  (void)in_sizes; (void)n_in; (void)out_size; (void)ws_size;

  char* ws = (char*)d_ws;
  size_t off = 0;
  auto take = [&](size_t bytes) -> void* {
    void* p = ws + off;
    off = (off + bytes + 255) & ~(size_t)255;
    return p;
  };
  int*   from_idx = (int*)  take((size_t)ETOT_*4);
  int*   to_idx   = (int*)  take((size_t)ETOT_*4);
  int*   in_cnt   = (int*)  take((size_t)NTOT_*4);
  int*   out_cnt  = (int*)  take((size_t)NTOT_*4);
  int*   in_list  = (int*)  take((size_t)NTOT_*DEGCAP_*4);
  int*   out_list = (int*)  take((size_t)NTOT_*DEGCAP_*4);
  float* h0       = (float*)take((size_t)NTOT_*D_*4);
  float* h1       = (float*)take((size_t)NTOT_*D_*4);
  _Float16* hb    = (_Float16*)take((size_t)NTOT_*D_*2);
  _Float16* eb    = (_Float16*)take((size_t)ETOT_*D_*2);
  float* agg      = (float*)take((size_t)NTOT_*2*D_*4);
  _Float16* hidden = (_Float16*)take((size_t)ETOT_*512*2);
  _Float16* emsg  = (_Float16*)take((size_t)ETOT_*512*2);
  float* tq_emb   = (float*)take((size_t)B_*NMAX_*TD_*4);
  float* tc_emb   = (float*)take((size_t)B_*NMAX_*TD_*4);
  float* plan_n   = (float*)take((size_t)B_*NMAX_*NMAX_*4);
  float* teq      = (float*)take((size_t)B_*EMAX_*TD_*4);
  float* tec      = (float*)take((size_t)B_*EMAX_*TD_*4);
  float* plan_e   = (float*)take((size_t)B_*EMAX_*EMAX_*4);
  _Float16* W1T   = (_Float16*)take((size_t)512*384*2);
  _Float16* W2T   = (_Float16*)take((size_t)512*256*2);
  float* bcat1    = (float*)take(512*4);
  float* bcat2    = (float*)take(512*4);

  k_build_idx<<<(ETOT_ + 255)/256, 256, 0, stream>>>(fq, tq, fc, tc, from_idx, to_idx);
  k_build_lists<<<B_, 256, 0, stream>>>(fq, tq, fc, tc, in_cnt, in_list, out_cnt, out_list);
  k_prep_w<<<(512*384 + 512*256 + 255)/256, 256, 0, stream>>>(
      Wm1, Wr1, Wm2, Wr2, bm1, br1, bm2, br2, W1T, W2T, bcat1, bcat2);
  k_node_enc<<<NTOT_, D_, 0, stream>>>(node_features, Wn, bn, h0);
  k_edge_enc<<<ETOT_, D_, 0, stream>>>(edge_features, We, be, eb);
  k_cvt<<<(NTOT_*D_/4 + 255)/256, 256, 0, stream>>>(h0, hb, NTOT_*D_/4);

  dim3 gg(ETOT_/128, 4);
  float* hc = h0;
  float* hn = h1;
  for (int p = 0; p < NPROP_; ++p) {
    k_gemm1<<<gg, 256, 0, stream>>>(hb, eb, from_idx, to_idx, W1T, bcat1, hidden);
    k_gemm2<<<gg, 256, 0, stream>>>(hidden, W2T, bcat2, emsg);
    k_agg<<<NTOT_, 256, 0, stream>>>(emsg, in_cnt, in_list, out_cnt, out_list, agg);
    k_update<<<NTOT_/8, 256, 0, stream>>>(hc, agg, Wu, bu, hn);
    float* t_ = hc; hc = hn; hn = t_;
    k_cvt<<<(NTOT_*D_/4 + 255)/256, 256, 0, stream>>>(hc, hb, NTOT_*D_/4);
  }

  k_node_emb<<<B_*2*NMAX_, D_, 0, stream>>>(hc, Wq1, bq1, Wq2, bq2, tq_emb, tc_emb);
  k_sinkhorn_n<<<B_, 256, 0, stream>>>(tq_emb, tc_emb, plan_n);

  // final edge messages -> emsg, then edge-embed MLP -> teq/tec
  k_gemm1<<<gg, 256, 0, stream>>>(hb, eb, from_idx, to_idx, W1T, bcat1, hidden);
  k_gemm2<<<gg, 256, 0, stream>>>(hidden, W2T, bcat2, emsg);
  hipMemsetAsync(teq, 0, (size_t)B_*EMAX_*TD_*4, stream);
  hipMemsetAsync(tec, 0, (size_t)B_*EMAX_*TD_*4, stream);
  k_edge_emb<<<ETOT_/16, 256, 0, stream>>>(emsg, We1, be1, We2, be2, teq, tec);

  dim3 g_es(B_, EMAX_/16);
  k_escore<<<g_es, 256, 0, stream>>>(teq, tec, plan_e);
  k_sinkhorn_e<<<B_, 512, 0, stream>>>(plan_e);
  k_final<<<B_, 256, 0, stream>>>(plan_e, plan_n, tq_emb, tc_emb,
                                  fq, tq, fc, tc, Wa, ba, (float*)d_out);
}

// Round 5
// 1062.186 us; speedup vs baseline: 6.3584x; 1.4968x over previous
//
#include <hip/hip_runtime.h>
#include <cstddef>
#include <cstdint>

// ---------------- problem constants ----------------
constexpr int B_    = 128;
constexpr int NQ_   = 32;
constexpr int NC_   = 40;
constexpr int NMAX_ = 40;
constexpr int EQ_   = 160;
constexpr int EC_   = 240;
constexpr int EMAX_ = 256;
constexpr int D_    = 128;
constexpr int TD_   = 16;
constexpr int NPROP_ = 5;
constexpr int ITERS_ = 20;
constexpr float TEMP_ = 0.1f;
constexpr int NF_   = 32;
constexpr int EF_   = 16;
constexpr int NPB_  = NQ_ + NC_;   // 72 nodes / batch
constexpr int EPB_  = EQ_ + EC_;   // 400 edges / batch
constexpr int NTOT_ = B_ * NPB_;   // 9216
constexpr int ETOT_ = B_ * EPB_;   // 51200
constexpr int DEGCAP_ = 64;        // max per-node degree (random graphs: ~6 avg)

typedef _Float16 f16x8 __attribute__((ext_vector_type(8)));
typedef _Float16 f16x4 __attribute__((ext_vector_type(4)));
typedef float f32x4 __attribute__((ext_vector_type(4)));

__device__ __forceinline__ void gload16(const void* g, void* l) {
  __builtin_amdgcn_global_load_lds(
      (const __attribute__((address_space(1))) unsigned int*)g,
      (__attribute__((address_space(3))) unsigned int*)l, 16, 0, 0);
}

// ---------------- index building ----------------
__global__ __launch_bounds__(256) void k_build_idx(
    const int* __restrict__ fq, const int* __restrict__ tq,
    const int* __restrict__ fc, const int* __restrict__ tc,
    int* __restrict__ from_idx, int* __restrict__ to_idx)
{
  int i = blockIdx.x * blockDim.x + threadIdx.x;
  if (i >= ETOT_) return;
  int b = i / EPB_, j = i - b * EPB_;
  int f, t;
  if (j < EQ_) {
    f = fq[b*EQ_ + j] + b*NPB_;
    t = tq[b*EQ_ + j] + b*NPB_;
  } else {
    int jj = j - EQ_;
    f = fc[b*EC_ + jj] + b*NPB_ + NQ_;
    t = tc[b*EC_ + jj] + b*NPB_ + NQ_;
  }
  from_idx[i] = f;
  to_idx[i]   = t;
}

// ---------------- per-node edge lists (deterministic ascending order) ----------------
__global__ __launch_bounds__(256) void k_build_lists(
    const int* __restrict__ fq, const int* __restrict__ tq,
    const int* __restrict__ fc, const int* __restrict__ tc,
    int* __restrict__ in_cnt, int* __restrict__ in_list,
    int* __restrict__ out_cnt, int* __restrict__ out_list)
{
  const int b = blockIdx.x, tid = threadIdx.x;
  __shared__ short sf[EPB_], st[EPB_];
  for (int j = tid; j < EPB_; j += 256) {
    int f, t;
    if (j < EQ_) { f = fq[b*EQ_ + j];              t = tq[b*EQ_ + j]; }
    else         { f = fc[b*EC_ + (j-EQ_)] + NQ_;  t = tc[b*EC_ + (j-EQ_)] + NQ_; }
    sf[j] = (short)f; st[j] = (short)t;
  }
  __syncthreads();
  if (tid < NPB_) {
    const int g = b*NPB_ + tid;
    int ic = 0, oc = 0;
    for (int j = 0; j < EPB_; ++j) {
      if ((int)st[j] == tid && ic < DEGCAP_) in_list[g*DEGCAP_ + (ic++)] = j;
      if ((int)sf[j] == tid && oc < DEGCAP_) out_list[g*DEGCAP_ + (oc++)] = j;
    }
    in_cnt[g] = ic; out_cnt[g] = oc;
  }
}

// ---------------- weight prep: fp16, transposed [n][k]; Wr1 rows permuted ----------------
__global__ __launch_bounds__(256) void k_prep_w(
    const float* __restrict__ Wm1, const float* __restrict__ Wr1,
    const float* __restrict__ Wm2, const float* __restrict__ Wr2,
    const float* __restrict__ bm1, const float* __restrict__ br1,
    const float* __restrict__ bm2, const float* __restrict__ br2,
    _Float16* __restrict__ W1T, _Float16* __restrict__ W2T,
    float* __restrict__ bcat1, float* __restrict__ bcat2)
{
  int i = blockIdx.x * 256 + threadIdx.x;
  if (i < 512 * 384) {                    // W1T[n][k], n<256: Wm1, else permuted Wr1
    int n = i / 384, k = i - n * 384;
    float v;
    if (n < 256) v = Wm1[(size_t)k * 256 + n];
    else {
      int kk = (k < 128) ? k + 128 : (k < 256 ? k - 128 : k);
      v = Wr1[(size_t)kk * 256 + (n - 256)];
    }
    W1T[i] = (_Float16)v;
  }
  int j = i - 512 * 384;
  if (j >= 0 && j < 512 * 256) {          // W2T[n][k]
    int n = j / 256, k = j - n * 256;
    float v = (n < 256) ? Wm2[(size_t)k * 256 + n] : Wr2[(size_t)k * 256 + (n - 256)];
    W2T[j] = (_Float16)v;
  }
  if (i < 512) bcat1[i] = (i < 256) ? bm1[i] : br1[i - 256];
  if (i >= 512 && i < 1024) {
    int n = i - 512;
    bcat2[n] = (n < 256) ? bm2[n] : br2[n - 256];
  }
}

// ---------------- encoders ----------------
__global__ __launch_bounds__(128) void k_node_enc(
    const float* __restrict__ nf, const float* __restrict__ Wn,
    const float* __restrict__ bn, float* __restrict__ h)
{
  int n = blockIdx.x, j = threadIdx.x;
  __shared__ float xs[NF_];
  if (j < NF_) xs[j] = nf[(size_t)n*NF_ + j];
  __syncthreads();
  float a = bn[j];
  #pragma unroll
  for (int k = 0; k < NF_; ++k) a = fmaf(xs[k], Wn[(size_t)k*D_ + j], a);
  h[(size_t)n*D_ + j] = a;
}

__global__ __launch_bounds__(128) void k_edge_enc(
    const float* __restrict__ ef, const float* __restrict__ We,
    const float* __restrict__ be, _Float16* __restrict__ eb)
{
  int i = blockIdx.x, j = threadIdx.x;
  __shared__ float xs[EF_];
  if (j < EF_) xs[j] = ef[(size_t)i*EF_ + j];
  __syncthreads();
  float a = be[j];
  #pragma unroll
  for (int k = 0; k < EF_; ++k) a = fmaf(xs[k], We[(size_t)k*D_ + j], a);
  eb[(size_t)i*D_ + j] = (_Float16)a;
}

// ---------------- fp32 -> fp16 convert (4-wide) ----------------
__global__ __launch_bounds__(256) void k_cvt(
    const float* __restrict__ in, _Float16* __restrict__ out, int n4)
{
  int i = blockIdx.x * 256 + threadIdx.x;
  if (i >= n4) return;
  float4 v = reinterpret_cast<const float4*>(in)[i];
  f16x4 o;
  o[0] = (_Float16)v.x; o[1] = (_Float16)v.y; o[2] = (_Float16)v.z; o[3] = (_Float16)v.w;
  *reinterpret_cast<f16x4*>(&out[(size_t)i*4]) = o;
}

// ---------------- GEMM1: X[51200x384] @ W1T -> relu -> hidden fp16 [51200x512] ----------------
__global__ __launch_bounds__(256) void k_gemm1(
    const _Float16* __restrict__ hb, const _Float16* __restrict__ eb,
    const int* __restrict__ from_idx, const int* __restrict__ to_idx,
    const _Float16* __restrict__ W1T, const float* __restrict__ bcat1,
    _Float16* __restrict__ hidden)
{
  const int m0 = blockIdx.x * 128;
  const int n0 = blockIdx.y * 128;
  __shared__ _Float16 As[128 * 64];   // [row][chunk] 16B-chunk XOR swizzled
  __shared__ _Float16 Bs[128 * 64];

  const int tid  = threadIdx.x;
  const int srow = tid >> 3, slot = tid & 7;

  int fi[4], ti[4];
  #pragma unroll
  for (int i = 0; i < 4; ++i) {
    int r = m0 + srow + 32*i;
    fi[i] = from_idx[r];
    ti[i] = to_idx[r];
  }

  const int wave = tid >> 6, lane = tid & 63;
  const int wm = wave >> 1, wn = wave & 1;
  const int lr = lane & 15, lk = lane >> 4;

  f32x4 acc[4][4] = {};

  for (int kt = 0; kt < 6; ++kt) {
    __syncthreads();
    #pragma unroll
    for (int i = 0; i < 4; ++i) {
      const int r = srow + 32*i;
      const int sslot = slot ^ (r & 7);
      const _Float16* src;
      if (kt < 2)      src = hb + (size_t)fi[i]*128 + kt*64 + sslot*8;
      else if (kt < 4) src = hb + (size_t)ti[i]*128 + (kt-2)*64 + sslot*8;
      else             src = eb + (size_t)(m0 + r)*128 + (kt-4)*64 + sslot*8;
      gload16(src, &As[r*64 + slot*8]);
    }
    #pragma unroll
    for (int i = 0; i < 4; ++i) {
      const int n = srow + 32*i;
      const int sslot = slot ^ (n & 7);
      gload16(W1T + (size_t)(n0 + n)*384 + kt*64 + sslot*8, &Bs[n*64 + slot*8]);
    }
    __syncthreads();
    #pragma unroll
    for (int ks = 0; ks < 2; ++ks) {
      f16x8 af[4], bfr[4];
      #pragma unroll
      for (int mf = 0; mf < 4; ++mf) {
        const int r = wm*64 + mf*16 + lr;
        const int ch = (ks*4 + lk) ^ (r & 7);
        af[mf] = *(const f16x8*)&As[r*64 + ch*8];
      }
      #pragma unroll
      for (int nf = 0; nf < 4; ++nf) {
        const int n = wn*64 + nf*16 + lr;
        const int ch = (ks*4 + lk) ^ (n & 7);
        bfr[nf] = *(const f16x8*)&Bs[n*64 + ch*8];
      }
      #pragma unroll
      for (int mf = 0; mf < 4; ++mf)
        #pragma unroll
        for (int nf = 0; nf < 4; ++nf)
          acc[mf][nf] = __builtin_amdgcn_mfma_f32_16x16x32_f16(af[mf], bfr[nf], acc[mf][nf], 0, 0, 0);
    }
  }

  #pragma unroll
  for (int nf = 0; nf < 4; ++nf) {
    const int c = n0 + wn*64 + nf*16 + lr;
    const float bias = bcat1[c];
    #pragma unroll
    for (int mf = 0; mf < 4; ++mf) {
      #pragma unroll
      for (int v = 0; v < 4; ++v) {
        const int r = m0 + wm*64 + mf*16 + lk*4 + v;
        hidden[(size_t)r*512 + c] = (_Float16)fmaxf(acc[mf][nf][v] + bias, 0.f);
      }
    }
  }
}

// ---------------- GEMM2: hidden @ W2T (+bias) -> emsg[e][0..511] = [m | mr] ----------------
__global__ __launch_bounds__(256) void k_gemm2(
    const _Float16* __restrict__ hidden,
    const _Float16* __restrict__ W2T, const float* __restrict__ bcat2,
    _Float16* __restrict__ emsg)
{
  const int m0 = blockIdx.x * 128;
  const int by = blockIdx.y;
  const int n0 = by * 128;
  const int aoff = (by < 2) ? 0 : 256;
  __shared__ _Float16 As[128 * 64];
  __shared__ _Float16 Bs[128 * 64];

  const int tid  = threadIdx.x;
  const int srow = tid >> 3, slot = tid & 7;
  const int wave = tid >> 6, lane = tid & 63;
  const int wm = wave >> 1, wn = wave & 1;
  const int lr = lane & 15, lk = lane >> 4;

  f32x4 acc[4][4] = {};

  for (int kt = 0; kt < 4; ++kt) {
    __syncthreads();
    #pragma unroll
    for (int i = 0; i < 4; ++i) {
      const int r = srow + 32*i;
      const int sslot = slot ^ (r & 7);
      gload16(hidden + (size_t)(m0 + r)*512 + aoff + kt*64 + sslot*8, &As[r*64 + slot*8]);
    }
    #pragma unroll
    for (int i = 0; i < 4; ++i) {
      const int n = srow + 32*i;
      const int sslot = slot ^ (n & 7);
      gload16(W2T + (size_t)(n0 + n)*256 + kt*64 + sslot*8, &Bs[n*64 + slot*8]);
    }
    __syncthreads();
    #pragma unroll
    for (int ks = 0; ks < 2; ++ks) {
      f16x8 af[4], bfr[4];
      #pragma unroll
      for (int mf = 0; mf < 4; ++mf) {
        const int r = wm*64 + mf*16 + lr;
        const int ch = (ks*4 + lk) ^ (r & 7);
        af[mf] = *(const f16x8*)&As[r*64 + ch*8];
      }
      #pragma unroll
      for (int nf = 0; nf < 4; ++nf) {
        const int n = wn*64 + nf*16 + lr;
        const int ch = (ks*4 + lk) ^ (n & 7);
        bfr[nf] = *(const f16x8*)&Bs[n*64 + ch*8];
      }
      #pragma unroll
      for (int mf = 0; mf < 4; ++mf)
        #pragma unroll
        for (int nf = 0; nf < 4; ++nf)
          acc[mf][nf] = __builtin_amdgcn_mfma_f32_16x16x32_f16(af[mf], bfr[nf], acc[mf][nf], 0, 0, 0);
    }
  }

  #pragma unroll
  for (int nf = 0; nf < 4; ++nf) {
    const int c = n0 + wn*64 + nf*16 + lr;
    const float bias = bcat2[c];
    #pragma unroll
    for (int mf = 0; mf < 4; ++mf) {
      #pragma unroll
      for (int v = 0; v < 4; ++v) {
        const int r = m0 + wm*64 + mf*16 + lk*4 + v;
        emsg[(size_t)r*512 + c] = (_Float16)(acc[mf][nf][v] + bias);
      }
    }
  }
}

// ---------------- deterministic segment-sum gather ----------------
__global__ __launch_bounds__(256) void k_agg(
    const _Float16* __restrict__ emsg,
    const int* __restrict__ in_cnt, const int* __restrict__ in_list,
    const int* __restrict__ out_cnt, const int* __restrict__ out_list,
    float* __restrict__ agg)
{
  const int g = blockIdx.x;
  const int b = g / NPB_;
  const int c = threadIdx.x;
  const int ebase = b * EPB_;
  const int ic = in_cnt[g], oc = out_cnt[g];
  float a = 0.f;
  for (int i = 0; i < ic; ++i) {
    const int e = ebase + in_list[g*DEGCAP_ + i];
    a += (float)emsg[(size_t)e*512 + c];
  }
  for (int i = 0; i < oc; ++i) {
    const int e = ebase + out_list[g*DEGCAP_ + i];
    a += (float)emsg[(size_t)e*512 + 256 + c];
  }
  agg[(size_t)g*256 + c] = a;
}

// ---------------- final edge embed MLP: (m+mr)[256] -> 16 relu -> 16 ----------------
__global__ __launch_bounds__(256) void k_edge_emb(
    const _Float16* __restrict__ emsg,
    const float* __restrict__ We1, const float* __restrict__ be1,
    const float* __restrict__ We2, const float* __restrict__ be2,
    float* __restrict__ teq, float* __restrict__ tec)
{
  const int e0 = blockIdx.x * 16;
  const int tid = threadIdx.x;
  __shared__ float es[16][257];
  __shared__ float l1s[16][TD_];
  for (int idx = tid; idx < 16*256; idx += 256) {
    const int t = idx >> 8, k = idx & 255;
    const size_t base = (size_t)(e0 + t)*512;
    es[t][k] = (float)emsg[base + k] + (float)emsg[base + 256 + k];
  }
  __syncthreads();
  const int t = tid >> 4, jj = tid & 15;
  float a = be1[jj];
  for (int k = 0; k < 256; ++k) a = fmaf(es[t][k], We1[(size_t)k*TD_ + jj], a);
  l1s[t][jj] = fmaxf(a, 0.f);
  __syncthreads();
  float a2 = be2[jj];
  #pragma unroll
  for (int k = 0; k < TD_; ++k) a2 = fmaf(l1s[t][k], We2[(size_t)k*TD_ + jj], a2);
  const int ei = e0 + t;
  const int bb = ei / EPB_, jl = ei - bb*EPB_;
  if (jl < EQ_) teq[((size_t)bb*EMAX_ + jl)*TD_ + jj] = a2;
  else          tec[((size_t)bb*EMAX_ + (jl - EQ_))*TD_ + jj] = a2;
}

// ---------------- node update: h = [h, agg] @ Wu + bu ----------------
__global__ __launch_bounds__(256) void k_update(
    const float* __restrict__ h, const float* __restrict__ agg,
    const float* __restrict__ Wu, const float* __restrict__ bu,
    float* __restrict__ hn)
{
  const int n0 = blockIdx.x * 8;
  const int j = threadIdx.x & 127, half = threadIdx.x >> 7;
  __shared__ float xs[8][3*D_];
  for (int idx = threadIdx.x; idx < 8*3*D_; idx += 256) {
    int t = idx / (3*D_), k = idx - t*(3*D_);
    xs[t][k] = (k < D_) ? h[(size_t)(n0 + t)*D_ + k]
                        : agg[(size_t)(n0 + t)*(2*D_) + (k - D_)];
  }
  __syncthreads();
  float acc[4];
  const float b0 = bu[j];
  #pragma unroll
  for (int t = 0; t < 4; ++t) acc[t] = b0;
  for (int k = 0; k < 3*D_; k += 4) {
    const float w0 = Wu[(size_t)(k+0)*D_ + j];
    const float w1 = Wu[(size_t)(k+1)*D_ + j];
    const float w2 = Wu[(size_t)(k+2)*D_ + j];
    const float w3 = Wu[(size_t)(k+3)*D_ + j];
    #pragma unroll
    for (int t = 0; t < 4; ++t) {
      const float4 xv = *reinterpret_cast<const float4*>(&xs[half*4 + t][k]);
      acc[t] = fmaf(xv.w, w3, fmaf(xv.z, w2, fmaf(xv.y, w1, fmaf(xv.x, w0, acc[t]))));
    }
  }
  #pragma unroll
  for (int t = 0; t < 4; ++t)
    hn[(size_t)(n0 + half*4 + t)*D_ + j] = acc[t];
}

// ---------------- node target embeddings (128 -> 16 relu -> 16) ----------------
__global__ __launch_bounds__(128) void k_node_emb(
    const float* __restrict__ h,
    const float* __restrict__ Wq1, const float* __restrict__ bq1,
    const float* __restrict__ Wq2, const float* __restrict__ bq2,
    float* __restrict__ tq_emb, float* __restrict__ tc_emb)
{
  const int bid = blockIdx.x;
  const int b = bid / (2*NMAX_), s = bid - b*(2*NMAX_);
  const bool isQ = s < NMAX_;
  const int r = isQ ? s : s - NMAX_;
  float* outp = (isQ ? tq_emb : tc_emb) + ((size_t)b*NMAX_ + r)*TD_;
  const int tid = threadIdx.x;
  if (isQ && r >= NQ_) {
    if (tid < TD_) outp[tid] = 0.f;
    return;
  }
  const int node = b*NPB_ + (isQ ? r : NQ_ + r);
  __shared__ float xs[D_];
  __shared__ float l1[TD_];
  xs[tid] = h[(size_t)node*D_ + tid];
  __syncthreads();
  if (tid < TD_) {
    float a = bq1[tid];
    for (int k = 0; k < D_; ++k) a = fmaf(xs[k], Wq1[(size_t)k*TD_ + tid], a);
    l1[tid] = fmaxf(a, 0.f);
  }
  __syncthreads();
  if (tid < TD_) {
    float a = bq2[tid];
    #pragma unroll
    for (int k = 0; k < TD_; ++k) a = fmaf(l1[k], Wq2[(size_t)k*TD_ + tid], a);
    outp[tid] = a;
  }
}

// ---------------- sinkhorn over 40x40 node plans (LDS) ----------------
__global__ __launch_bounds__(256) void k_sinkhorn_n(
    const float* __restrict__ tq_emb, const float* __restrict__ tc_emb,
    float* __restrict__ plan_n)
{
  const int b = blockIdx.x, tid = threadIdx.x;
  __shared__ float la[NMAX_][NMAX_];
  __shared__ float qe[NMAX_][TD_], ce[NMAX_][TD_];
  for (int idx = tid; idx < NMAX_*TD_; idx += 256) {
    qe[idx / TD_][idx % TD_] = tq_emb[(size_t)b*NMAX_*TD_ + idx];
    ce[idx / TD_][idx % TD_] = tc_emb[(size_t)b*NMAX_*TD_ + idx];
  }
  __syncthreads();
  for (int idx = tid; idx < NMAX_*NMAX_; idx += 256) {
    int q = idx / NMAX_, c = idx - q*NMAX_;
    float a = 0.f;
    #pragma unroll
    for (int d = 0; d < TD_; ++d) a = fmaf(qe[q][d], ce[c][d], a);
    la[q][c] = a / TEMP_;
  }
  __syncthreads();
  for (int it = 0; it < ITERS_; ++it) {
    if (tid < NMAX_) {
      float m = -INFINITY;
      for (int c = 0; c < NMAX_; ++c) m = fmaxf(m, la[tid][c]);
      float s = 0.f;
      for (int c = 0; c < NMAX_; ++c) s += __expf(la[tid][c] - m);
      const float lse = m + __logf(s);
      for (int c = 0; c < NMAX_; ++c) la[tid][c] -= lse;
    }
    __syncthreads();
    if (tid < NMAX_) {
      float m = -INFINITY;
      for (int q = 0; q < NMAX_; ++q) m = fmaxf(m, la[q][tid]);
      float s = 0.f;
      for (int q = 0; q < NMAX_; ++q) s += __expf(la[q][tid] - m);
      const float lse = m + __logf(s);
      for (int q = 0; q < NMAX_; ++q) la[q][tid] -= lse;
    }
    __syncthreads();
  }
  for (int idx = tid; idx < NMAX_*NMAX_; idx += 256)
    plan_n[(size_t)b*NMAX_*NMAX_ + idx] = __expf(la[idx / NMAX_][idx % NMAX_]);
}

// ---------------- fused: escore + sinkhorn_e (in registers) + final score ----------------
// 1024 threads; thread (tr = t>>4, tc = t&15) owns rows tr*4+{0..3}, cols tc*16+{0..15}.
__global__ __launch_bounds__(1024) void k_plan_score(
    const float* __restrict__ teq, const float* __restrict__ tec,
    const float* __restrict__ plan_n,
    const float* __restrict__ tq_emb, const float* __restrict__ tc_emb,
    const int* __restrict__ fq, const int* __restrict__ tq,
    const int* __restrict__ fc, const int* __restrict__ tc,
    const float* __restrict__ Wa, const float* __restrict__ ba,
    float* __restrict__ out)
{
  const int b = blockIdx.x;
  const int t = threadIdx.x;
  const int tr = t >> 4;          // 0..63
  const int tcg = t & 15;         // 0..15
  const int lane = t & 63;
  const int w = t >> 6;           // wave 0..15

  __shared__ float sq[EMAX_][TD_];     // 16 KB
  __shared__ float sc[EMAX_][TD_];     // 16 KB
  __shared__ float wpart[16][16][16];  // 16 KB
  __shared__ float bcast[EMAX_];       // 1 KB
  __shared__ float pn[NMAX_*NMAX_];    // 6.4 KB
  __shared__ float qe[NMAX_*TD_], ce[NMAX_*TD_];  // 5.1 KB
  __shared__ int sfq[EQ_], stq[EQ_], sfc[EC_], stc[EC_];  // 3.2 KB

  // loads
  {
    const float4* src = reinterpret_cast<const float4*>(teq + (size_t)b*EMAX_*TD_);
    reinterpret_cast<float4*>(&sq[0][0])[t] = src[t];
    const float4* src2 = reinterpret_cast<const float4*>(tec + (size_t)b*EMAX_*TD_);
    reinterpret_cast<float4*>(&sc[0][0])[t] = src2[t];
  }
  for (int i = t; i < NMAX_*NMAX_; i += 1024) pn[i] = plan_n[(size_t)b*NMAX_*NMAX_ + i];
  if (t < NMAX_*TD_) { qe[t] = tq_emb[(size_t)b*NMAX_*TD_ + t]; ce[t] = tc_emb[(size_t)b*NMAX_*TD_ + t]; }
  if (t < EQ_) { sfq[t] = fq[b*EQ_ + t]; stq[t] = tq[b*EQ_ + t]; }
  if (t >= 512 && t < 512 + EC_) { sfc[t-512] = fc[b*EC_ + (t-512)]; stc[t-512] = tc[b*EC_ + (t-512)]; }
  __syncthreads();

  // scores: la[i][j] = dot(sq[row], sc[col]) / TEMP
  float la[4][16];
  #pragma unroll
  for (int i = 0; i < 4; ++i) {
    const int q = tr*4 + i;
    float qv[TD_];
    #pragma unroll
    for (int k = 0; k < TD_; ++k) qv[k] = sq[q][k];
    #pragma unroll
    for (int j = 0; j < 16; ++j) {
      const int c = tcg*16 + j;
      float a = 0.f;
      #pragma unroll
      for (int k = 0; k < TD_; ++k) a = fmaf(qv[k], sc[c][k], a);
      la[i][j] = a * 10.0f;   // 1/TEMP
    }
  }

  for (int it = 0; it < ITERS_; ++it) {
    // ---- row LSE (16 threads per row, consecutive lanes) ----
    #pragma unroll
    for (int i = 0; i < 4; ++i) {
      float m = la[i][0];
      #pragma unroll
      for (int j = 1; j < 16; ++j) m = fmaxf(m, la[i][j]);
      m = fmaxf(m, __shfl_xor(m, 1)); m = fmaxf(m, __shfl_xor(m, 2));
      m = fmaxf(m, __shfl_xor(m, 4)); m = fmaxf(m, __shfl_xor(m, 8));
      float s = 0.f;
      #pragma unroll
      for (int j = 0; j < 16; ++j) s += __expf(la[i][j] - m);
      s += __shfl_xor(s, 1); s += __shfl_xor(s, 2);
      s += __shfl_xor(s, 4); s += __shfl_xor(s, 8);
      const float lse = m + __logf(s);
      #pragma unroll
      for (int j = 0; j < 16; ++j) la[i][j] -= lse;
    }
    // ---- col max ----
    {
      float cm[16];
      #pragma unroll
      for (int j = 0; j < 16; ++j) {
        float m = fmaxf(fmaxf(la[0][j], la[1][j]), fmaxf(la[2][j], la[3][j]));
        m = fmaxf(m, __shfl_xor(m, 16));
        m = fmaxf(m, __shfl_xor(m, 32));
        cm[j] = m;
      }
      if (lane < 16) {
        #pragma unroll
        for (int j = 0; j < 16; ++j) wpart[w][lane][j] = cm[j];
      }
    }
    __syncthreads();
    if (t < EMAX_) {
      float m = wpart[0][t >> 4][t & 15];
      #pragma unroll
      for (int ww = 1; ww < 16; ++ww) m = fmaxf(m, wpart[ww][t >> 4][t & 15]);
      bcast[t] = m;
    }
    __syncthreads();
    // ---- col sum of exp ----
    {
      float cs[16];
      #pragma unroll
      for (int j = 0; j < 16; ++j) {
        const float cm = bcast[tcg*16 + j];
        float s = __expf(la[0][j] - cm) + __expf(la[1][j] - cm)
                + __expf(la[2][j] - cm) + __expf(la[3][j] - cm);
        s += __shfl_xor(s, 16);
        s += __shfl_xor(s, 32);
        cs[j] = s;
      }
      if (lane < 16) {
        #pragma unroll
        for (int j = 0; j < 16; ++j) wpart[w][lane][j] = cs[j];
      }
    }
    __syncthreads();
    if (t < EMAX_) {
      float s = wpart[0][t >> 4][t & 15];
      #pragma unroll
      for (int ww = 1; ww < 16; ++ww) s += wpart[ww][t >> 4][t & 15];
      bcast[t] = bcast[t] + __logf(s);   // col lse
    }
    __syncthreads();
    #pragma unroll
    for (int j = 0; j < 16; ++j) {
      const float lse = bcast[tcg*16 + j];
      #pragma unroll
      for (int i = 0; i < 4; ++i) la[i][j] -= lse;
    }
    __syncthreads();
  }

  // ---- epilogue: consistency + hinge ----
  float csum = 0.f;
  #pragma unroll
  for (int i = 0; i < 4; ++i) {
    const int q = tr*4 + i;
    if (q < EQ_) {
      const int gq0 = sfq[q]*NMAX_, gq1 = stq[q]*NMAX_;
      #pragma unroll
      for (int j = 0; j < 16; ++j) {
        const int c = tcg*16 + j;
        if (c < EC_) {
          const float pe = __expf(la[i][j]);
          const float a0 = pn[gq0 + sfc[c]] * pn[gq1 + stc[c]];
          const float a1 = pn[gq0 + stc[c]] * pn[gq1 + sfc[c]];
          csum += pe * fmaxf(a0, a1);
        }
      }
    }
  }
  float hsum = 0.f;
  if (t < NMAX_*TD_) {
    const int q = t >> 4, d2 = t & 15;
    float a = 0.f;
    for (int c = 0; c < NMAX_; ++c) a = fmaf(pn[q*NMAX_ + c], ce[c*TD_ + d2], a);
    hsum = fmaxf(qe[t] - a, 0.f);
  }
  #pragma unroll
  for (int off2 = 32; off2; off2 >>= 1) {
    csum += __shfl_xor(csum, off2);
    hsum += __shfl_xor(hsum, off2);
  }
  if (lane == 0) { bcast[w] = csum; bcast[32 + w] = hsum; }
  __syncthreads();
  if (t == 0) {
    float C = 0.f, H = 0.f;
    #pragma unroll
    for (int ww = 0; ww < 16; ++ww) { C += bcast[ww]; H += bcast[32 + ww]; }
    out[b] = (-H) * Wa[0] + C * Wa[1] + ba[0];
  }
}

// ---------------- host launcher ----------------
extern "C" void kernel_launch(void* const* d_in, const int* in_sizes, int n_in,
                              void* d_out, int out_size, void* d_ws, size_t ws_size,
                              hipStream_t stream) {
  const float* node_features = (const float*)d_in[0];
  const float* edge_features = (const float*)d_in[1];
  const float* Wn  = (const float*)d_in[2];
  const float* bn  = (const float*)d_in[3];
  const float* We  = (const float*)d_in[4];
  const float* be  = (const float*)d_in[5];
  const float* Wm1 = (const float*)d_in[6];
  const float* bm1 = (const float*)d_in[7];
  const float* Wm2 = (const float*)d_in[8];
  const float* bm2 = (const float*)d_in[9];
  const float* Wr1 = (const float*)d_in[10];
  const float* br1 = (const float*)d_in[11];
  const float* Wr2 = (const float*)d_in[12];
  const float* br2 = (const float*)d_in[13];
  const float* Wu  = (const float*)d_in[14];
  const float* bu  = (const float*)d_in[15];
  const float* Wq1 = (const float*)d_in[16];
  const float* bq1 = (const float*)d_in[17];
  const float* Wq2 = (const float*)d_in[18];
  const float* bq2 = (const float*)d_in[19];
  const float* We1 = (const float*)d_in[20];
  const float* be1 = (const float*)d_in[21];
  const float* We2 = (const float*)d_in[22];
  const float* be2 = (const float*)d_in[23];
  const float* Wa  = (const float*)d_in[24];
  const float* ba  = (const float*)d_in[25];
  const int* fq = (const int*)d_in[26];
  const int* tq = (const int*)d_in[27];
  const int* fc = (const int*)d_in[28];
  const int* tc = (const int*)d_in[29];
  (void)in_sizes; (void)n_in; (void)out_size; (void)ws_size;

  char* ws = (char*)d_ws;
  size_t off = 0;
  auto take = [&](size_t bytes) -> void* {
    void* p = ws + off;
    off = (off + bytes + 255) & ~(size_t)255;
    return p;
  };
  int*   from_idx = (int*)  take((size_t)ETOT_*4);
  int*   to_idx   = (int*)  take((size_t)ETOT_*4);
  int*   in_cnt   = (int*)  take((size_t)NTOT_*4);
  int*   out_cnt  = (int*)  take((size_t)NTOT_*4);
  int*   in_list  = (int*)  take((size_t)NTOT_*DEGCAP_*4);
  int*   out_list = (int*)  take((size_t)NTOT_*DEGCAP_*4);
  float* h0       = (float*)take((size_t)NTOT_*D_*4);
  float* h1       = (float*)take((size_t)NTOT_*D_*4);
  _Float16* hb    = (_Float16*)take((size_t)NTOT_*D_*2);
  _Float16* eb    = (_Float16*)take((size_t)ETOT_*D_*2);
  float* agg      = (float*)take((size_t)NTOT_*2*D_*4);
  _Float16* hidden = (_Float16*)take((size_t)ETOT_*512*2);
  _Float16* emsg  = (_Float16*)take((size_t)ETOT_*512*2);
  float* tq_emb   = (float*)take((size_t)B_*NMAX_*TD_*4);
  float* tc_emb   = (float*)take((size_t)B_*NMAX_*TD_*4);
  float* plan_n   = (float*)take((size_t)B_*NMAX_*NMAX_*4);
  float* teq      = (float*)take((size_t)B_*EMAX_*TD_*4);
  float* tec      = (float*)take((size_t)B_*EMAX_*TD_*4);
  _Float16* W1T   = (_Float16*)take((size_t)512*384*2);
  _Float16* W2T   = (_Float16*)take((size_t)512*256*2);
  float* bcat1    = (float*)take(512*4);
  float* bcat2    = (float*)take(512*4);

  k_build_idx<<<(ETOT_ + 255)/256, 256, 0, stream>>>(fq, tq, fc, tc, from_idx, to_idx);
  k_build_lists<<<B_, 256, 0, stream>>>(fq, tq, fc, tc, in_cnt, in_list, out_cnt, out_list);
  k_prep_w<<<(512*384 + 512*256 + 255)/256, 256, 0, stream>>>(
      Wm1, Wr1, Wm2, Wr2, bm1, br1, bm2, br2, W1T, W2T, bcat1, bcat2);
  k_node_enc<<<NTOT_, D_, 0, stream>>>(node_features, Wn, bn, h0);
  k_edge_enc<<<ETOT_, D_, 0, stream>>>(edge_features, We, be, eb);
  k_cvt<<<(NTOT_*D_/4 + 255)/256, 256, 0, stream>>>(h0, hb, NTOT_*D_/4);

  dim3 gg(ETOT_/128, 4);
  float* hc = h0;
  float* hn = h1;
  for (int p = 0; p < NPROP_; ++p) {
    k_gemm1<<<gg, 256, 0, stream>>>(hb, eb, from_idx, to_idx, W1T, bcat1, hidden);
    k_gemm2<<<gg, 256, 0, stream>>>(hidden, W2T, bcat2, emsg);
    k_agg<<<NTOT_, 256, 0, stream>>>(emsg, in_cnt, in_list, out_cnt, out_list, agg);
    k_update<<<NTOT_/8, 256, 0, stream>>>(hc, agg, Wu, bu, hn);
    float* t_ = hc; hc = hn; hn = t_;
    k_cvt<<<(NTOT_*D_/4 + 255)/256, 256, 0, stream>>>(hc, hb, NTOT_*D_/4);
  }

  k_node_emb<<<B_*2*NMAX_, D_, 0, stream>>>(hc, Wq1, bq1, Wq2, bq2, tq_emb, tc_emb);
  k_sinkhorn_n<<<B_, 256, 0, stream>>>(tq_emb, tc_emb, plan_n);

  // final edge messages -> emsg, then edge-embed MLP -> teq/tec
  k_gemm1<<<gg, 256, 0, stream>>>(hb, eb, from_idx, to_idx, W1T, bcat1, hidden);
  k_gemm2<<<gg, 256, 0, stream>>>(hidden, W2T, bcat2, emsg);
  hipMemsetAsync(teq, 0, (size_t)B_*EMAX_*TD_*4, stream);
  hipMemsetAsync(tec, 0, (size_t)B_*EMAX_*TD_*4, stream);
  k_edge_emb<<<ETOT_/16, 256, 0, stream>>>(emsg, We1, be1, We2, be2, teq, tec);

  // fused escore + sinkhorn_e + final
  k_plan_score<<<B_, 1024, 0, stream>>>(teq, tec, plan_n, tq_emb, tc_emb,
                                        fq, tq, fc, tc, Wa, ba, (float*)d_out);
}

// Round 6
// 1038.587 us; speedup vs baseline: 6.5028x; 1.0227x over previous
//
#include <hip/hip_runtime.h>
#include <cstddef>
#include <cstdint>

// ---------------- problem constants ----------------
constexpr int B_    = 128;
constexpr int NQ_   = 32;
constexpr int NC_   = 40;
constexpr int NMAX_ = 40;
constexpr int EQ_   = 160;
constexpr int EC_   = 240;
constexpr int EMAX_ = 256;
constexpr int D_    = 128;
constexpr int TD_   = 16;
constexpr int NPROP_ = 5;
constexpr int ITERS_ = 20;
constexpr float TEMP_ = 0.1f;
constexpr int NF_   = 32;
constexpr int EF_   = 16;
constexpr int NPB_  = NQ_ + NC_;   // 72 nodes / batch
constexpr int EPB_  = EQ_ + EC_;   // 400 edges / batch
constexpr int NTOT_ = B_ * NPB_;   // 9216
constexpr int ETOT_ = B_ * EPB_;   // 51200
constexpr int DEGCAP_ = 64;

typedef _Float16 f16x8 __attribute__((ext_vector_type(8)));
typedef float f32x4 __attribute__((ext_vector_type(4)));

__device__ __forceinline__ void gload16(const void* g, void* l) {
  __builtin_amdgcn_global_load_lds(
      (const __attribute__((address_space(1))) unsigned int*)g,
      (__attribute__((address_space(3))) unsigned int*)l, 16, 0, 0);
}

// ---------------- index building ----------------
__global__ __launch_bounds__(256) void k_build_idx(
    const int* __restrict__ fq, const int* __restrict__ tq,
    const int* __restrict__ fc, const int* __restrict__ tc,
    int* __restrict__ from_idx, int* __restrict__ to_idx)
{
  int i = blockIdx.x * blockDim.x + threadIdx.x;
  if (i >= ETOT_) return;
  int b = i / EPB_, j = i - b * EPB_;
  int f, t;
  if (j < EQ_) {
    f = fq[b*EQ_ + j] + b*NPB_;
    t = tq[b*EQ_ + j] + b*NPB_;
  } else {
    int jj = j - EQ_;
    f = fc[b*EC_ + jj] + b*NPB_ + NQ_;
    t = tc[b*EC_ + jj] + b*NPB_ + NQ_;
  }
  from_idx[i] = f;
  to_idx[i]   = t;
}

// ---------------- per-node edge lists (deterministic ascending order) ----------------
__global__ __launch_bounds__(256) void k_build_lists(
    const int* __restrict__ fq, const int* __restrict__ tq,
    const int* __restrict__ fc, const int* __restrict__ tc,
    int* __restrict__ in_cnt, int* __restrict__ in_list,
    int* __restrict__ out_cnt, int* __restrict__ out_list)
{
  const int b = blockIdx.x, tid = threadIdx.x;
  __shared__ short sf[EPB_], st[EPB_];
  for (int j = tid; j < EPB_; j += 256) {
    int f, t;
    if (j < EQ_) { f = fq[b*EQ_ + j];              t = tq[b*EQ_ + j]; }
    else         { f = fc[b*EC_ + (j-EQ_)] + NQ_;  t = tc[b*EC_ + (j-EQ_)] + NQ_; }
    sf[j] = (short)f; st[j] = (short)t;
  }
  __syncthreads();
  if (tid < NPB_) {
    const int g = b*NPB_ + tid;
    int ic = 0, oc = 0;
    for (int j = 0; j < EPB_; ++j) {
      if ((int)st[j] == tid && ic < DEGCAP_) in_list[g*DEGCAP_ + (ic++)] = j;
      if ((int)sf[j] == tid && oc < DEGCAP_) out_list[g*DEGCAP_ + (oc++)] = j;
    }
    in_cnt[g] = ic; out_cnt[g] = oc;
  }
}

// ---------------- weight prep ----------------
// W1Tn[1024][128]: n<512 -> F-part (W1 rows 0:128), n>=512 -> T-part (rows 128:256)
// W1Te[512][128]:  e-part (W1 rows 256:384)
// W2cT[256][512]:  agg GEMM B: k<256 -> Wm2[k][n], k>=256 -> Wr2[k-256][n]
// bcat1[512]: concat(bm1, br1)
__global__ __launch_bounds__(256) void k_prep_w(
    const float* __restrict__ Wm1, const float* __restrict__ Wr1,
    const float* __restrict__ Wm2, const float* __restrict__ Wr2,
    const float* __restrict__ bm1, const float* __restrict__ br1,
    _Float16* __restrict__ W1Tn, _Float16* __restrict__ W1Te,
    _Float16* __restrict__ W2cT, float* __restrict__ bcat1)
{
  int i = blockIdx.x * 256 + threadIdx.x;
  if (i < 1024*128) {
    int n = i >> 7, k = i & 127;
    float v;
    if (n < 512) {            // F-part: W1 row k
      v = (n < 256) ? Wm1[(size_t)k*256 + n]
                    : Wr1[(size_t)(k + 128)*256 + (n - 256)];
    } else {                  // T-part: W1 row 128+k
      int n2 = n - 512;
      v = (n2 < 256) ? Wm1[(size_t)(128 + k)*256 + n2]
                     : Wr1[(size_t)k*256 + (n2 - 256)];
    }
    W1Tn[i] = (_Float16)v;
  }
  int j = i - 1024*128;
  if (j >= 0 && j < 512*128) {
    int n = j >> 7, k = j & 127;   // W1 row 256+k
    float v = (n < 256) ? Wm1[(size_t)(256 + k)*256 + n]
                        : Wr1[(size_t)(256 + k)*256 + (n - 256)];
    W1Te[j] = (_Float16)v;
  }
  int l = i - 1024*128 - 512*128;
  if (l >= 0 && l < 256*512) {
    int n = l >> 9, k = l & 511;
    float v = (k < 256) ? Wm2[(size_t)k*256 + n] : Wr2[(size_t)(k-256)*256 + n];
    W2cT[l] = (_Float16)v;
  }
  if (i < 512) bcat1[i] = (i < 256) ? bm1[i] : br1[i - 256];
}

// WceT[16][512] = (W2cat @ We1)^T ; bce[16] = (bm2+br2)@We1 + be1
__global__ __launch_bounds__(256) void k_prep_wce(
    const float* __restrict__ Wm2, const float* __restrict__ Wr2,
    const float* __restrict__ We1, const float* __restrict__ bm2,
    const float* __restrict__ br2, const float* __restrict__ be1,
    float* __restrict__ WceT, float* __restrict__ bce)
{
  int i = blockIdx.x * 256 + threadIdx.x;
  if (i < 16*512) {
    int j = i >> 9, k = i & 511;
    float a = 0.f;
    for (int m = 0; m < 256; ++m) {
      const float w2 = (k < 256) ? Wm2[(size_t)k*256 + m] : Wr2[(size_t)(k-256)*256 + m];
      a = fmaf(w2, We1[(size_t)m*TD_ + j], a);
    }
    WceT[(size_t)j*512 + k] = a;
  }
  if (i < 16) {
    float a = be1[i];
    for (int m = 0; m < 256; ++m) a = fmaf(bm2[m] + br2[m], We1[(size_t)m*TD_ + i], a);
    bce[i] = a;
  }
}

// ---------------- encoders ----------------
__global__ __launch_bounds__(128) void k_node_enc(
    const float* __restrict__ nf, const float* __restrict__ Wn,
    const float* __restrict__ bn, float* __restrict__ h, _Float16* __restrict__ hb)
{
  int n = blockIdx.x, j = threadIdx.x;
  __shared__ float xs[NF_];
  if (j < NF_) xs[j] = nf[(size_t)n*NF_ + j];
  __syncthreads();
  float a = bn[j];
  #pragma unroll
  for (int k = 0; k < NF_; ++k) a = fmaf(xs[k], Wn[(size_t)k*D_ + j], a);
  h[(size_t)n*D_ + j] = a;
  hb[(size_t)n*D_ + j] = (_Float16)a;
}

__global__ __launch_bounds__(128) void k_edge_enc(
    const float* __restrict__ ef, const float* __restrict__ We,
    const float* __restrict__ be, _Float16* __restrict__ eb)
{
  int i = blockIdx.x, j = threadIdx.x;
  __shared__ float xs[EF_];
  if (j < EF_) xs[j] = ef[(size_t)i*EF_ + j];
  __syncthreads();
  float a = be[j];
  #pragma unroll
  for (int k = 0; k < EF_; ++k) a = fmaf(xs[k], We[(size_t)k*D_ + j], a);
  eb[(size_t)i*D_ + j] = (_Float16)a;
}

// ---------------- GEMM: FT = hb @ W1Tn  (M=9216, N=1024, K=128) ----------------
__global__ __launch_bounds__(256) void k_gemm_FT(
    const _Float16* __restrict__ A, const _Float16* __restrict__ Bm,
    _Float16* __restrict__ FT)
{
  const int m0 = blockIdx.x * 128, n0 = blockIdx.y * 128;
  __shared__ _Float16 As[128*64], Bs[128*64];
  const int tid = threadIdx.x;
  const int srow = tid >> 3, slot = tid & 7;
  const int wave = tid >> 6, lane = tid & 63;
  const int wm = wave >> 1, wn = wave & 1;
  const int lr = lane & 15, lk = lane >> 4;
  f32x4 acc[4][4] = {};
  for (int kt = 0; kt < 2; ++kt) {
    __syncthreads();
    #pragma unroll
    for (int i = 0; i < 4; ++i) {
      const int r = srow + 32*i;
      const int ss = slot ^ (r & 7);
      gload16(A + (size_t)(m0 + r)*128 + kt*64 + ss*8, &As[r*64 + slot*8]);
      gload16(Bm + (size_t)(n0 + r)*128 + kt*64 + ss*8, &Bs[r*64 + slot*8]);
    }
    __syncthreads();
    #pragma unroll
    for (int ks = 0; ks < 2; ++ks) {
      f16x8 af[4], bfr[4];
      #pragma unroll
      for (int mf = 0; mf < 4; ++mf) {
        const int r = wm*64 + mf*16 + lr;
        const int ch = (ks*4 + lk) ^ (r & 7);
        af[mf] = *(const f16x8*)&As[r*64 + ch*8];
      }
      #pragma unroll
      for (int nf = 0; nf < 4; ++nf) {
        const int n = wn*64 + nf*16 + lr;
        const int ch = (ks*4 + lk) ^ (n & 7);
        bfr[nf] = *(const f16x8*)&Bs[n*64 + ch*8];
      }
      #pragma unroll
      for (int mf = 0; mf < 4; ++mf)
        #pragma unroll
        for (int nf = 0; nf < 4; ++nf)
          acc[mf][nf] = __builtin_amdgcn_mfma_f32_16x16x32_f16(af[mf], bfr[nf], acc[mf][nf], 0, 0, 0);
    }
  }
  #pragma unroll
  for (int nf = 0; nf < 4; ++nf) {
    const int c = n0 + wn*64 + nf*16 + lr;
    #pragma unroll
    for (int mf = 0; mf < 4; ++mf)
      #pragma unroll
      for (int v = 0; v < 4; ++v) {
        const int r = m0 + wm*64 + mf*16 + lk*4 + v;
        FT[(size_t)r*1024 + c] = (_Float16)acc[mf][nf][v];
      }
  }
}

// ---------------- GEMM: E = eb @ W1Te + bcat1  (M=51200, N=512, K=128) ----------------
__global__ __launch_bounds__(256) void k_gemm_E(
    const _Float16* __restrict__ A, const _Float16* __restrict__ Bm,
    const float* __restrict__ bcat1, _Float16* __restrict__ E)
{
  const int m0 = blockIdx.x * 128, n0 = blockIdx.y * 128;
  __shared__ _Float16 As[128*64], Bs[128*64];
  const int tid = threadIdx.x;
  const int srow = tid >> 3, slot = tid & 7;
  const int wave = tid >> 6, lane = tid & 63;
  const int wm = wave >> 1, wn = wave & 1;
  const int lr = lane & 15, lk = lane >> 4;
  f32x4 acc[4][4] = {};
  for (int kt = 0; kt < 2; ++kt) {
    __syncthreads();
    #pragma unroll
    for (int i = 0; i < 4; ++i) {
      const int r = srow + 32*i;
      const int ss = slot ^ (r & 7);
      gload16(A + (size_t)(m0 + r)*128 + kt*64 + ss*8, &As[r*64 + slot*8]);
      gload16(Bm + (size_t)(n0 + r)*128 + kt*64 + ss*8, &Bs[r*64 + slot*8]);
    }
    __syncthreads();
    #pragma unroll
    for (int ks = 0; ks < 2; ++ks) {
      f16x8 af[4], bfr[4];
      #pragma unroll
      for (int mf = 0; mf < 4; ++mf) {
        const int r = wm*64 + mf*16 + lr;
        const int ch = (ks*4 + lk) ^ (r & 7);
        af[mf] = *(const f16x8*)&As[r*64 + ch*8];
      }
      #pragma unroll
      for (int nf = 0; nf < 4; ++nf) {
        const int n = wn*64 + nf*16 + lr;
        const int ch = (ks*4 + lk) ^ (n & 7);
        bfr[nf] = *(const f16x8*)&Bs[n*64 + ch*8];
      }
      #pragma unroll
      for (int mf = 0; mf < 4; ++mf)
        #pragma unroll
        for (int nf = 0; nf < 4; ++nf)
          acc[mf][nf] = __builtin_amdgcn_mfma_f32_16x16x32_f16(af[mf], bfr[nf], acc[mf][nf], 0, 0, 0);
    }
  }
  #pragma unroll
  for (int nf = 0; nf < 4; ++nf) {
    const int c = n0 + wn*64 + nf*16 + lr;
    const float bias = bcat1[c];
    #pragma unroll
    for (int mf = 0; mf < 4; ++mf)
      #pragma unroll
      for (int v = 0; v < 4; ++v) {
        const int r = m0 + wm*64 + mf*16 + lk*4 + v;
        E[(size_t)r*512 + c] = (_Float16)(acc[mf][nf][v] + bias);
      }
  }
}

// ---------------- fused hidden + deterministic segment-sum ----------------
// Hsum[n][0:256]   = sum_{e in(n)} relu(F[from][c] + T[n][c] + E[e][c])
// Hsum[n][256:512] = sum_{e out(n)} relu(F[n][256+c] + T[to][256+c] + E[e][256+c])
__global__ __launch_bounds__(256) void k_agg_fused(
    const _Float16* __restrict__ FT, const _Float16* __restrict__ E,
    const int* __restrict__ from_idx, const int* __restrict__ to_idx,
    const int* __restrict__ in_cnt, const int* __restrict__ in_list,
    const int* __restrict__ out_cnt, const int* __restrict__ out_list,
    _Float16* __restrict__ Hsum)
{
  const int g = blockIdx.x;
  const int b = g / NPB_;
  const int c = threadIdx.x;
  const int ebase = b * EPB_;
  const float Tn = (float)FT[(size_t)g*1024 + 512 + c];
  const float Fn = (float)FT[(size_t)g*1024 + 256 + c];
  const int ic = in_cnt[g], oc = out_cnt[g];
  float si = 0.f, so = 0.f;
  for (int i = 0; i < ic; ++i) {
    const int ge = ebase + in_list[g*DEGCAP_ + i];
    const int src = from_idx[ge];
    si += fmaxf((float)FT[(size_t)src*1024 + c] + Tn + (float)E[(size_t)ge*512 + c], 0.f);
  }
  for (int i = 0; i < oc; ++i) {
    const int ge = ebase + out_list[g*DEGCAP_ + i];
    const int dst = to_idx[ge];
    so += fmaxf(Fn + (float)FT[(size_t)dst*1024 + 768 + c] + (float)E[(size_t)ge*512 + 256 + c], 0.f);
  }
  Hsum[(size_t)g*512 + c] = (_Float16)si;
  Hsum[(size_t)g*512 + 256 + c] = (_Float16)so;
}

// ---------------- GEMM: agg = Hsum @ W2cT + ic*bm2 + oc*br2  (M=9216, N=256, K=512) ----------------
__global__ __launch_bounds__(256) void k_gemm_agg(
    const _Float16* __restrict__ A, const _Float16* __restrict__ Bm,
    const int* __restrict__ in_cnt, const int* __restrict__ out_cnt,
    const float* __restrict__ bm2, const float* __restrict__ br2,
    float* __restrict__ agg)
{
  const int m0 = blockIdx.x * 128, n0 = blockIdx.y * 128;
  __shared__ _Float16 As[128*64], Bs[128*64];
  const int tid = threadIdx.x;
  const int srow = tid >> 3, slot = tid & 7;
  const int wave = tid >> 6, lane = tid & 63;
  const int wm = wave >> 1, wn = wave & 1;
  const int lr = lane & 15, lk = lane >> 4;
  f32x4 acc[4][4] = {};
  for (int kt = 0; kt < 8; ++kt) {
    __syncthreads();
    #pragma unroll
    for (int i = 0; i < 4; ++i) {
      const int r = srow + 32*i;
      const int ss = slot ^ (r & 7);
      gload16(A + (size_t)(m0 + r)*512 + kt*64 + ss*8, &As[r*64 + slot*8]);
      gload16(Bm + (size_t)(n0 + r)*512 + kt*64 + ss*8, &Bs[r*64 + slot*8]);
    }
    __syncthreads();
    #pragma unroll
    for (int ks = 0; ks < 2; ++ks) {
      f16x8 af[4], bfr[4];
      #pragma unroll
      for (int mf = 0; mf < 4; ++mf) {
        const int r = wm*64 + mf*16 + lr;
        const int ch = (ks*4 + lk) ^ (r & 7);
        af[mf] = *(const f16x8*)&As[r*64 + ch*8];
      }
      #pragma unroll
      for (int nf = 0; nf < 4; ++nf) {
        const int n = wn*64 + nf*16 + lr;
        const int ch = (ks*4 + lk) ^ (n & 7);
        bfr[nf] = *(const f16x8*)&Bs[n*64 + ch*8];
      }
      #pragma unroll
      for (int mf = 0; mf < 4; ++mf)
        #pragma unroll
        for (int nf = 0; nf < 4; ++nf)
          acc[mf][nf] = __builtin_amdgcn_mfma_f32_16x16x32_f16(af[mf], bfr[nf], acc[mf][nf], 0, 0, 0);
    }
  }
  #pragma unroll
  for (int nf = 0; nf < 4; ++nf) {
    const int c = n0 + wn*64 + nf*16 + lr;
    const float b2m = bm2[c], b2r = br2[c];
    #pragma unroll
    for (int mf = 0; mf < 4; ++mf)
      #pragma unroll
      for (int v = 0; v < 4; ++v) {
        const int r = m0 + wm*64 + mf*16 + lk*4 + v;
        agg[(size_t)r*256 + c] = acc[mf][nf][v] + in_cnt[r]*b2m + out_cnt[r]*b2r;
      }
  }
}

// ---------------- node update: h = [h, agg] @ Wu + bu  (+ fp16 copy) ----------------
__global__ __launch_bounds__(256) void k_update(
    const float* __restrict__ h, const float* __restrict__ agg,
    const float* __restrict__ Wu, const float* __restrict__ bu,
    float* __restrict__ hn, _Float16* __restrict__ hbn)
{
  const int n0 = blockIdx.x * 8;
  const int j = threadIdx.x & 127, half = threadIdx.x >> 7;
  __shared__ float xs[8][3*D_];
  for (int idx = threadIdx.x; idx < 8*3*D_; idx += 256) {
    int t = idx / (3*D_), k = idx - t*(3*D_);
    xs[t][k] = (k < D_) ? h[(size_t)(n0 + t)*D_ + k]
                        : agg[(size_t)(n0 + t)*(2*D_) + (k - D_)];
  }
  __syncthreads();
  float acc[4];
  const float b0 = bu[j];
  #pragma unroll
  for (int t = 0; t < 4; ++t) acc[t] = b0;
  for (int k = 0; k < 3*D_; k += 4) {
    const float w0 = Wu[(size_t)(k+0)*D_ + j];
    const float w1 = Wu[(size_t)(k+1)*D_ + j];
    const float w2 = Wu[(size_t)(k+2)*D_ + j];
    const float w3 = Wu[(size_t)(k+3)*D_ + j];
    #pragma unroll
    for (int t = 0; t < 4; ++t) {
      const float4 xv = *reinterpret_cast<const float4*>(&xs[half*4 + t][k]);
      acc[t] = fmaf(xv.w, w3, fmaf(xv.z, w2, fmaf(xv.y, w1, fmaf(xv.x, w0, acc[t]))));
    }
  }
  #pragma unroll
  for (int t = 0; t < 4; ++t) {
    const int r = n0 + half*4 + t;
    hn[(size_t)r*D_ + j] = acc[t];
    hbn[(size_t)r*D_ + j] = (_Float16)acc[t];
  }
}

// ---------------- node target embeddings ----------------
__global__ __launch_bounds__(128) void k_node_emb(
    const float* __restrict__ h,
    const float* __restrict__ Wq1, const float* __restrict__ bq1,
    const float* __restrict__ Wq2, const float* __restrict__ bq2,
    float* __restrict__ tq_emb, float* __restrict__ tc_emb)
{
  const int bid = blockIdx.x;
  const int b = bid / (2*NMAX_), s = bid - b*(2*NMAX_);
  const bool isQ = s < NMAX_;
  const int r = isQ ? s : s - NMAX_;
  float* outp = (isQ ? tq_emb : tc_emb) + ((size_t)b*NMAX_ + r)*TD_;
  const int tid = threadIdx.x;
  if (isQ && r >= NQ_) {
    if (tid < TD_) outp[tid] = 0.f;
    return;
  }
  const int node = b*NPB_ + (isQ ? r : NQ_ + r);
  __shared__ float xs[D_];
  __shared__ float l1[TD_];
  xs[tid] = h[(size_t)node*D_ + tid];
  __syncthreads();
  if (tid < TD_) {
    float a = bq1[tid];
    for (int k = 0; k < D_; ++k) a = fmaf(xs[k], Wq1[(size_t)k*TD_ + tid], a);
    l1[tid] = fmaxf(a, 0.f);
  }
  __syncthreads();
  if (tid < TD_) {
    float a = bq2[tid];
    #pragma unroll
    for (int k = 0; k < TD_; ++k) a = fmaf(l1[k], Wq2[(size_t)k*TD_ + tid], a);
    outp[tid] = a;
  }
}

// ---------------- sinkhorn over 40x40 node plans ----------------
__global__ __launch_bounds__(256) void k_sinkhorn_n(
    const float* __restrict__ tq_emb, const float* __restrict__ tc_emb,
    float* __restrict__ plan_n)
{
  const int b = blockIdx.x, tid = threadIdx.x;
  __shared__ float la[NMAX_][NMAX_];
  __shared__ float qe[NMAX_][TD_], ce[NMAX_][TD_];
  for (int idx = tid; idx < NMAX_*TD_; idx += 256) {
    qe[idx / TD_][idx % TD_] = tq_emb[(size_t)b*NMAX_*TD_ + idx];
    ce[idx / TD_][idx % TD_] = tc_emb[(size_t)b*NMAX_*TD_ + idx];
  }
  __syncthreads();
  for (int idx = tid; idx < NMAX_*NMAX_; idx += 256) {
    int q = idx / NMAX_, c = idx - q*NMAX_;
    float a = 0.f;
    #pragma unroll
    for (int d = 0; d < TD_; ++d) a = fmaf(qe[q][d], ce[c][d], a);
    la[q][c] = a / TEMP_;
  }
  __syncthreads();
  for (int it = 0; it < ITERS_; ++it) {
    if (tid < NMAX_) {
      float m = -INFINITY;
      for (int c = 0; c < NMAX_; ++c) m = fmaxf(m, la[tid][c]);
      float s = 0.f;
      for (int c = 0; c < NMAX_; ++c) s += __expf(la[tid][c] - m);
      const float lse = m + __logf(s);
      for (int c = 0; c < NMAX_; ++c) la[tid][c] -= lse;
    }
    __syncthreads();
    if (tid < NMAX_) {
      float m = -INFINITY;
      for (int q = 0; q < NMAX_; ++q) m = fmaxf(m, la[q][tid]);
      float s = 0.f;
      for (int q = 0; q < NMAX_; ++q) s += __expf(la[q][tid] - m);
      const float lse = m + __logf(s);
      for (int q = 0; q < NMAX_; ++q) la[q][tid] -= lse;
    }
    __syncthreads();
  }
  for (int idx = tid; idx < NMAX_*NMAX_; idx += 256)
    plan_n[(size_t)b*NMAX_*NMAX_ + idx] = __expf(la[idx / NMAX_][idx % NMAX_]);
}

// ---------------- final edge embed, fully fused ----------------
// hidden[e] = relu(F[from]+T[to]+E[e]); l1 = relu(hidden@WceT^T + bce); te = l1@We2 + be2
__global__ __launch_bounds__(256) void k_edge_emb_f(
    const _Float16* __restrict__ FT, const _Float16* __restrict__ E,
    const int* __restrict__ from_idx, const int* __restrict__ to_idx,
    const float* __restrict__ WceT, const float* __restrict__ bce,
    const float* __restrict__ We2, const float* __restrict__ be2,
    float* __restrict__ teq, float* __restrict__ tec)
{
  const int e0 = blockIdx.x * 16;
  const int tid = threadIdx.x;
  __shared__ float es[16][516];
  __shared__ float l1s[16][TD_];
  __shared__ int sfrom[16], sto[16];
  if (tid < 16) { sfrom[tid] = from_idx[e0 + tid]; sto[tid] = to_idx[e0 + tid]; }
  __syncthreads();
  for (int idx = tid; idx < 16*512; idx += 256) {
    const int t = idx >> 9, k = idx & 511;
    es[t][k] = fmaxf((float)FT[(size_t)sfrom[t]*1024 + k]
                   + (float)FT[(size_t)sto[t]*1024 + 512 + k]
                   + (float)E[(size_t)(e0 + t)*512 + k], 0.f);
  }
  __syncthreads();
  const int t = tid >> 4, jj = tid & 15;
  float a = bce[jj];
  const float4* wrow = reinterpret_cast<const float4*>(WceT + (size_t)jj*512);
  const float4* xrow = reinterpret_cast<const float4*>(&es[t][0]);
  for (int k0 = 0; k0 < 128; ++k0) {
    const float4 wv = wrow[k0];
    const float4 xv = xrow[k0];
    a += xv.x*wv.x + xv.y*wv.y + xv.z*wv.z + xv.w*wv.w;
  }
  l1s[t][jj] = fmaxf(a, 0.f);
  __syncthreads();
  float a2 = be2[jj];
  #pragma unroll
  for (int k = 0; k < TD_; ++k) a2 = fmaf(l1s[t][k], We2[(size_t)k*TD_ + jj], a2);
  const int ei = e0 + t;
  const int bb = ei / EPB_, jl = ei - bb*EPB_;
  if (jl < EQ_) teq[((size_t)bb*EMAX_ + jl)*TD_ + jj] = a2;
  else          tec[((size_t)bb*EMAX_ + (jl - EQ_))*TD_ + jj] = a2;
}

// ---------------- fused: escore + sinkhorn_e (registers) + final score ----------------
// Thread (tr=t>>4, tcg=t&15) owns rows tr*4+{0..3}, cols {j*16+tcg : j<16}.
__global__ __launch_bounds__(1024) void k_plan_score(
    const float* __restrict__ teq, const float* __restrict__ tec,
    const float* __restrict__ plan_n,
    const float* __restrict__ tq_emb, const float* __restrict__ tc_emb,
    const int* __restrict__ fq, const int* __restrict__ tq,
    const int* __restrict__ fc, const int* __restrict__ tc,
    const float* __restrict__ Wa, const float* __restrict__ ba,
    float* __restrict__ out)
{
  const int b = blockIdx.x, t = threadIdx.x;
  const int tr = t >> 4, tcg = t & 15, lane = t & 63, w = t >> 6;

  __shared__ float sq[256*17];   // padded: conflict-free
  __shared__ float sc[256*17];
  __shared__ float wov[4096];    // wave partials; overlaid post-loop
  __shared__ float bcast[256];

  for (int idx = t; idx < 4096; idx += 1024) {
    const int r = idx >> 4, k = idx & 15;
    sq[r*17 + k] = teq[(size_t)b*4096 + idx];
    sc[r*17 + k] = tec[(size_t)b*4096 + idx];
  }
  __syncthreads();

  // ---- scores la[i][j] = 10 * dot(q=tr*4+i, c=j*16+tcg) ----
  float la[4][16];
  #pragma unroll
  for (int i = 0; i < 4; ++i)
    #pragma unroll
    for (int j = 0; j < 16; ++j) la[i][j] = 0.f;
  for (int k = 0; k < 16; ++k) {
    float qk[4];
    #pragma unroll
    for (int i = 0; i < 4; ++i) qk[i] = sq[(tr*4 + i)*17 + k];
    #pragma unroll
    for (int j = 0; j < 16; ++j) {
      const float sck = sc[(j*16 + tcg)*17 + k];
      #pragma unroll
      for (int i = 0; i < 4; ++i) la[i][j] = fmaf(qk[i], sck, la[i][j]);
    }
  }
  #pragma unroll
  for (int i = 0; i < 4; ++i)
    #pragma unroll
    for (int j = 0; j < 16; ++j) la[i][j] *= 10.0f;   // 1/TEMP

  for (int it = 0; it < ITERS_; ++it) {
    // row LSE (16 consecutive lanes per row)
    #pragma unroll
    for (int i = 0; i < 4; ++i) {
      float m = la[i][0];
      #pragma unroll
      for (int j = 1; j < 16; ++j) m = fmaxf(m, la[i][j]);
      m = fmaxf(m, __shfl_xor(m, 1)); m = fmaxf(m, __shfl_xor(m, 2));
      m = fmaxf(m, __shfl_xor(m, 4)); m = fmaxf(m, __shfl_xor(m, 8));
      float s = 0.f;
      #pragma unroll
      for (int j = 0; j < 16; ++j) s += __expf(la[i][j] - m);
      s += __shfl_xor(s, 1); s += __shfl_xor(s, 2);
      s += __shfl_xor(s, 4); s += __shfl_xor(s, 8);
      const float lse = m + __logf(s);
      #pragma unroll
      for (int j = 0; j < 16; ++j) la[i][j] -= lse;
    }
    // col max partials (per wave), wov[w*256 + c] with c=j*16+lane
    #pragma unroll
    for (int j = 0; j < 16; ++j) {
      float m = fmaxf(fmaxf(la[0][j], la[1][j]), fmaxf(la[2][j], la[3][j]));
      m = fmaxf(m, __shfl_xor(m, 16));
      m = fmaxf(m, __shfl_xor(m, 32));
      if (lane < 16) wov[w*256 + j*16 + lane] = m;
    }
    __syncthreads();
    if (t < 256) {
      float m = wov[t];
      #pragma unroll
      for (int ww = 1; ww < 16; ++ww) m = fmaxf(m, wov[ww*256 + t]);
      bcast[t] = m;
    }
    __syncthreads();
    // col sum partials
    #pragma unroll
    for (int j = 0; j < 16; ++j) {
      const float cm = bcast[j*16 + tcg];
      float s = __expf(la[0][j] - cm) + __expf(la[1][j] - cm)
              + __expf(la[2][j] - cm) + __expf(la[3][j] - cm);
      s += __shfl_xor(s, 16);
      s += __shfl_xor(s, 32);
      if (lane < 16) wov[w*256 + j*16 + lane] = s;
    }
    __syncthreads();
    if (t < 256) {
      float s = wov[t];
      #pragma unroll
      for (int ww = 1; ww < 16; ++ww) s += wov[ww*256 + t];
      bcast[t] += __logf(s);    // col lse
    }
    __syncthreads();
    #pragma unroll
    for (int j = 0; j < 16; ++j) {
      const float lse = bcast[j*16 + tcg];
      #pragma unroll
      for (int i = 0; i < 4; ++i) la[i][j] -= lse;
    }
    __syncthreads();
  }

  // ---- epilogue: overlay pn/qe/ce/indices into wov ----
  float* pn = wov;                 // 1600
  float* qe = wov + 1600;          // 640
  float* ce = wov + 2240;          // 640
  int*   ib = (int*)(wov + 2880);  // 800 ints
  int* sfq = ib, *stq = ib + 160, *sfc = ib + 320, *stc = ib + 560;
  for (int i = t; i < 1600; i += 1024) pn[i] = plan_n[(size_t)b*1600 + i];
  if (t < 640) { qe[t] = tq_emb[(size_t)b*640 + t]; ce[t] = tc_emb[(size_t)b*640 + t]; }
  if (t < 160) { sfq[t] = fq[b*160 + t]; stq[t] = tq[b*160 + t]; }
  if (t >= 512 && t < 752) { sfc[t-512] = fc[b*240 + (t-512)]; stc[t-512] = tc[b*240 + (t-512)]; }
  __syncthreads();

  float csum = 0.f;
  if (tr < 40) {                       // q = tr*4+i < 160
    #pragma unroll
    for (int i = 0; i < 4; ++i) {
      const int q = tr*4 + i;
      const int g0 = sfq[q]*NMAX_, g1 = stq[q]*NMAX_;
      #pragma unroll
      for (int j = 0; j < 15; ++j) {   // c = j*16+tcg < 240
        const int c = j*16 + tcg;
        const float pe = __expf(la[i][j]);
        const float a0 = pn[g0 + sfc[c]] * pn[g1 + stc[c]];
        const float a1 = pn[g0 + stc[c]] * pn[g1 + sfc[c]];
        csum += pe * fmaxf(a0, a1);
      }
    }
  }
  float hsum = 0.f;
  if (t < NMAX_*TD_) {
    const int q = t >> 4, d2 = t & 15;
    float a = 0.f;
    for (int c = 0; c < NMAX_; ++c) a = fmaf(pn[q*NMAX_ + c], ce[c*TD_ + d2], a);
    hsum = fmaxf(qe[t] - a, 0.f);
  }
  #pragma unroll
  for (int off = 32; off; off >>= 1) {
    csum += __shfl_xor(csum, off);
    hsum += __shfl_xor(hsum, off);
  }
  if (lane == 0) { bcast[w] = csum; bcast[32 + w] = hsum; }
  __syncthreads();
  if (t == 0) {
    float C = 0.f, H = 0.f;
    #pragma unroll
    for (int ww = 0; ww < 16; ++ww) { C += bcast[ww]; H += bcast[32 + ww]; }
    out[b] = (-H) * Wa[0] + C * Wa[1] + ba[0];
  }
}

// ---------------- host launcher ----------------
extern "C" void kernel_launch(void* const* d_in, const int* in_sizes, int n_in,
                              void* d_out, int out_size, void* d_ws, size_t ws_size,
                              hipStream_t stream) {
  const float* node_features = (const float*)d_in[0];
  const float* edge_features = (const float*)d_in[1];
  const float* Wn  = (const float*)d_in[2];
  const float* bn  = (const float*)d_in[3];
  const float* We  = (const float*)d_in[4];
  const float* be  = (const float*)d_in[5];
  const float* Wm1 = (const float*)d_in[6];
  const float* bm1 = (const float*)d_in[7];
  const float* Wm2 = (const float*)d_in[8];
  const float* bm2 = (const float*)d_in[9];
  const float* Wr1 = (const float*)d_in[10];
  const float* br1 = (const float*)d_in[11];
  const float* Wr2 = (const float*)d_in[12];
  const float* br2 = (const float*)d_in[13];
  const float* Wu  = (const float*)d_in[14];
  const float* bu  = (const float*)d_in[15];
  const float* Wq1 = (const float*)d_in[16];
  const float* bq1 = (const float*)d_in[17];
  const float* Wq2 = (const float*)d_in[18];
  const float* bq2 = (const float*)d_in[19];
  const float* We1 = (const float*)d_in[20];
  const float* be1 = (const float*)d_in[21];
  const float* We2 = (const float*)d_in[22];
  const float* be2 = (const float*)d_in[23];
  const float* Wa  = (const float*)d_in[24];
  const float* ba  = (const float*)d_in[25];
  const int* fq = (const int*)d_in[26];
  const int* tq = (const int*)d_in[27];
  const int* fc = (const int*)d_in[28];
  const int* tc = (const int*)d_in[29];
  (void)in_sizes; (void)n_in; (void)out_size; (void)ws_size;

  char* ws = (char*)d_ws;
  size_t off = 0;
  auto take = [&](size_t bytes) -> void* {
    void* p = ws + off;
    off = (off + bytes + 255) & ~(size_t)255;
    return p;
  };
  int*   from_idx = (int*)  take((size_t)ETOT_*4);
  int*   to_idx   = (int*)  take((size_t)ETOT_*4);
  int*   in_cnt   = (int*)  take((size_t)NTOT_*4);
  int*   out_cnt  = (int*)  take((size_t)NTOT_*4);
  int*   in_list  = (int*)  take((size_t)NTOT_*DEGCAP_*4);
  int*   out_list = (int*)  take((size_t)NTOT_*DEGCAP_*4);
  float* h0       = (float*)take((size_t)NTOT_*D_*4);
  float* h1       = (float*)take((size_t)NTOT_*D_*4);
  _Float16* hb    = (_Float16*)take((size_t)NTOT_*D_*2);
  _Float16* eb    = (_Float16*)take((size_t)ETOT_*D_*2);
  _Float16* FT    = (_Float16*)take((size_t)NTOT_*1024*2);
  _Float16* Ebuf  = (_Float16*)take((size_t)ETOT_*512*2);
  _Float16* Hsum  = (_Float16*)take((size_t)NTOT_*512*2);
  float* agg      = (float*)take((size_t)NTOT_*256*4);
  float* tq_emb   = (float*)take((size_t)B_*NMAX_*TD_*4);
  float* tc_emb   = (float*)take((size_t)B_*NMAX_*TD_*4);
  float* plan_n   = (float*)take((size_t)B_*NMAX_*NMAX_*4);
  float* teq      = (float*)take((size_t)B_*EMAX_*TD_*4);
  float* tec      = (float*)take((size_t)B_*EMAX_*TD_*4);
  _Float16* W1Tn  = (_Float16*)take((size_t)1024*128*2);
  _Float16* W1Te  = (_Float16*)take((size_t)512*128*2);
  _Float16* W2cT  = (_Float16*)take((size_t)256*512*2);
  float* bcat1    = (float*)take(512*4);
  float* WceT     = (float*)take((size_t)16*512*4);
  float* bce      = (float*)take(16*4);

  k_build_idx<<<(ETOT_ + 255)/256, 256, 0, stream>>>(fq, tq, fc, tc, from_idx, to_idx);
  k_build_lists<<<B_, 256, 0, stream>>>(fq, tq, fc, tc, in_cnt, in_list, out_cnt, out_list);
  k_prep_w<<<(1024*128 + 512*128 + 256*512 + 255)/256, 256, 0, stream>>>(
      Wm1, Wr1, Wm2, Wr2, bm1, br1, W1Tn, W1Te, W2cT, bcat1);
  k_prep_wce<<<32, 256, 0, stream>>>(Wm2, Wr2, We1, bm2, br2, be1, WceT, bce);
  k_node_enc<<<NTOT_, D_, 0, stream>>>(node_features, Wn, bn, h0, hb);
  k_edge_enc<<<ETOT_, D_, 0, stream>>>(edge_features, We, be, eb);

  dim3 gE(ETOT_/128, 4);
  k_gemm_E<<<gE, 256, 0, stream>>>(eb, W1Te, bcat1, Ebuf);

  dim3 gFT(NTOT_/128, 8);
  dim3 gAG(NTOT_/128, 2);
  float* hc = h0;
  float* hn = h1;
  for (int p = 0; p < NPROP_; ++p) {
    k_gemm_FT<<<gFT, 256, 0, stream>>>(hb, W1Tn, FT);
    k_agg_fused<<<NTOT_, 256, 0, stream>>>(FT, Ebuf, from_idx, to_idx,
                                           in_cnt, in_list, out_cnt, out_list, Hsum);
    k_gemm_agg<<<gAG, 256, 0, stream>>>(Hsum, W2cT, in_cnt, out_cnt, bm2, br2, agg);
    k_update<<<NTOT_/8, 256, 0, stream>>>(hc, agg, Wu, bu, hn, hb);
    float* t_ = hc; hc = hn; hn = t_;
  }

  k_node_emb<<<B_*2*NMAX_, D_, 0, stream>>>(hc, Wq1, bq1, Wq2, bq2, tq_emb, tc_emb);
  k_sinkhorn_n<<<B_, 256, 0, stream>>>(tq_emb, tc_emb, plan_n);

  // final edge pass: FT of final h, then fused edge-embed
  k_gemm_FT<<<gFT, 256, 0, stream>>>(hb, W1Tn, FT);
  hipMemsetAsync(teq, 0, (size_t)B_*EMAX_*TD_*4, stream);
  hipMemsetAsync(tec, 0, (size_t)B_*EMAX_*TD_*4, stream);
  k_edge_emb_f<<<ETOT_/16, 256, 0, stream>>>(FT, Ebuf, from_idx, to_idx,
                                             WceT, bce, We2, be2, teq, tec);

  k_plan_score<<<B_, 1024, 0, stream>>>(teq, tec, plan_n, tq_emb, tc_emb,
                                        fq, tq, fc, tc, Wa, ba, (float*)d_out);
}

// Round 7
// 991.432 us; speedup vs baseline: 6.8121x; 1.0476x over previous
//
#include <hip/hip_runtime.h>
#include <cstddef>
#include <cstdint>

// ---------------- problem constants ----------------
constexpr int B_    = 128;
constexpr int NQ_   = 32;
constexpr int NC_   = 40;
constexpr int NMAX_ = 40;
constexpr int EQ_   = 160;
constexpr int EC_   = 240;
constexpr int EMAX_ = 256;
constexpr int D_    = 128;
constexpr int TD_   = 16;
constexpr int NPROP_ = 5;
constexpr int ITERS_ = 20;
constexpr float TEMP_ = 0.1f;
constexpr int NF_   = 32;
constexpr int EF_   = 16;
constexpr int NPB_  = NQ_ + NC_;   // 72 nodes / batch
constexpr int EPB_  = EQ_ + EC_;   // 400 edges / batch
constexpr int NTOT_ = B_ * NPB_;   // 9216
constexpr int ETOT_ = B_ * EPB_;   // 51200
constexpr int DEGCAP_ = 64;
constexpr float L2E10_ = 14.4269504088896f;  // 10 * log2(e)

typedef _Float16 f16x8 __attribute__((ext_vector_type(8)));
typedef float f32x4 __attribute__((ext_vector_type(4)));

__device__ __forceinline__ void gload16(const void* g, void* l) {
  __builtin_amdgcn_global_load_lds(
      (const __attribute__((address_space(1))) unsigned int*)g,
      (__attribute__((address_space(3))) unsigned int*)l, 16, 0, 0);
}
__device__ __forceinline__ float ex2(float x) { return __builtin_amdgcn_exp2f(x); }
__device__ __forceinline__ float lg2(float x) { return __builtin_amdgcn_logf(x); }

// ---------------- index building ----------------
__global__ __launch_bounds__(256) void k_build_idx(
    const int* __restrict__ fq, const int* __restrict__ tq,
    const int* __restrict__ fc, const int* __restrict__ tc,
    int* __restrict__ from_idx, int* __restrict__ to_idx)
{
  int i = blockIdx.x * blockDim.x + threadIdx.x;
  if (i >= ETOT_) return;
  int b = i / EPB_, j = i - b * EPB_;
  int f, t;
  if (j < EQ_) {
    f = fq[b*EQ_ + j] + b*NPB_;
    t = tq[b*EQ_ + j] + b*NPB_;
  } else {
    int jj = j - EQ_;
    f = fc[b*EC_ + jj] + b*NPB_ + NQ_;
    t = tc[b*EC_ + jj] + b*NPB_ + NQ_;
  }
  from_idx[i] = f;
  to_idx[i]   = t;
}

// ---------------- per-node edge lists (deterministic ascending order) ----------------
__global__ __launch_bounds__(256) void k_build_lists(
    const int* __restrict__ fq, const int* __restrict__ tq,
    const int* __restrict__ fc, const int* __restrict__ tc,
    int* __restrict__ in_cnt, int* __restrict__ in_list,
    int* __restrict__ out_cnt, int* __restrict__ out_list)
{
  const int b = blockIdx.x, tid = threadIdx.x;
  __shared__ short sf[EPB_], st[EPB_];
  for (int j = tid; j < EPB_; j += 256) {
    int f, t;
    if (j < EQ_) { f = fq[b*EQ_ + j];              t = tq[b*EQ_ + j]; }
    else         { f = fc[b*EC_ + (j-EQ_)] + NQ_;  t = tc[b*EC_ + (j-EQ_)] + NQ_; }
    sf[j] = (short)f; st[j] = (short)t;
  }
  __syncthreads();
  if (tid < NPB_) {
    const int g = b*NPB_ + tid;
    int ic = 0, oc = 0;
    for (int j = 0; j < EPB_; ++j) {
      if ((int)st[j] == tid && ic < DEGCAP_) in_list[g*DEGCAP_ + (ic++)] = j;
      if ((int)sf[j] == tid && oc < DEGCAP_) out_list[g*DEGCAP_ + (oc++)] = j;
    }
    in_cnt[g] = ic; out_cnt[g] = oc;
  }
}

// ---------------- weight prep ----------------
__global__ __launch_bounds__(256) void k_prep_w(
    const float* __restrict__ Wm1, const float* __restrict__ Wr1,
    const float* __restrict__ Wm2, const float* __restrict__ Wr2,
    const float* __restrict__ bm1, const float* __restrict__ br1,
    _Float16* __restrict__ W1Tn, _Float16* __restrict__ W1Te,
    _Float16* __restrict__ W2cT, float* __restrict__ bcat1)
{
  int i = blockIdx.x * 256 + threadIdx.x;
  if (i < 1024*128) {
    int n = i >> 7, k = i & 127;
    float v;
    if (n < 512) {            // F-part: W1 row k
      v = (n < 256) ? Wm1[(size_t)k*256 + n]
                    : Wr1[(size_t)(k + 128)*256 + (n - 256)];
    } else {                  // T-part: W1 row 128+k
      int n2 = n - 512;
      v = (n2 < 256) ? Wm1[(size_t)(128 + k)*256 + n2]
                     : Wr1[(size_t)k*256 + (n2 - 256)];
    }
    W1Tn[i] = (_Float16)v;
  }
  int j = i - 1024*128;
  if (j >= 0 && j < 512*128) {
    int n = j >> 7, k = j & 127;   // W1 row 256+k
    float v = (n < 256) ? Wm1[(size_t)(256 + k)*256 + n]
                        : Wr1[(size_t)(256 + k)*256 + (n - 256)];
    W1Te[j] = (_Float16)v;
  }
  int l = i - 1024*128 - 512*128;
  if (l >= 0 && l < 256*512) {
    int n = l >> 9, k = l & 511;
    float v = (k < 256) ? Wm2[(size_t)k*256 + n] : Wr2[(size_t)(k-256)*256 + n];
    W2cT[l] = (_Float16)v;
  }
  if (i < 512) bcat1[i] = (i < 256) ? bm1[i] : br1[i - 256];
}

// WceT[16][512] = (W2cat @ We1)^T ; bce[16] = (bm2+br2)@We1 + be1
__global__ __launch_bounds__(256) void k_prep_wce(
    const float* __restrict__ Wm2, const float* __restrict__ Wr2,
    const float* __restrict__ We1, const float* __restrict__ bm2,
    const float* __restrict__ br2, const float* __restrict__ be1,
    float* __restrict__ WceT, float* __restrict__ bce)
{
  int i = blockIdx.x * 256 + threadIdx.x;
  if (i < 16*512) {
    int j = i >> 9, k = i & 511;
    float a = 0.f;
    for (int m = 0; m < 256; ++m) {
      const float w2 = (k < 256) ? Wm2[(size_t)k*256 + m] : Wr2[(size_t)(k-256)*256 + m];
      a = fmaf(w2, We1[(size_t)m*TD_ + j], a);
    }
    WceT[(size_t)j*512 + k] = a;
  }
  if (i < 16) {
    float a = be1[i];
    for (int m = 0; m < 256; ++m) a = fmaf(bm2[m] + br2[m], We1[(size_t)m*TD_ + i], a);
    bce[i] = a;
  }
}

// ---------------- encoders ----------------
__global__ __launch_bounds__(128) void k_node_enc(
    const float* __restrict__ nf, const float* __restrict__ Wn,
    const float* __restrict__ bn, float* __restrict__ h, _Float16* __restrict__ hb)
{
  int n = blockIdx.x, j = threadIdx.x;
  __shared__ float xs[NF_];
  if (j < NF_) xs[j] = nf[(size_t)n*NF_ + j];
  __syncthreads();
  float a = bn[j];
  #pragma unroll
  for (int k = 0; k < NF_; ++k) a = fmaf(xs[k], Wn[(size_t)k*D_ + j], a);
  h[(size_t)n*D_ + j] = a;
  hb[(size_t)n*D_ + j] = (_Float16)a;
}

__global__ __launch_bounds__(128) void k_edge_enc(
    const float* __restrict__ ef, const float* __restrict__ We,
    const float* __restrict__ be, _Float16* __restrict__ eb)
{
  int i = blockIdx.x, j = threadIdx.x;
  __shared__ float xs[EF_];
  if (j < EF_) xs[j] = ef[(size_t)i*EF_ + j];
  __syncthreads();
  float a = be[j];
  #pragma unroll
  for (int k = 0; k < EF_; ++k) a = fmaf(xs[k], We[(size_t)k*D_ + j], a);
  eb[(size_t)i*D_ + j] = (_Float16)a;
}

// ---------------- GEMM: FT = hb @ W1Tn  (M=9216, N=1024, K=128) ----------------
__global__ __launch_bounds__(256) void k_gemm_FT(
    const _Float16* __restrict__ A, const _Float16* __restrict__ Bm,
    _Float16* __restrict__ FT)
{
  const int m0 = blockIdx.x * 128, n0 = blockIdx.y * 128;
  __shared__ _Float16 As[128*64], Bs[128*64];
  const int tid = threadIdx.x;
  const int srow = tid >> 3, slot = tid & 7;
  const int wave = tid >> 6, lane = tid & 63;
  const int wm = wave >> 1, wn = wave & 1;
  const int lr = lane & 15, lk = lane >> 4;
  f32x4 acc[4][4] = {};
  for (int kt = 0; kt < 2; ++kt) {
    __syncthreads();
    #pragma unroll
    for (int i = 0; i < 4; ++i) {
      const int r = srow + 32*i;
      const int ss = slot ^ (r & 7);
      gload16(A + (size_t)(m0 + r)*128 + kt*64 + ss*8, &As[r*64 + slot*8]);
      gload16(Bm + (size_t)(n0 + r)*128 + kt*64 + ss*8, &Bs[r*64 + slot*8]);
    }
    __syncthreads();
    #pragma unroll
    for (int ks = 0; ks < 2; ++ks) {
      f16x8 af[4], bfr[4];
      #pragma unroll
      for (int mf = 0; mf < 4; ++mf) {
        const int r = wm*64 + mf*16 + lr;
        const int ch = (ks*4 + lk) ^ (r & 7);
        af[mf] = *(const f16x8*)&As[r*64 + ch*8];
      }
      #pragma unroll
      for (int nf = 0; nf < 4; ++nf) {
        const int n = wn*64 + nf*16 + lr;
        const int ch = (ks*4 + lk) ^ (n & 7);
        bfr[nf] = *(const f16x8*)&Bs[n*64 + ch*8];
      }
      #pragma unroll
      for (int mf = 0; mf < 4; ++mf)
        #pragma unroll
        for (int nf = 0; nf < 4; ++nf)
          acc[mf][nf] = __builtin_amdgcn_mfma_f32_16x16x32_f16(af[mf], bfr[nf], acc[mf][nf], 0, 0, 0);
    }
  }
  #pragma unroll
  for (int nf = 0; nf < 4; ++nf) {
    const int c = n0 + wn*64 + nf*16 + lr;
    #pragma unroll
    for (int mf = 0; mf < 4; ++mf)
      #pragma unroll
      for (int v = 0; v < 4; ++v) {
        const int r = m0 + wm*64 + mf*16 + lk*4 + v;
        FT[(size_t)r*1024 + c] = (_Float16)acc[mf][nf][v];
      }
  }
}

// ---------------- GEMM: E = eb @ W1Te + bcat1  (M=51200, N=512, K=128) ----------------
__global__ __launch_bounds__(256) void k_gemm_E(
    const _Float16* __restrict__ A, const _Float16* __restrict__ Bm,
    const float* __restrict__ bcat1, _Float16* __restrict__ E)
{
  const int m0 = blockIdx.x * 128, n0 = blockIdx.y * 128;
  __shared__ _Float16 As[128*64], Bs[128*64];
  const int tid = threadIdx.x;
  const int srow = tid >> 3, slot = tid & 7;
  const int wave = tid >> 6, lane = tid & 63;
  const int wm = wave >> 1, wn = wave & 1;
  const int lr = lane & 15, lk = lane >> 4;
  f32x4 acc[4][4] = {};
  for (int kt = 0; kt < 2; ++kt) {
    __syncthreads();
    #pragma unroll
    for (int i = 0; i < 4; ++i) {
      const int r = srow + 32*i;
      const int ss = slot ^ (r & 7);
      gload16(A + (size_t)(m0 + r)*128 + kt*64 + ss*8, &As[r*64 + slot*8]);
      gload16(Bm + (size_t)(n0 + r)*128 + kt*64 + ss*8, &Bs[r*64 + slot*8]);
    }
    __syncthreads();
    #pragma unroll
    for (int ks = 0; ks < 2; ++ks) {
      f16x8 af[4], bfr[4];
      #pragma unroll
      for (int mf = 0; mf < 4; ++mf) {
        const int r = wm*64 + mf*16 + lr;
        const int ch = (ks*4 + lk) ^ (r & 7);
        af[mf] = *(const f16x8*)&As[r*64 + ch*8];
      }
      #pragma unroll
      for (int nf = 0; nf < 4; ++nf) {
        const int n = wn*64 + nf*16 + lr;
        const int ch = (ks*4 + lk) ^ (n & 7);
        bfr[nf] = *(const f16x8*)&Bs[n*64 + ch*8];
      }
      #pragma unroll
      for (int mf = 0; mf < 4; ++mf)
        #pragma unroll
        for (int nf = 0; nf < 4; ++nf)
          acc[mf][nf] = __builtin_amdgcn_mfma_f32_16x16x32_f16(af[mf], bfr[nf], acc[mf][nf], 0, 0, 0);
    }
  }
  #pragma unroll
  for (int nf = 0; nf < 4; ++nf) {
    const int c = n0 + wn*64 + nf*16 + lr;
    const float bias = bcat1[c];
    #pragma unroll
    for (int mf = 0; mf < 4; ++mf)
      #pragma unroll
      for (int v = 0; v < 4; ++v) {
        const int r = m0 + wm*64 + mf*16 + lk*4 + v;
        E[(size_t)r*512 + c] = (_Float16)(acc[mf][nf][v] + bias);
      }
  }
}

// ---------------- fused hidden + deterministic segment-sum (1 wave/node, f16x8) ----------------
// lanes 0-31: in-part  (cols c8=lane*8 of [0,256)):  sum relu(F[src][c] + T[n][c] + E[ge][c])
// lanes 32-63: out-part (cols of [256,512)):         sum relu(F[n][256+c] + T[dst][768-512+c] ...)
__global__ __launch_bounds__(64) void k_agg_fused(
    const _Float16* __restrict__ FT, const _Float16* __restrict__ E,
    const int* __restrict__ from_idx, const int* __restrict__ to_idx,
    const int* __restrict__ in_cnt, const int* __restrict__ in_list,
    const int* __restrict__ out_cnt, const int* __restrict__ out_list,
    _Float16* __restrict__ Hsum)
{
  const int g = blockIdx.x;
  const int b = g / NPB_;
  const int lane = threadIdx.x;
  const int half = lane >> 5;          // 0 = in, 1 = out
  const int c8 = (lane & 31) * 8;      // element offset within 256
  const int ebase = b * EPB_;
  const size_t ftg = (size_t)g * 1024;

  const f16x8 base = (half == 0) ? *(const f16x8*)&FT[ftg + 512 + c8]    // T[n]
                                 : *(const f16x8*)&FT[ftg + 256 + c8];   // F[n] (r-part)
  const int cnt = (half == 0) ? in_cnt[g] : out_cnt[g];
  const int* lst = (half == 0) ? &in_list[(size_t)g*DEGCAP_] : &out_list[(size_t)g*DEGCAP_];
  const int eoff = half * 256;
  const int foff = (half == 0) ? 0 : 768;

  float acc[8] = {};
  for (int i = 0; i < cnt; ++i) {
    const int ge = ebase + lst[i];
    const int other = (half == 0) ? from_idx[ge] : to_idx[ge];
    const f16x8 fo = *(const f16x8*)&FT[(size_t)other*1024 + foff + c8];
    const f16x8 ev = *(const f16x8*)&E[(size_t)ge*512 + eoff + c8];
    #pragma unroll
    for (int k = 0; k < 8; ++k)
      acc[k] += fmaxf((float)base[k] + (float)fo[k] + (float)ev[k], 0.f);
  }
  f16x8 o;
  #pragma unroll
  for (int k = 0; k < 8; ++k) o[k] = (_Float16)acc[k];
  *(f16x8*)&Hsum[(size_t)g*512 + eoff + c8] = o;
}

// ---------------- GEMM: agg = Hsum @ W2cT + ic*bm2 + oc*br2  (M=9216, N=256, K=512) ----------------
__global__ __launch_bounds__(256) void k_gemm_agg(
    const _Float16* __restrict__ A, const _Float16* __restrict__ Bm,
    const int* __restrict__ in_cnt, const int* __restrict__ out_cnt,
    const float* __restrict__ bm2, const float* __restrict__ br2,
    float* __restrict__ agg)
{
  const int m0 = blockIdx.x * 128, n0 = blockIdx.y * 128;
  __shared__ _Float16 As[128*64], Bs[128*64];
  const int tid = threadIdx.x;
  const int srow = tid >> 3, slot = tid & 7;
  const int wave = tid >> 6, lane = tid & 63;
  const int wm = wave >> 1, wn = wave & 1;
  const int lr = lane & 15, lk = lane >> 4;
  f32x4 acc[4][4] = {};
  for (int kt = 0; kt < 8; ++kt) {
    __syncthreads();
    #pragma unroll
    for (int i = 0; i < 4; ++i) {
      const int r = srow + 32*i;
      const int ss = slot ^ (r & 7);
      gload16(A + (size_t)(m0 + r)*512 + kt*64 + ss*8, &As[r*64 + slot*8]);
      gload16(Bm + (size_t)(n0 + r)*512 + kt*64 + ss*8, &Bs[r*64 + slot*8]);
    }
    __syncthreads();
    #pragma unroll
    for (int ks = 0; ks < 2; ++ks) {
      f16x8 af[4], bfr[4];
      #pragma unroll
      for (int mf = 0; mf < 4; ++mf) {
        const int r = wm*64 + mf*16 + lr;
        const int ch = (ks*4 + lk) ^ (r & 7);
        af[mf] = *(const f16x8*)&As[r*64 + ch*8];
      }
      #pragma unroll
      for (int nf = 0; nf < 4; ++nf) {
        const int n = wn*64 + nf*16 + lr;
        const int ch = (ks*4 + lk) ^ (n & 7);
        bfr[nf] = *(const f16x8*)&Bs[n*64 + ch*8];
      }
      #pragma unroll
      for (int mf = 0; mf < 4; ++mf)
        #pragma unroll
        for (int nf = 0; nf < 4; ++nf)
          acc[mf][nf] = __builtin_amdgcn_mfma_f32_16x16x32_f16(af[mf], bfr[nf], acc[mf][nf], 0, 0, 0);
    }
  }
  #pragma unroll
  for (int nf = 0; nf < 4; ++nf) {
    const int c = n0 + wn*64 + nf*16 + lr;
    const float b2m = bm2[c], b2r = br2[c];
    #pragma unroll
    for (int mf = 0; mf < 4; ++mf)
      #pragma unroll
      for (int v = 0; v < 4; ++v) {
        const int r = m0 + wm*64 + mf*16 + lk*4 + v;
        agg[(size_t)r*256 + c] = acc[mf][nf][v] + in_cnt[r]*b2m + out_cnt[r]*b2r;
      }
  }
}

// ---------------- node update: h = [h, agg] @ Wu + bu  (+ fp16 copy) ----------------
__global__ __launch_bounds__(256) void k_update(
    const float* __restrict__ h, const float* __restrict__ agg,
    const float* __restrict__ Wu, const float* __restrict__ bu,
    float* __restrict__ hn, _Float16* __restrict__ hbn)
{
  const int n0 = blockIdx.x * 8;
  const int j = threadIdx.x & 127, half = threadIdx.x >> 7;
  __shared__ float xs[8][3*D_];
  for (int idx = threadIdx.x; idx < 8*3*D_; idx += 256) {
    int t = idx / (3*D_), k = idx - t*(3*D_);
    xs[t][k] = (k < D_) ? h[(size_t)(n0 + t)*D_ + k]
                        : agg[(size_t)(n0 + t)*(2*D_) + (k - D_)];
  }
  __syncthreads();
  float acc[4];
  const float b0 = bu[j];
  #pragma unroll
  for (int t = 0; t < 4; ++t) acc[t] = b0;
  for (int k = 0; k < 3*D_; k += 4) {
    const float w0 = Wu[(size_t)(k+0)*D_ + j];
    const float w1 = Wu[(size_t)(k+1)*D_ + j];
    const float w2 = Wu[(size_t)(k+2)*D_ + j];
    const float w3 = Wu[(size_t)(k+3)*D_ + j];
    #pragma unroll
    for (int t = 0; t < 4; ++t) {
      const float4 xv = *reinterpret_cast<const float4*>(&xs[half*4 + t][k]);
      acc[t] = fmaf(xv.w, w3, fmaf(xv.z, w2, fmaf(xv.y, w1, fmaf(xv.x, w0, acc[t]))));
    }
  }
  #pragma unroll
  for (int t = 0; t < 4; ++t) {
    const int r = n0 + half*4 + t;
    hn[(size_t)r*D_ + j] = acc[t];
    hbn[(size_t)r*D_ + j] = (_Float16)acc[t];
  }
}

// ---------------- node target embeddings ----------------
__global__ __launch_bounds__(128) void k_node_emb(
    const float* __restrict__ h,
    const float* __restrict__ Wq1, const float* __restrict__ bq1,
    const float* __restrict__ Wq2, const float* __restrict__ bq2,
    float* __restrict__ tq_emb, float* __restrict__ tc_emb)
{
  const int bid = blockIdx.x;
  const int b = bid / (2*NMAX_), s = bid - b*(2*NMAX_);
  const bool isQ = s < NMAX_;
  const int r = isQ ? s : s - NMAX_;
  float* outp = (isQ ? tq_emb : tc_emb) + ((size_t)b*NMAX_ + r)*TD_;
  const int tid = threadIdx.x;
  if (isQ && r >= NQ_) {
    if (tid < TD_) outp[tid] = 0.f;
    return;
  }
  const int node = b*NPB_ + (isQ ? r : NQ_ + r);
  __shared__ float xs[D_];
  __shared__ float l1[TD_];
  xs[tid] = h[(size_t)node*D_ + tid];
  __syncthreads();
  if (tid < TD_) {
    float a = bq1[tid];
    for (int k = 0; k < D_; ++k) a = fmaf(xs[k], Wq1[(size_t)k*TD_ + tid], a);
    l1[tid] = fmaxf(a, 0.f);
  }
  __syncthreads();
  if (tid < TD_) {
    float a = bq2[tid];
    #pragma unroll
    for (int k = 0; k < TD_; ++k) a = fmaf(l1[k], Wq2[(size_t)k*TD_ + tid], a);
    outp[tid] = a;
  }
}

// ---------------- sinkhorn over 40x40 node plans ----------------
__global__ __launch_bounds__(256) void k_sinkhorn_n(
    const float* __restrict__ tq_emb, const float* __restrict__ tc_emb,
    float* __restrict__ plan_n)
{
  const int b = blockIdx.x, tid = threadIdx.x;
  __shared__ float la[NMAX_][NMAX_];
  __shared__ float qe[NMAX_][TD_], ce[NMAX_][TD_];
  for (int idx = tid; idx < NMAX_*TD_; idx += 256) {
    qe[idx / TD_][idx % TD_] = tq_emb[(size_t)b*NMAX_*TD_ + idx];
    ce[idx / TD_][idx % TD_] = tc_emb[(size_t)b*NMAX_*TD_ + idx];
  }
  __syncthreads();
  for (int idx = tid; idx < NMAX_*NMAX_; idx += 256) {
    int q = idx / NMAX_, c = idx - q*NMAX_;
    float a = 0.f;
    #pragma unroll
    for (int d = 0; d < TD_; ++d) a = fmaf(qe[q][d], ce[c][d], a);
    la[q][c] = a * L2E10_;
  }
  __syncthreads();
  for (int it = 0; it < ITERS_; ++it) {
    if (tid < NMAX_) {
      float m = -INFINITY;
      for (int c = 0; c < NMAX_; ++c) m = fmaxf(m, la[tid][c]);
      float s = 0.f;
      for (int c = 0; c < NMAX_; ++c) s += ex2(la[tid][c] - m);
      const float lse = m + lg2(s);
      for (int c = 0; c < NMAX_; ++c) la[tid][c] -= lse;
    }
    __syncthreads();
    if (tid < NMAX_) {
      float m = -INFINITY;
      for (int q = 0; q < NMAX_; ++q) m = fmaxf(m, la[q][tid]);
      float s = 0.f;
      for (int q = 0; q < NMAX_; ++q) s += ex2(la[q][tid] - m);
      const float lse = m + lg2(s);
      for (int q = 0; q < NMAX_; ++q) la[q][tid] -= lse;
    }
    __syncthreads();
  }
  for (int idx = tid; idx < NMAX_*NMAX_; idx += 256)
    plan_n[(size_t)b*NMAX_*NMAX_ + idx] = ex2(la[idx / NMAX_][idx % NMAX_]);
}

// ---------------- final edge embed, fully fused (vectorized staging) ----------------
__global__ __launch_bounds__(256) void k_edge_emb_f(
    const _Float16* __restrict__ FT, const _Float16* __restrict__ E,
    const int* __restrict__ from_idx, const int* __restrict__ to_idx,
    const float* __restrict__ WceT, const float* __restrict__ bce,
    const float* __restrict__ We2, const float* __restrict__ be2,
    float* __restrict__ teq, float* __restrict__ tec)
{
  const int e0 = blockIdx.x * 16;
  const int tid = threadIdx.x;
  __shared__ float es[16][516];
  __shared__ float l1s[16][TD_];
  __shared__ int sfrom[16], sto[16];
  if (tid < 16) { sfrom[tid] = from_idx[e0 + tid]; sto[tid] = to_idx[e0 + tid]; }
  __syncthreads();
  // 16 edges x 64 chunks of 8: f16x8 loads
  for (int idx = tid; idx < 16*64; idx += 256) {
    const int t = idx >> 6, k8 = (idx & 63) * 8;
    const f16x8 fa = *(const f16x8*)&FT[(size_t)sfrom[t]*1024 + k8];
    const f16x8 fb = *(const f16x8*)&FT[(size_t)sto[t]*1024 + 512 + k8];
    const f16x8 ev = *(const f16x8*)&E[(size_t)(e0 + t)*512 + k8];
    float4 o0, o1;
    o0.x = fmaxf((float)fa[0]+(float)fb[0]+(float)ev[0], 0.f);
    o0.y = fmaxf((float)fa[1]+(float)fb[1]+(float)ev[1], 0.f);
    o0.z = fmaxf((float)fa[2]+(float)fb[2]+(float)ev[2], 0.f);
    o0.w = fmaxf((float)fa[3]+(float)fb[3]+(float)ev[3], 0.f);
    o1.x = fmaxf((float)fa[4]+(float)fb[4]+(float)ev[4], 0.f);
    o1.y = fmaxf((float)fa[5]+(float)fb[5]+(float)ev[5], 0.f);
    o1.z = fmaxf((float)fa[6]+(float)fb[6]+(float)ev[6], 0.f);
    o1.w = fmaxf((float)fa[7]+(float)fb[7]+(float)ev[7], 0.f);
    *reinterpret_cast<float4*>(&es[t][k8])     = o0;
    *reinterpret_cast<float4*>(&es[t][k8 + 4]) = o1;
  }
  __syncthreads();
  const int t = tid >> 4, jj = tid & 15;
  float a0 = bce[jj], a1 = 0.f, a2 = 0.f, a3 = 0.f;
  const float4* wrow = reinterpret_cast<const float4*>(WceT + (size_t)jj*512);
  const float4* xrow = reinterpret_cast<const float4*>(&es[t][0]);
  #pragma unroll 8
  for (int k0 = 0; k0 < 128; k0 += 4) {
    const float4 w0 = wrow[k0],   x0 = xrow[k0];
    const float4 w1 = wrow[k0+1], x1 = xrow[k0+1];
    const float4 w2 = wrow[k0+2], x2 = xrow[k0+2];
    const float4 w3 = wrow[k0+3], x3 = xrow[k0+3];
    a0 += x0.x*w0.x + x0.y*w0.y + x0.z*w0.z + x0.w*w0.w;
    a1 += x1.x*w1.x + x1.y*w1.y + x1.z*w1.z + x1.w*w1.w;
    a2 += x2.x*w2.x + x2.y*w2.y + x2.z*w2.z + x2.w*w2.w;
    a3 += x3.x*w3.x + x3.y*w3.y + x3.z*w3.z + x3.w*w3.w;
  }
  l1s[t][jj] = fmaxf((a0 + a1) + (a2 + a3), 0.f);
  __syncthreads();
  float a2f = be2[jj];
  #pragma unroll
  for (int k = 0; k < TD_; ++k) a2f = fmaf(l1s[t][k], We2[(size_t)k*TD_ + jj], a2f);
  const int ei = e0 + t;
  const int bb = ei / EPB_, jl = ei - bb*EPB_;
  if (jl < EQ_) teq[((size_t)bb*EMAX_ + jl)*TD_ + jj] = a2f;
  else          tec[((size_t)bb*EMAX_ + (jl - EQ_))*TD_ + jj] = a2f;
}

// ---------------- fused: escore + sinkhorn_e (registers, base-2) + final score ----------------
// Thread (tr=t>>4, tcg=t&15) owns rows tr*4+{0..3}, cols {j*16+tcg : j<16}.
__global__ __launch_bounds__(1024) void k_plan_score(
    const float* __restrict__ teq, const float* __restrict__ tec,
    const float* __restrict__ plan_n,
    const float* __restrict__ tq_emb, const float* __restrict__ tc_emb,
    const int* __restrict__ fq, const int* __restrict__ tq,
    const int* __restrict__ fc, const int* __restrict__ tc,
    const float* __restrict__ Wa, const float* __restrict__ ba,
    float* __restrict__ out)
{
  const int b = blockIdx.x, t = threadIdx.x;
  const int tr = t >> 4, tcg = t & 15, lane = t & 63, w = t >> 6;

  __shared__ float shm[8704];    // overlay: {sq,sc} | {wovm,wovs} | epilogue tables
  __shared__ float bcast[256];

  // ---- load embeddings (sq/sc padded 17) ----
  {
    float* sq = shm;             // 256*17
    float* sc = shm + 4352;      // 256*17
    for (int idx = t; idx < 4096; idx += 1024) {
      const int r = idx >> 4, k = idx & 15;
      sq[r*17 + k] = teq[(size_t)b*4096 + idx];
      sc[r*17 + k] = tec[(size_t)b*4096 + idx];
    }
  }
  __syncthreads();

  // ---- scores la[i][j] = (10*log2 e) * dot(q=tr*4+i, c=j*16+tcg) ----
  float la[4][16];
  {
    const float* sq = shm;
    const float* sc = shm + 4352;
    #pragma unroll
    for (int i = 0; i < 4; ++i)
      #pragma unroll
      for (int j = 0; j < 16; ++j) la[i][j] = 0.f;
    for (int k = 0; k < 16; ++k) {
      float qk[4];
      #pragma unroll
      for (int i = 0; i < 4; ++i) qk[i] = sq[(tr*4 + i)*17 + k];
      #pragma unroll
      for (int j = 0; j < 16; ++j) {
        const float sck = sc[(j*16 + tcg)*17 + k];
        #pragma unroll
        for (int i = 0; i < 4; ++i) la[i][j] = fmaf(qk[i], sck, la[i][j]);
      }
    }
    #pragma unroll
    for (int i = 0; i < 4; ++i)
      #pragma unroll
      for (int j = 0; j < 16; ++j) la[i][j] *= L2E10_;
  }
  __syncthreads();   // sq/sc dead; shm reused as wovm/wovs

  float* wovm = shm;           // 4096
  float* wovs = shm + 4096;    // 4096

  for (int it = 0; it < ITERS_; ++it) {
    // ---- row LSE (16 consecutive lanes per row, base-2) ----
    #pragma unroll
    for (int i = 0; i < 4; ++i) {
      float m = la[i][0];
      #pragma unroll
      for (int j = 1; j < 16; ++j) m = fmaxf(m, la[i][j]);
      m = fmaxf(m, __shfl_xor(m, 1)); m = fmaxf(m, __shfl_xor(m, 2));
      m = fmaxf(m, __shfl_xor(m, 4)); m = fmaxf(m, __shfl_xor(m, 8));
      float s = 0.f;
      #pragma unroll
      for (int j = 0; j < 16; ++j) s += ex2(la[i][j] - m);
      s += __shfl_xor(s, 1); s += __shfl_xor(s, 2);
      s += __shfl_xor(s, 4); s += __shfl_xor(s, 8);
      const float lse = m + lg2(s);
      #pragma unroll
      for (int j = 0; j < 16; ++j) la[i][j] -= lse;
    }
    // ---- col (max,sum) partial per wave: one pass over la ----
    #pragma unroll
    for (int j = 0; j < 16; ++j) {
      float m = fmaxf(fmaxf(la[0][j], la[1][j]), fmaxf(la[2][j], la[3][j]));
      m = fmaxf(m, __shfl_xor(m, 16));
      m = fmaxf(m, __shfl_xor(m, 32));
      float s = ex2(la[0][j] - m) + ex2(la[1][j] - m)
              + ex2(la[2][j] - m) + ex2(la[3][j] - m);
      s += __shfl_xor(s, 16);
      s += __shfl_xor(s, 32);
      if (lane < 16) { wovm[w*256 + j*16 + lane] = m; wovs[w*256 + j*16 + lane] = s; }
    }
    __syncthreads();
    if (t < 256) {
      float M = wovm[t];
      #pragma unroll
      for (int ww = 1; ww < 16; ++ww) M = fmaxf(M, wovm[ww*256 + t]);
      float S = 0.f;
      #pragma unroll
      for (int ww = 0; ww < 16; ++ww) S += wovs[ww*256 + t] * ex2(wovm[ww*256 + t] - M);
      bcast[t] = M + lg2(S);
    }
    __syncthreads();
    #pragma unroll
    for (int j = 0; j < 16; ++j) {
      const float lse = bcast[j*16 + tcg];
      #pragma unroll
      for (int i = 0; i < 4; ++i) la[i][j] -= lse;
    }
  }
  __syncthreads();

  // ---- epilogue: overlay pn/qe/ce/indices into shm ----
  float* pn = shm;                 // 1600
  float* qe = shm + 1600;          // 640
  float* ce = shm + 2240;          // 640
  int*   ib = (int*)(shm + 2880);  // 800 ints
  int* sfq = ib, *stq = ib + 160, *sfc = ib + 320, *stc = ib + 560;
  for (int i = t; i < 1600; i += 1024) pn[i] = plan_n[(size_t)b*1600 + i];
  if (t < 640) { qe[t] = tq_emb[(size_t)b*640 + t]; ce[t] = tc_emb[(size_t)b*640 + t]; }
  if (t < 160) { sfq[t] = fq[b*160 + t]; stq[t] = tq[b*160 + t]; }
  if (t >= 512 && t < 752) { sfc[t-512] = fc[b*240 + (t-512)]; stc[t-512] = tc[b*240 + (t-512)]; }
  __syncthreads();

  float csum = 0.f;
  if (tr < 40) {                       // q = tr*4+i < 160
    #pragma unroll
    for (int i = 0; i < 4; ++i) {
      const int q = tr*4 + i;
      const int g0 = sfq[q]*NMAX_, g1 = stq[q]*NMAX_;
      #pragma unroll
      for (int j = 0; j < 15; ++j) {   // c = j*16+tcg < 240
        const int c = j*16 + tcg;
        const float pe = ex2(la[i][j]);
        const float a0 = pn[g0 + sfc[c]] * pn[g1 + stc[c]];
        const float a1 = pn[g0 + stc[c]] * pn[g1 + sfc[c]];
        csum += pe * fmaxf(a0, a1);
      }
    }
  }
  float hsum = 0.f;
  if (t < NMAX_*TD_) {
    const int q = t >> 4, d2 = t & 15;
    float a = 0.f;
    for (int c = 0; c < NMAX_; ++c) a = fmaf(pn[q*NMAX_ + c], ce[c*TD_ + d2], a);
    hsum = fmaxf(qe[t] - a, 0.f);
  }
  #pragma unroll
  for (int off = 32; off; off >>= 1) {
    csum += __shfl_xor(csum, off);
    hsum += __shfl_xor(hsum, off);
  }
  if (lane == 0) { bcast[w] = csum; bcast[32 + w] = hsum; }
  __syncthreads();
  if (t == 0) {
    float C = 0.f, H = 0.f;
    #pragma unroll
    for (int ww = 0; ww < 16; ++ww) { C += bcast[ww]; H += bcast[32 + ww]; }
    out[b] = (-H) * Wa[0] + C * Wa[1] + ba[0];
  }
}

// ---------------- host launcher ----------------
extern "C" void kernel_launch(void* const* d_in, const int* in_sizes, int n_in,
                              void* d_out, int out_size, void* d_ws, size_t ws_size,
                              hipStream_t stream) {
  const float* node_features = (const float*)d_in[0];
  const float* edge_features = (const float*)d_in[1];
  const float* Wn  = (const float*)d_in[2];
  const float* bn  = (const float*)d_in[3];
  const float* We  = (const float*)d_in[4];
  const float* be  = (const float*)d_in[5];
  const float* Wm1 = (const float*)d_in[6];
  const float* bm1 = (const float*)d_in[7];
  const float* Wm2 = (const float*)d_in[8];
  const float* bm2 = (const float*)d_in[9];
  const float* Wr1 = (const float*)d_in[10];
  const float* br1 = (const float*)d_in[11];
  const float* Wr2 = (const float*)d_in[12];
  const float* br2 = (const float*)d_in[13];
  const float* Wu  = (const float*)d_in[14];
  const float* bu  = (const float*)d_in[15];
  const float* Wq1 = (const float*)d_in[16];
  const float* bq1 = (const float*)d_in[17];
  const float* Wq2 = (const float*)d_in[18];
  const float* bq2 = (const float*)d_in[19];
  const float* We1 = (const float*)d_in[20];
  const float* be1 = (const float*)d_in[21];
  const float* We2 = (const float*)d_in[22];
  const float* be2 = (const float*)d_in[23];
  const float* Wa  = (const float*)d_in[24];
  const float* ba  = (const float*)d_in[25];
  const int* fq = (const int*)d_in[26];
  const int* tq = (const int*)d_in[27];
  const int* fc = (const int*)d_in[28];
  const int* tc = (const int*)d_in[29];
  (void)in_sizes; (void)n_in; (void)out_size; (void)ws_size;

  char* ws = (char*)d_ws;
  size_t off = 0;
  auto take = [&](size_t bytes) -> void* {
    void* p = ws + off;
    off = (off + bytes + 255) & ~(size_t)255;
    return p;
  };
  int*   from_idx = (int*)  take((size_t)ETOT_*4);
  int*   to_idx   = (int*)  take((size_t)ETOT_*4);
  int*   in_cnt   = (int*)  take((size_t)NTOT_*4);
  int*   out_cnt  = (int*)  take((size_t)NTOT_*4);
  int*   in_list  = (int*)  take((size_t)NTOT_*DEGCAP_*4);
  int*   out_list = (int*)  take((size_t)NTOT_*DEGCAP_*4);
  float* h0       = (float*)take((size_t)NTOT_*D_*4);
  float* h1       = (float*)take((size_t)NTOT_*D_*4);
  _Float16* hb    = (_Float16*)take((size_t)NTOT_*D_*2);
  _Float16* eb    = (_Float16*)take((size_t)ETOT_*D_*2);
  _Float16* FT    = (_Float16*)take((size_t)NTOT_*1024*2);
  _Float16* Ebuf  = (_Float16*)take((size_t)ETOT_*512*2);
  _Float16* Hsum  = (_Float16*)take((size_t)NTOT_*512*2);
  float* agg      = (float*)take((size_t)NTOT_*256*4);
  float* tq_emb   = (float*)take((size_t)B_*NMAX_*TD_*4);
  float* tc_emb   = (float*)take((size_t)B_*NMAX_*TD_*4);
  float* plan_n   = (float*)take((size_t)B_*NMAX_*NMAX_*4);
  float* teq      = (float*)take((size_t)B_*EMAX_*TD_*4);
  float* tec      = (float*)take((size_t)B_*EMAX_*TD_*4);
  _Float16* W1Tn  = (_Float16*)take((size_t)1024*128*2);
  _Float16* W1Te  = (_Float16*)take((size_t)512*128*2);
  _Float16* W2cT  = (_Float16*)take((size_t)256*512*2);
  float* bcat1    = (float*)take(512*4);
  float* WceT     = (float*)take((size_t)16*512*4);
  float* bce      = (float*)take(16*4);

  k_build_idx<<<(ETOT_ + 255)/256, 256, 0, stream>>>(fq, tq, fc, tc, from_idx, to_idx);
  k_build_lists<<<B_, 256, 0, stream>>>(fq, tq, fc, tc, in_cnt, in_list, out_cnt, out_list);
  k_prep_w<<<(1024*128 + 512*128 + 256*512 + 255)/256, 256, 0, stream>>>(
      Wm1, Wr1, Wm2, Wr2, bm1, br1, W1Tn, W1Te, W2cT, bcat1);
  k_prep_wce<<<32, 256, 0, stream>>>(Wm2, Wr2, We1, bm2, br2, be1, WceT, bce);
  k_node_enc<<<NTOT_, D_, 0, stream>>>(node_features, Wn, bn, h0, hb);
  k_edge_enc<<<ETOT_, D_, 0, stream>>>(edge_features, We, be, eb);

  dim3 gE(ETOT_/128, 4);
  k_gemm_E<<<gE, 256, 0, stream>>>(eb, W1Te, bcat1, Ebuf);

  dim3 gFT(NTOT_/128, 8);
  dim3 gAG(NTOT_/128, 2);
  float* hc = h0;
  float* hn = h1;
  for (int p = 0; p < NPROP_; ++p) {
    k_gemm_FT<<<gFT, 256, 0, stream>>>(hb, W1Tn, FT);
    k_agg_fused<<<NTOT_, 64, 0, stream>>>(FT, Ebuf, from_idx, to_idx,
                                          in_cnt, in_list, out_cnt, out_list, Hsum);
    k_gemm_agg<<<gAG, 256, 0, stream>>>(Hsum, W2cT, in_cnt, out_cnt, bm2, br2, agg);
    k_update<<<NTOT_/8, 256, 0, stream>>>(hc, agg, Wu, bu, hn, hb);
    float* t_ = hc; hc = hn; hn = t_;
  }

  k_node_emb<<<B_*2*NMAX_, D_, 0, stream>>>(hc, Wq1, bq1, Wq2, bq2, tq_emb, tc_emb);
  k_sinkhorn_n<<<B_, 256, 0, stream>>>(tq_emb, tc_emb, plan_n);

  // final edge pass: FT of final h, then fused edge-embed
  k_gemm_FT<<<gFT, 256, 0, stream>>>(hb, W1Tn, FT);
  hipMemsetAsync(teq, 0, (size_t)B_*EMAX_*TD_*4, stream);
  hipMemsetAsync(tec, 0, (size_t)B_*EMAX_*TD_*4, stream);
  k_edge_emb_f<<<ETOT_/16, 256, 0, stream>>>(FT, Ebuf, from_idx, to_idx,
                                             WceT, bce, We2, be2, teq, tec);

  k_plan_score<<<B_, 1024, 0, stream>>>(teq, tec, plan_n, tq_emb, tc_emb,
                                        fq, tq, fc, tc, Wa, ba, (float*)d_out);
}

// Round 8
// 989.823 us; speedup vs baseline: 6.8232x; 1.0016x over previous
//
#include <hip/hip_runtime.h>
#include <cstddef>
#include <cstdint>

// ---------------- problem constants ----------------
constexpr int B_    = 128;
constexpr int NQ_   = 32;
constexpr int NC_   = 40;
constexpr int NMAX_ = 40;
constexpr int EQ_   = 160;
constexpr int EC_   = 240;
constexpr int EMAX_ = 256;
constexpr int D_    = 128;
constexpr int TD_   = 16;
constexpr int NPROP_ = 5;
constexpr int ITERS_ = 20;
constexpr float TEMP_ = 0.1f;
constexpr int NF_   = 32;
constexpr int EF_   = 16;
constexpr int NPB_  = NQ_ + NC_;   // 72 nodes / batch
constexpr int EPB_  = EQ_ + EC_;   // 400 edges / batch
constexpr int NTOT_ = B_ * NPB_;   // 9216
constexpr int ETOT_ = B_ * EPB_;   // 51200
constexpr int DEGCAP_ = 64;
constexpr float L2E10_ = 14.4269504088896f;  // 10 * log2(e)

typedef _Float16 f16x8 __attribute__((ext_vector_type(8)));
typedef _Float16 f16x4 __attribute__((ext_vector_type(4)));
typedef float f32x4 __attribute__((ext_vector_type(4)));

__device__ __forceinline__ void gload16(const void* g, void* l) {
  __builtin_amdgcn_global_load_lds(
      (const __attribute__((address_space(1))) unsigned int*)g,
      (__attribute__((address_space(3))) unsigned int*)l, 16, 0, 0);
}
__device__ __forceinline__ float ex2(float x) { return __builtin_amdgcn_exp2f(x); }
__device__ __forceinline__ float lg2(float x) { return __builtin_amdgcn_logf(x); }

// ---------------- index building ----------------
__global__ __launch_bounds__(256) void k_build_idx(
    const int* __restrict__ fq, const int* __restrict__ tq,
    const int* __restrict__ fc, const int* __restrict__ tc,
    int* __restrict__ from_idx, int* __restrict__ to_idx)
{
  int i = blockIdx.x * blockDim.x + threadIdx.x;
  if (i >= ETOT_) return;
  int b = i / EPB_, j = i - b * EPB_;
  int f, t;
  if (j < EQ_) {
    f = fq[b*EQ_ + j] + b*NPB_;
    t = tq[b*EQ_ + j] + b*NPB_;
  } else {
    int jj = j - EQ_;
    f = fc[b*EC_ + jj] + b*NPB_ + NQ_;
    t = tc[b*EC_ + jj] + b*NPB_ + NQ_;
  }
  from_idx[i] = f;
  to_idx[i]   = t;
}

// ---------------- per-node edge lists (deterministic ascending order) ----------------
__global__ __launch_bounds__(256) void k_build_lists(
    const int* __restrict__ fq, const int* __restrict__ tq,
    const int* __restrict__ fc, const int* __restrict__ tc,
    int* __restrict__ in_cnt, int* __restrict__ in_list,
    int* __restrict__ out_cnt, int* __restrict__ out_list)
{
  const int b = blockIdx.x, tid = threadIdx.x;
  __shared__ short sf[EPB_], st[EPB_];
  for (int j = tid; j < EPB_; j += 256) {
    int f, t;
    if (j < EQ_) { f = fq[b*EQ_ + j];              t = tq[b*EQ_ + j]; }
    else         { f = fc[b*EC_ + (j-EQ_)] + NQ_;  t = tc[b*EC_ + (j-EQ_)] + NQ_; }
    sf[j] = (short)f; st[j] = (short)t;
  }
  __syncthreads();
  if (tid < NPB_) {
    const int g = b*NPB_ + tid;
    int ic = 0, oc = 0;
    for (int j = 0; j < EPB_; ++j) {
      if ((int)st[j] == tid && ic < DEGCAP_) in_list[g*DEGCAP_ + (ic++)] = j;
      if ((int)sf[j] == tid && oc < DEGCAP_) out_list[g*DEGCAP_ + (oc++)] = j;
    }
    in_cnt[g] = ic; out_cnt[g] = oc;
  }
}

// ---------------- weight prep ----------------
__global__ __launch_bounds__(256) void k_prep_w(
    const float* __restrict__ Wm1, const float* __restrict__ Wr1,
    const float* __restrict__ Wm2, const float* __restrict__ Wr2,
    const float* __restrict__ bm1, const float* __restrict__ br1,
    _Float16* __restrict__ W1Tn, _Float16* __restrict__ W1Te,
    _Float16* __restrict__ W2cT, float* __restrict__ bcat1)
{
  int i = blockIdx.x * 256 + threadIdx.x;
  if (i < 1024*128) {
    int n = i >> 7, k = i & 127;
    float v;
    if (n < 512) {            // F-part: W1 row k
      v = (n < 256) ? Wm1[(size_t)k*256 + n]
                    : Wr1[(size_t)(k + 128)*256 + (n - 256)];
    } else {                  // T-part: W1 row 128+k
      int n2 = n - 512;
      v = (n2 < 256) ? Wm1[(size_t)(128 + k)*256 + n2]
                     : Wr1[(size_t)k*256 + (n2 - 256)];
    }
    W1Tn[i] = (_Float16)v;
  }
  int j = i - 1024*128;
  if (j >= 0 && j < 512*128) {
    int n = j >> 7, k = j & 127;   // W1 row 256+k
    float v = (n < 256) ? Wm1[(size_t)(256 + k)*256 + n]
                        : Wr1[(size_t)(256 + k)*256 + (n - 256)];
    W1Te[j] = (_Float16)v;
  }
  int l = i - 1024*128 - 512*128;
  if (l >= 0 && l < 256*512) {
    int n = l >> 9, k = l & 511;
    float v = (k < 256) ? Wm2[(size_t)k*256 + n] : Wr2[(size_t)(k-256)*256 + n];
    W2cT[l] = (_Float16)v;
  }
  if (i < 512) bcat1[i] = (i < 256) ? bm1[i] : br1[i - 256];
}

// WceT[16][512] = (W2cat @ We1)^T ; bce[16] = (bm2+br2)@We1 + be1
__global__ __launch_bounds__(256) void k_prep_wce(
    const float* __restrict__ Wm2, const float* __restrict__ Wr2,
    const float* __restrict__ We1, const float* __restrict__ bm2,
    const float* __restrict__ br2, const float* __restrict__ be1,
    float* __restrict__ WceT, float* __restrict__ bce)
{
  int i = blockIdx.x * 256 + threadIdx.x;
  if (i < 16*512) {
    int j = i >> 9, k = i & 511;
    float a = 0.f;
    for (int m = 0; m < 256; ++m) {
      const float w2 = (k < 256) ? Wm2[(size_t)k*256 + m] : Wr2[(size_t)(k-256)*256 + m];
      a = fmaf(w2, We1[(size_t)m*TD_ + j], a);
    }
    WceT[(size_t)j*512 + k] = a;
  }
  if (i < 16) {
    float a = be1[i];
    for (int m = 0; m < 256; ++m) a = fmaf(bm2[m] + br2[m], We1[(size_t)m*TD_ + i], a);
    bce[i] = a;
  }
}

// ---------------- encoders ----------------
__global__ __launch_bounds__(128) void k_node_enc(
    const float* __restrict__ nf, const float* __restrict__ Wn,
    const float* __restrict__ bn, float* __restrict__ h, _Float16* __restrict__ hb)
{
  int n = blockIdx.x, j = threadIdx.x;
  __shared__ float xs[NF_];
  if (j < NF_) xs[j] = nf[(size_t)n*NF_ + j];
  __syncthreads();
  float a = bn[j];
  #pragma unroll
  for (int k = 0; k < NF_; ++k) a = fmaf(xs[k], Wn[(size_t)k*D_ + j], a);
  h[(size_t)n*D_ + j] = a;
  hb[(size_t)n*D_ + j] = (_Float16)a;
}

__global__ __launch_bounds__(128) void k_edge_enc(
    const float* __restrict__ ef, const float* __restrict__ We,
    const float* __restrict__ be, _Float16* __restrict__ eb)
{
  int i = blockIdx.x, j = threadIdx.x;
  __shared__ float xs[EF_];
  if (j < EF_) xs[j] = ef[(size_t)i*EF_ + j];
  __syncthreads();
  float a = be[j];
  #pragma unroll
  for (int k = 0; k < EF_; ++k) a = fmaf(xs[k], We[(size_t)k*D_ + j], a);
  eb[(size_t)i*D_ + j] = (_Float16)a;
}

// ---------------- GEMM: FT = hb @ W1Tn  (M=9216, N=1024, K=128) ----------------
__global__ __launch_bounds__(256) void k_gemm_FT(
    const _Float16* __restrict__ A, const _Float16* __restrict__ Bm,
    _Float16* __restrict__ FT)
{
  const int m0 = blockIdx.x * 128, n0 = blockIdx.y * 128;
  __shared__ _Float16 As[128*64], Bs[128*64];
  const int tid = threadIdx.x;
  const int srow = tid >> 3, slot = tid & 7;
  const int wave = tid >> 6, lane = tid & 63;
  const int wm = wave >> 1, wn = wave & 1;
  const int lr = lane & 15, lk = lane >> 4;
  f32x4 acc[4][4] = {};
  for (int kt = 0; kt < 2; ++kt) {
    __syncthreads();
    #pragma unroll
    for (int i = 0; i < 4; ++i) {
      const int r = srow + 32*i;
      const int ss = slot ^ (r & 7);
      gload16(A + (size_t)(m0 + r)*128 + kt*64 + ss*8, &As[r*64 + slot*8]);
      gload16(Bm + (size_t)(n0 + r)*128 + kt*64 + ss*8, &Bs[r*64 + slot*8]);
    }
    __syncthreads();
    #pragma unroll
    for (int ks = 0; ks < 2; ++ks) {
      f16x8 af[4], bfr[4];
      #pragma unroll
      for (int mf = 0; mf < 4; ++mf) {
        const int r = wm*64 + mf*16 + lr;
        const int ch = (ks*4 + lk) ^ (r & 7);
        af[mf] = *(const f16x8*)&As[r*64 + ch*8];
      }
      #pragma unroll
      for (int nf = 0; nf < 4; ++nf) {
        const int n = wn*64 + nf*16 + lr;
        const int ch = (ks*4 + lk) ^ (n & 7);
        bfr[nf] = *(const f16x8*)&Bs[n*64 + ch*8];
      }
      #pragma unroll
      for (int mf = 0; mf < 4; ++mf)
        #pragma unroll
        for (int nf = 0; nf < 4; ++nf)
          acc[mf][nf] = __builtin_amdgcn_mfma_f32_16x16x32_f16(af[mf], bfr[nf], acc[mf][nf], 0, 0, 0);
    }
  }
  #pragma unroll
  for (int nf = 0; nf < 4; ++nf) {
    const int c = n0 + wn*64 + nf*16 + lr;
    #pragma unroll
    for (int mf = 0; mf < 4; ++mf)
      #pragma unroll
      for (int v = 0; v < 4; ++v) {
        const int r = m0 + wm*64 + mf*16 + lk*4 + v;
        FT[(size_t)r*1024 + c] = (_Float16)acc[mf][nf][v];
      }
  }
}

// ---------------- GEMM: E = eb @ W1Te + bcat1  (M=51200, N=512, K=128) ----------------
__global__ __launch_bounds__(256) void k_gemm_E(
    const _Float16* __restrict__ A, const _Float16* __restrict__ Bm,
    const float* __restrict__ bcat1, _Float16* __restrict__ E)
{
  const int m0 = blockIdx.x * 128, n0 = blockIdx.y * 128;
  __shared__ _Float16 As[128*64], Bs[128*64];
  const int tid = threadIdx.x;
  const int srow = tid >> 3, slot = tid & 7;
  const int wave = tid >> 6, lane = tid & 63;
  const int wm = wave >> 1, wn = wave & 1;
  const int lr = lane & 15, lk = lane >> 4;
  f32x4 acc[4][4] = {};
  for (int kt = 0; kt < 2; ++kt) {
    __syncthreads();
    #pragma unroll
    for (int i = 0; i < 4; ++i) {
      const int r = srow + 32*i;
      const int ss = slot ^ (r & 7);
      gload16(A + (size_t)(m0 + r)*128 + kt*64 + ss*8, &As[r*64 + slot*8]);
      gload16(Bm + (size_t)(n0 + r)*128 + kt*64 + ss*8, &Bs[r*64 + slot*8]);
    }
    __syncthreads();
    #pragma unroll
    for (int ks = 0; ks < 2; ++ks) {
      f16x8 af[4], bfr[4];
      #pragma unroll
      for (int mf = 0; mf < 4; ++mf) {
        const int r = wm*64 + mf*16 + lr;
        const int ch = (ks*4 + lk) ^ (r & 7);
        af[mf] = *(const f16x8*)&As[r*64 + ch*8];
      }
      #pragma unroll
      for (int nf = 0; nf < 4; ++nf) {
        const int n = wn*64 + nf*16 + lr;
        const int ch = (ks*4 + lk) ^ (n & 7);
        bfr[nf] = *(const f16x8*)&Bs[n*64 + ch*8];
      }
      #pragma unroll
      for (int mf = 0; mf < 4; ++mf)
        #pragma unroll
        for (int nf = 0; nf < 4; ++nf)
          acc[mf][nf] = __builtin_amdgcn_mfma_f32_16x16x32_f16(af[mf], bfr[nf], acc[mf][nf], 0, 0, 0);
    }
  }
  #pragma unroll
  for (int nf = 0; nf < 4; ++nf) {
    const int c = n0 + wn*64 + nf*16 + lr;
    const float bias = bcat1[c];
    #pragma unroll
    for (int mf = 0; mf < 4; ++mf)
      #pragma unroll
      for (int v = 0; v < 4; ++v) {
        const int r = m0 + wm*64 + mf*16 + lk*4 + v;
        E[(size_t)r*512 + c] = (_Float16)(acc[mf][nf][v] + bias);
      }
  }
}

// ---------------- fused hidden + deterministic segment-sum (1 wave/node, f16x8) ----------------
__global__ __launch_bounds__(64) void k_agg_fused(
    const _Float16* __restrict__ FT, const _Float16* __restrict__ E,
    const int* __restrict__ from_idx, const int* __restrict__ to_idx,
    const int* __restrict__ in_cnt, const int* __restrict__ in_list,
    const int* __restrict__ out_cnt, const int* __restrict__ out_list,
    _Float16* __restrict__ Hsum)
{
  const int g = blockIdx.x;
  const int b = g / NPB_;
  const int lane = threadIdx.x;
  const int half = lane >> 5;          // 0 = in, 1 = out
  const int c8 = (lane & 31) * 8;      // element offset within 256
  const int ebase = b * EPB_;
  const size_t ftg = (size_t)g * 1024;

  const f16x8 base = (half == 0) ? *(const f16x8*)&FT[ftg + 512 + c8]    // T[n]
                                 : *(const f16x8*)&FT[ftg + 256 + c8];   // F[n] (r-part)
  const int cnt = (half == 0) ? in_cnt[g] : out_cnt[g];
  const int* lst = (half == 0) ? &in_list[(size_t)g*DEGCAP_] : &out_list[(size_t)g*DEGCAP_];
  const int eoff = half * 256;
  const int foff = (half == 0) ? 0 : 768;

  float acc[8] = {};
  for (int i = 0; i < cnt; ++i) {
    const int ge = ebase + lst[i];
    const int other = (half == 0) ? from_idx[ge] : to_idx[ge];
    const f16x8 fo = *(const f16x8*)&FT[(size_t)other*1024 + foff + c8];
    const f16x8 ev = *(const f16x8*)&E[(size_t)ge*512 + eoff + c8];
    #pragma unroll
    for (int k = 0; k < 8; ++k)
      acc[k] += fmaxf((float)base[k] + (float)fo[k] + (float)ev[k], 0.f);
  }
  f16x8 o;
  #pragma unroll
  for (int k = 0; k < 8; ++k) o[k] = (_Float16)acc[k];
  *(f16x8*)&Hsum[(size_t)g*512 + eoff + c8] = o;
}

// ---------------- GEMM: agg = Hsum @ W2cT + ic*bm2 + oc*br2  (M=9216, N=256, K=512) ----------------
__global__ __launch_bounds__(256) void k_gemm_agg(
    const _Float16* __restrict__ A, const _Float16* __restrict__ Bm,
    const int* __restrict__ in_cnt, const int* __restrict__ out_cnt,
    const float* __restrict__ bm2, const float* __restrict__ br2,
    float* __restrict__ agg)
{
  const int m0 = blockIdx.x * 128, n0 = blockIdx.y * 128;
  __shared__ _Float16 As[128*64], Bs[128*64];
  const int tid = threadIdx.x;
  const int srow = tid >> 3, slot = tid & 7;
  const int wave = tid >> 6, lane = tid & 63;
  const int wm = wave >> 1, wn = wave & 1;
  const int lr = lane & 15, lk = lane >> 4;
  f32x4 acc[4][4] = {};
  for (int kt = 0; kt < 8; ++kt) {
    __syncthreads();
    #pragma unroll
    for (int i = 0; i < 4; ++i) {
      const int r = srow + 32*i;
      const int ss = slot ^ (r & 7);
      gload16(A + (size_t)(m0 + r)*512 + kt*64 + ss*8, &As[r*64 + slot*8]);
      gload16(Bm + (size_t)(n0 + r)*512 + kt*64 + ss*8, &Bs[r*64 + slot*8]);
    }
    __syncthreads();
    #pragma unroll
    for (int ks = 0; ks < 2; ++ks) {
      f16x8 af[4], bfr[4];
      #pragma unroll
      for (int mf = 0; mf < 4; ++mf) {
        const int r = wm*64 + mf*16 + lr;
        const int ch = (ks*4 + lk) ^ (r & 7);
        af[mf] = *(const f16x8*)&As[r*64 + ch*8];
      }
      #pragma unroll
      for (int nf = 0; nf < 4; ++nf) {
        const int n = wn*64 + nf*16 + lr;
        const int ch = (ks*4 + lk) ^ (n & 7);
        bfr[nf] = *(const f16x8*)&Bs[n*64 + ch*8];
      }
      #pragma unroll
      for (int mf = 0; mf < 4; ++mf)
        #pragma unroll
        for (int nf = 0; nf < 4; ++nf)
          acc[mf][nf] = __builtin_amdgcn_mfma_f32_16x16x32_f16(af[mf], bfr[nf], acc[mf][nf], 0, 0, 0);
    }
  }
  #pragma unroll
  for (int nf = 0; nf < 4; ++nf) {
    const int c = n0 + wn*64 + nf*16 + lr;
    const float b2m = bm2[c], b2r = br2[c];
    #pragma unroll
    for (int mf = 0; mf < 4; ++mf)
      #pragma unroll
      for (int v = 0; v < 4; ++v) {
        const int r = m0 + wm*64 + mf*16 + lk*4 + v;
        agg[(size_t)r*256 + c] = acc[mf][nf][v] + in_cnt[r]*b2m + out_cnt[r]*b2r;
      }
  }
}

// ---------------- node update: h = [h, agg] @ Wu + bu  (+ fp16 copy) ----------------
__global__ __launch_bounds__(256) void k_update(
    const float* __restrict__ h, const float* __restrict__ agg,
    const float* __restrict__ Wu, const float* __restrict__ bu,
    float* __restrict__ hn, _Float16* __restrict__ hbn)
{
  const int n0 = blockIdx.x * 8;
  const int j = threadIdx.x & 127, half = threadIdx.x >> 7;
  __shared__ float xs[8][3*D_];
  for (int idx = threadIdx.x; idx < 8*3*D_; idx += 256) {
    int t = idx / (3*D_), k = idx - t*(3*D_);
    xs[t][k] = (k < D_) ? h[(size_t)(n0 + t)*D_ + k]
                        : agg[(size_t)(n0 + t)*(2*D_) + (k - D_)];
  }
  __syncthreads();
  float acc[4];
  const float b0 = bu[j];
  #pragma unroll
  for (int t = 0; t < 4; ++t) acc[t] = b0;
  for (int k = 0; k < 3*D_; k += 4) {
    const float w0 = Wu[(size_t)(k+0)*D_ + j];
    const float w1 = Wu[(size_t)(k+1)*D_ + j];
    const float w2 = Wu[(size_t)(k+2)*D_ + j];
    const float w3 = Wu[(size_t)(k+3)*D_ + j];
    #pragma unroll
    for (int t = 0; t < 4; ++t) {
      const float4 xv = *reinterpret_cast<const float4*>(&xs[half*4 + t][k]);
      acc[t] = fmaf(xv.w, w3, fmaf(xv.z, w2, fmaf(xv.y, w1, fmaf(xv.x, w0, acc[t]))));
    }
  }
  #pragma unroll
  for (int t = 0; t < 4; ++t) {
    const int r = n0 + half*4 + t;
    hn[(size_t)r*D_ + j] = acc[t];
    hbn[(size_t)r*D_ + j] = (_Float16)acc[t];
  }
}

// ---------------- node target embeddings ----------------
__global__ __launch_bounds__(128) void k_node_emb(
    const float* __restrict__ h,
    const float* __restrict__ Wq1, const float* __restrict__ bq1,
    const float* __restrict__ Wq2, const float* __restrict__ bq2,
    float* __restrict__ tq_emb, float* __restrict__ tc_emb)
{
  const int bid = blockIdx.x;
  const int b = bid / (2*NMAX_), s = bid - b*(2*NMAX_);
  const bool isQ = s < NMAX_;
  const int r = isQ ? s : s - NMAX_;
  float* outp = (isQ ? tq_emb : tc_emb) + ((size_t)b*NMAX_ + r)*TD_;
  const int tid = threadIdx.x;
  if (isQ && r >= NQ_) {
    if (tid < TD_) outp[tid] = 0.f;
    return;
  }
  const int node = b*NPB_ + (isQ ? r : NQ_ + r);
  __shared__ float xs[D_];
  __shared__ float l1[TD_];
  xs[tid] = h[(size_t)node*D_ + tid];
  __syncthreads();
  if (tid < TD_) {
    float a = bq1[tid];
    for (int k = 0; k < D_; ++k) a = fmaf(xs[k], Wq1[(size_t)k*TD_ + tid], a);
    l1[tid] = fmaxf(a, 0.f);
  }
  __syncthreads();
  if (tid < TD_) {
    float a = bq2[tid];
    #pragma unroll
    for (int k = 0; k < TD_; ++k) a = fmaf(l1[k], Wq2[(size_t)k*TD_ + tid], a);
    outp[tid] = a;
  }
}

// ---------------- sinkhorn over 40x40 node plans ----------------
__global__ __launch_bounds__(256) void k_sinkhorn_n(
    const float* __restrict__ tq_emb, const float* __restrict__ tc_emb,
    float* __restrict__ plan_n)
{
  const int b = blockIdx.x, tid = threadIdx.x;
  __shared__ float la[NMAX_][NMAX_];
  __shared__ float qe[NMAX_][TD_], ce[NMAX_][TD_];
  for (int idx = tid; idx < NMAX_*TD_; idx += 256) {
    qe[idx / TD_][idx % TD_] = tq_emb[(size_t)b*NMAX_*TD_ + idx];
    ce[idx / TD_][idx % TD_] = tc_emb[(size_t)b*NMAX_*TD_ + idx];
  }
  __syncthreads();
  for (int idx = tid; idx < NMAX_*NMAX_; idx += 256) {
    int q = idx / NMAX_, c = idx - q*NMAX_;
    float a = 0.f;
    #pragma unroll
    for (int d = 0; d < TD_; ++d) a = fmaf(qe[q][d], ce[c][d], a);
    la[q][c] = a * L2E10_;
  }
  __syncthreads();
  for (int it = 0; it < ITERS_; ++it) {
    if (tid < NMAX_) {
      float m = -INFINITY;
      for (int c = 0; c < NMAX_; ++c) m = fmaxf(m, la[tid][c]);
      float s = 0.f;
      for (int c = 0; c < NMAX_; ++c) s += ex2(la[tid][c] - m);
      const float lse = m + lg2(s);
      for (int c = 0; c < NMAX_; ++c) la[tid][c] -= lse;
    }
    __syncthreads();
    if (tid < NMAX_) {
      float m = -INFINITY;
      for (int q = 0; q < NMAX_; ++q) m = fmaxf(m, la[q][tid]);
      float s = 0.f;
      for (int q = 0; q < NMAX_; ++q) s += ex2(la[q][tid] - m);
      const float lse = m + lg2(s);
      for (int q = 0; q < NMAX_; ++q) la[q][tid] -= lse;
    }
    __syncthreads();
  }
  for (int idx = tid; idx < NMAX_*NMAX_; idx += 256)
    plan_n[(size_t)b*NMAX_*NMAX_ + idx] = ex2(la[idx / NMAX_][idx % NMAX_]);
}

// ---------------- final edge embed, fully fused (conflict-free staging) ----------------
// Staging map: t = idx>>7, c4 = idx&127 — each wave writes 64 CONSECUTIVE float4
// chunks of one row (conflict-free b128); global loads f16x4 = 8 B/lane coalesced.
__global__ __launch_bounds__(256) void k_edge_emb_f(
    const _Float16* __restrict__ FT, const _Float16* __restrict__ E,
    const int* __restrict__ from_idx, const int* __restrict__ to_idx,
    const float* __restrict__ WceT, const float* __restrict__ bce,
    const float* __restrict__ We2, const float* __restrict__ be2,
    float* __restrict__ teq, float* __restrict__ tec)
{
  const int e0 = blockIdx.x * 16;
  const int tid = threadIdx.x;
  __shared__ float es[16][516];
  __shared__ float l1s[16][TD_];
  __shared__ int sfrom[16], sto[16];
  if (tid < 16) { sfrom[tid] = from_idx[e0 + tid]; sto[tid] = to_idx[e0 + tid]; }
  __syncthreads();
  // 16 edges x 128 float4 chunks; lane -> consecutive c4 within one row
  for (int idx = tid; idx < 16*128; idx += 256) {
    const int t = idx >> 7, k4 = (idx & 127) * 4;
    const f16x4 fa = *(const f16x4*)&FT[(size_t)sfrom[t]*1024 + k4];
    const f16x4 fb = *(const f16x4*)&FT[(size_t)sto[t]*1024 + 512 + k4];
    const f16x4 ev = *(const f16x4*)&E[(size_t)(e0 + t)*512 + k4];
    float4 o;
    o.x = fmaxf((float)fa[0]+(float)fb[0]+(float)ev[0], 0.f);
    o.y = fmaxf((float)fa[1]+(float)fb[1]+(float)ev[1], 0.f);
    o.z = fmaxf((float)fa[2]+(float)fb[2]+(float)ev[2], 0.f);
    o.w = fmaxf((float)fa[3]+(float)fb[3]+(float)ev[3], 0.f);
    *reinterpret_cast<float4*>(&es[t][k4]) = o;
  }
  __syncthreads();
  const int t = tid >> 4, jj = tid & 15;
  float a0 = bce[jj], a1 = 0.f, a2 = 0.f, a3 = 0.f;
  const float4* wrow = reinterpret_cast<const float4*>(WceT + (size_t)jj*512);
  const float4* xrow = reinterpret_cast<const float4*>(&es[t][0]);
  #pragma unroll 8
  for (int k0 = 0; k0 < 128; k0 += 4) {
    const float4 w0 = wrow[k0],   x0 = xrow[k0];
    const float4 w1 = wrow[k0+1], x1 = xrow[k0+1];
    const float4 w2 = wrow[k0+2], x2 = xrow[k0+2];
    const float4 w3 = wrow[k0+3], x3 = xrow[k0+3];
    a0 += x0.x*w0.x + x0.y*w0.y + x0.z*w0.z + x0.w*w0.w;
    a1 += x1.x*w1.x + x1.y*w1.y + x1.z*w1.z + x1.w*w1.w;
    a2 += x2.x*w2.x + x2.y*w2.y + x2.z*w2.z + x2.w*w2.w;
    a3 += x3.x*w3.x + x3.y*w3.y + x3.z*w3.z + x3.w*w3.w;
  }
  l1s[t][jj] = fmaxf((a0 + a1) + (a2 + a3), 0.f);
  __syncthreads();
  float a2f = be2[jj];
  #pragma unroll
  for (int k = 0; k < TD_; ++k) a2f = fmaf(l1s[t][k], We2[(size_t)k*TD_ + jj], a2f);
  const int ei = e0 + t;
  const int bb = ei / EPB_, jl = ei - bb*EPB_;
  if (jl < EQ_) teq[((size_t)bb*EMAX_ + jl)*TD_ + jj] = a2f;
  else          tec[((size_t)bb*EMAX_ + (jl - EQ_))*TD_ + jj] = a2f;
}

// ---------------- fused: escore + sinkhorn_e (registers, base-2) + final score ----------------
__global__ __launch_bounds__(1024) void k_plan_score(
    const float* __restrict__ teq, const float* __restrict__ tec,
    const float* __restrict__ plan_n,
    const float* __restrict__ tq_emb, const float* __restrict__ tc_emb,
    const int* __restrict__ fq, const int* __restrict__ tq,
    const int* __restrict__ fc, const int* __restrict__ tc,
    const float* __restrict__ Wa, const float* __restrict__ ba,
    float* __restrict__ out)
{
  const int b = blockIdx.x, t = threadIdx.x;
  const int tr = t >> 4, tcg = t & 15, lane = t & 63, w = t >> 6;

  __shared__ float shm[8704];    // overlay: {sq,sc} | {wovm,wovs} | epilogue tables
  __shared__ float bcast[256];

  {
    float* sq = shm;             // 256*17
    float* sc = shm + 4352;      // 256*17
    for (int idx = t; idx < 4096; idx += 1024) {
      const int r = idx >> 4, k = idx & 15;
      sq[r*17 + k] = teq[(size_t)b*4096 + idx];
      sc[r*17 + k] = tec[(size_t)b*4096 + idx];
    }
  }
  __syncthreads();

  float la[4][16];
  {
    const float* sq = shm;
    const float* sc = shm + 4352;
    #pragma unroll
    for (int i = 0; i < 4; ++i)
      #pragma unroll
      for (int j = 0; j < 16; ++j) la[i][j] = 0.f;
    for (int k = 0; k < 16; ++k) {
      float qk[4];
      #pragma unroll
      for (int i = 0; i < 4; ++i) qk[i] = sq[(tr*4 + i)*17 + k];
      #pragma unroll
      for (int j = 0; j < 16; ++j) {
        const float sck = sc[(j*16 + tcg)*17 + k];
        #pragma unroll
        for (int i = 0; i < 4; ++i) la[i][j] = fmaf(qk[i], sck, la[i][j]);
      }
    }
    #pragma unroll
    for (int i = 0; i < 4; ++i)
      #pragma unroll
      for (int j = 0; j < 16; ++j) la[i][j] *= L2E10_;
  }
  __syncthreads();

  float* wovm = shm;           // 4096
  float* wovs = shm + 4096;    // 4096

  for (int it = 0; it < ITERS_; ++it) {
    #pragma unroll
    for (int i = 0; i < 4; ++i) {
      float m = la[i][0];
      #pragma unroll
      for (int j = 1; j < 16; ++j) m = fmaxf(m, la[i][j]);
      m = fmaxf(m, __shfl_xor(m, 1)); m = fmaxf(m, __shfl_xor(m, 2));
      m = fmaxf(m, __shfl_xor(m, 4)); m = fmaxf(m, __shfl_xor(m, 8));
      float s = 0.f;
      #pragma unroll
      for (int j = 0; j < 16; ++j) s += ex2(la[i][j] - m);
      s += __shfl_xor(s, 1); s += __shfl_xor(s, 2);
      s += __shfl_xor(s, 4); s += __shfl_xor(s, 8);
      const float lse = m + lg2(s);
      #pragma unroll
      for (int j = 0; j < 16; ++j) la[i][j] -= lse;
    }
    #pragma unroll
    for (int j = 0; j < 16; ++j) {
      float m = fmaxf(fmaxf(la[0][j], la[1][j]), fmaxf(la[2][j], la[3][j]));
      m = fmaxf(m, __shfl_xor(m, 16));
      m = fmaxf(m, __shfl_xor(m, 32));
      float s = ex2(la[0][j] - m) + ex2(la[1][j] - m)
              + ex2(la[2][j] - m) + ex2(la[3][j] - m);
      s += __shfl_xor(s, 16);
      s += __shfl_xor(s, 32);
      if (lane < 16) { wovm[w*256 + j*16 + lane] = m; wovs[w*256 + j*16 + lane] = s; }
    }
    __syncthreads();
    if (t < 256) {
      float M = wovm[t];
      #pragma unroll
      for (int ww = 1; ww < 16; ++ww) M = fmaxf(M, wovm[ww*256 + t]);
      float S = 0.f;
      #pragma unroll
      for (int ww = 0; ww < 16; ++ww) S += wovs[ww*256 + t] * ex2(wovm[ww*256 + t] - M);
      bcast[t] = M + lg2(S);
    }
    __syncthreads();
    #pragma unroll
    for (int j = 0; j < 16; ++j) {
      const float lse = bcast[j*16 + tcg];
      #pragma unroll
      for (int i = 0; i < 4; ++i) la[i][j] -= lse;
    }
  }
  __syncthreads();

  float* pn = shm;                 // 1600
  float* qe = shm + 1600;          // 640
  float* ce = shm + 2240;          // 640
  int*   ib = (int*)(shm + 2880);  // 800 ints
  int* sfq = ib, *stq = ib + 160, *sfc = ib + 320, *stc = ib + 560;
  for (int i = t; i < 1600; i += 1024) pn[i] = plan_n[(size_t)b*1600 + i];
  if (t < 640) { qe[t] = tq_emb[(size_t)b*640 + t]; ce[t] = tc_emb[(size_t)b*640 + t]; }
  if (t < 160) { sfq[t] = fq[b*160 + t]; stq[t] = tq[b*160 + t]; }
  if (t >= 512 && t < 752) { sfc[t-512] = fc[b*240 + (t-512)]; stc[t-512] = tc[b*240 + (t-512)]; }
  __syncthreads();

  float csum = 0.f;
  if (tr < 40) {
    #pragma unroll
    for (int i = 0; i < 4; ++i) {
      const int q = tr*4 + i;
      const int g0 = sfq[q]*NMAX_, g1 = stq[q]*NMAX_;
      #pragma unroll
      for (int j = 0; j < 15; ++j) {
        const int c = j*16 + tcg;
        const float pe = ex2(la[i][j]);
        const float a0 = pn[g0 + sfc[c]] * pn[g1 + stc[c]];
        const float a1 = pn[g0 + stc[c]] * pn[g1 + sfc[c]];
        csum += pe * fmaxf(a0, a1);
      }
    }
  }
  float hsum = 0.f;
  if (t < NMAX_*TD_) {
    const int q = t >> 4, d2 = t & 15;
    float a = 0.f;
    for (int c = 0; c < NMAX_; ++c) a = fmaf(pn[q*NMAX_ + c], ce[c*TD_ + d2], a);
    hsum = fmaxf(qe[t] - a, 0.f);
  }
  #pragma unroll
  for (int off = 32; off; off >>= 1) {
    csum += __shfl_xor(csum, off);
    hsum += __shfl_xor(hsum, off);
  }
  if (lane == 0) { bcast[w] = csum; bcast[32 + w] = hsum; }
  __syncthreads();
  if (t == 0) {
    float C = 0.f, H = 0.f;
    #pragma unroll
    for (int ww = 0; ww < 16; ++ww) { C += bcast[ww]; H += bcast[32 + ww]; }
    out[b] = (-H) * Wa[0] + C * Wa[1] + ba[0];
  }
}

// ---------------- host launcher ----------------
extern "C" void kernel_launch(void* const* d_in, const int* in_sizes, int n_in,
                              void* d_out, int out_size, void* d_ws, size_t ws_size,
                              hipStream_t stream) {
  const float* node_features = (const float*)d_in[0];
  const float* edge_features = (const float*)d_in[1];
  const float* Wn  = (const float*)d_in[2];
  const float* bn  = (const float*)d_in[3];
  const float* We  = (const float*)d_in[4];
  const float* be  = (const float*)d_in[5];
  const float* Wm1 = (const float*)d_in[6];
  const float* bm1 = (const float*)d_in[7];
  const float* Wm2 = (const float*)d_in[8];
  const float* bm2 = (const float*)d_in[9];
  const float* Wr1 = (const float*)d_in[10];
  const float* br1 = (const float*)d_in[11];
  const float* Wr2 = (const float*)d_in[12];
  const float* br2 = (const float*)d_in[13];
  const float* Wu  = (const float*)d_in[14];
  const float* bu  = (const float*)d_in[15];
  const float* Wq1 = (const float*)d_in[16];
  const float* bq1 = (const float*)d_in[17];
  const float* Wq2 = (const float*)d_in[18];
  const float* bq2 = (const float*)d_in[19];
  const float* We1 = (const float*)d_in[20];
  const float* be1 = (const float*)d_in[21];
  const float* We2 = (const float*)d_in[22];
  const float* be2 = (const float*)d_in[23];
  const float* Wa  = (const float*)d_in[24];
  const float* ba  = (const float*)d_in[25];
  const int* fq = (const int*)d_in[26];
  const int* tq = (const int*)d_in[27];
  const int* fc = (const int*)d_in[28];
  const int* tc = (const int*)d_in[29];
  (void)in_sizes; (void)n_in; (void)out_size; (void)ws_size;

  char* ws = (char*)d_ws;
  size_t off = 0;
  auto take = [&](size_t bytes) -> void* {
    void* p = ws + off;
    off = (off + bytes + 255) & ~(size_t)255;
    return p;
  };
  int*   from_idx = (int*)  take((size_t)ETOT_*4);
  int*   to_idx   = (int*)  take((size_t)ETOT_*4);
  int*   in_cnt   = (int*)  take((size_t)NTOT_*4);
  int*   out_cnt  = (int*)  take((size_t)NTOT_*4);
  int*   in_list  = (int*)  take((size_t)NTOT_*DEGCAP_*4);
  int*   out_list = (int*)  take((size_t)NTOT_*DEGCAP_*4);
  float* h0       = (float*)take((size_t)NTOT_*D_*4);
  float* h1       = (float*)take((size_t)NTOT_*D_*4);
  _Float16* hb    = (_Float16*)take((size_t)NTOT_*D_*2);
  _Float16* eb    = (_Float16*)take((size_t)ETOT_*D_*2);
  _Float16* FT    = (_Float16*)take((size_t)NTOT_*1024*2);
  _Float16* Ebuf  = (_Float16*)take((size_t)ETOT_*512*2);
  _Float16* Hsum  = (_Float16*)take((size_t)NTOT_*512*2);
  float* agg      = (float*)take((size_t)NTOT_*256*4);
  float* tq_emb   = (float*)take((size_t)B_*NMAX_*TD_*4);
  float* tc_emb   = (float*)take((size_t)B_*NMAX_*TD_*4);
  float* plan_n   = (float*)take((size_t)B_*NMAX_*NMAX_*4);
  float* teq      = (float*)take((size_t)B_*EMAX_*TD_*4);
  float* tec      = (float*)take((size_t)B_*EMAX_*TD_*4);
  _Float16* W1Tn  = (_Float16*)take((size_t)1024*128*2);
  _Float16* W1Te  = (_Float16*)take((size_t)512*128*2);
  _Float16* W2cT  = (_Float16*)take((size_t)256*512*2);
  float* bcat1    = (float*)take(512*4);
  float* WceT     = (float*)take((size_t)16*512*4);
  float* bce      = (float*)take(16*4);

  k_build_idx<<<(ETOT_ + 255)/256, 256, 0, stream>>>(fq, tq, fc, tc, from_idx, to_idx);
  k_build_lists<<<B_, 256, 0, stream>>>(fq, tq, fc, tc, in_cnt, in_list, out_cnt, out_list);
  k_prep_w<<<(1024*128 + 512*128 + 256*512 + 255)/256, 256, 0, stream>>>(
      Wm1, Wr1, Wm2, Wr2, bm1, br1, W1Tn, W1Te, W2cT, bcat1);
  k_prep_wce<<<32, 256, 0, stream>>>(Wm2, Wr2, We1, bm2, br2, be1, WceT, bce);
  k_node_enc<<<NTOT_, D_, 0, stream>>>(node_features, Wn, bn, h0, hb);
  k_edge_enc<<<ETOT_, D_, 0, stream>>>(edge_features, We, be, eb);

  dim3 gE(ETOT_/128, 4);
  k_gemm_E<<<gE, 256, 0, stream>>>(eb, W1Te, bcat1, Ebuf);

  dim3 gFT(NTOT_/128, 8);
  dim3 gAG(NTOT_/128, 2);
  float* hc = h0;
  float* hn = h1;
  for (int p = 0; p < NPROP_; ++p) {
    k_gemm_FT<<<gFT, 256, 0, stream>>>(hb, W1Tn, FT);
    k_agg_fused<<<NTOT_, 64, 0, stream>>>(FT, Ebuf, from_idx, to_idx,
                                          in_cnt, in_list, out_cnt, out_list, Hsum);
    k_gemm_agg<<<gAG, 256, 0, stream>>>(Hsum, W2cT, in_cnt, out_cnt, bm2, br2, agg);
    k_update<<<NTOT_/8, 256, 0, stream>>>(hc, agg, Wu, bu, hn, hb);
    float* t_ = hc; hc = hn; hn = t_;
  }

  k_node_emb<<<B_*2*NMAX_, D_, 0, stream>>>(hc, Wq1, bq1, Wq2, bq2, tq_emb, tc_emb);
  k_sinkhorn_n<<<B_, 256, 0, stream>>>(tq_emb, tc_emb, plan_n);

  k_gemm_FT<<<gFT, 256, 0, stream>>>(hb, W1Tn, FT);
  hipMemsetAsync(teq, 0, (size_t)B_*EMAX_*TD_*4, stream);
  hipMemsetAsync(tec, 0, (size_t)B_*EMAX_*TD_*4, stream);
  k_edge_emb_f<<<ETOT_/16, 256, 0, stream>>>(FT, Ebuf, from_idx, to_idx,
                                             WceT, bce, We2, be2, teq, tec);

  k_plan_score<<<B_, 1024, 0, stream>>>(teq, tec, plan_n, tq_emb, tc_emb,
                                        fq, tq, fc, tc, Wa, ba, (float*)d_out);
}

// Round 9
// 799.459 us; speedup vs baseline: 8.4479x; 1.2381x over previous
//
#include <hip/hip_runtime.h>
#include <cstddef>
#include <cstdint>

// ---------------- problem constants ----------------
constexpr int B_    = 128;
constexpr int NQ_   = 32;
constexpr int NC_   = 40;
constexpr int NMAX_ = 40;
constexpr int EQ_   = 160;
constexpr int EC_   = 240;
constexpr int EMAX_ = 256;
constexpr int D_    = 128;
constexpr int TD_   = 16;
constexpr int NPROP_ = 5;
constexpr int ITERS_ = 20;
constexpr float TEMP_ = 0.1f;
constexpr int NF_   = 32;
constexpr int EF_   = 16;
constexpr int NPB_  = NQ_ + NC_;   // 72 nodes / batch
constexpr int EPB_  = EQ_ + EC_;   // 400 edges / batch
constexpr int NTOT_ = B_ * NPB_;   // 9216
constexpr int ETOT_ = B_ * EPB_;   // 51200
constexpr int DEGCAP_ = 64;
constexpr float L2E10_ = 14.4269504088896f;  // 10 * log2(e)

typedef _Float16 f16x8 __attribute__((ext_vector_type(8)));
typedef _Float16 f16x4 __attribute__((ext_vector_type(4)));
typedef float f32x4 __attribute__((ext_vector_type(4)));

__device__ __forceinline__ void gload16(const void* g, void* l) {
  __builtin_amdgcn_global_load_lds(
      (const __attribute__((address_space(1))) unsigned int*)g,
      (__attribute__((address_space(3))) unsigned int*)l, 16, 0, 0);
}
__device__ __forceinline__ float ex2(float x) { return __builtin_amdgcn_exp2f(x); }
__device__ __forceinline__ float lg2(float x) { return __builtin_amdgcn_logf(x); }

// ---------------- index building ----------------
__global__ __launch_bounds__(256) void k_build_idx(
    const int* __restrict__ fq, const int* __restrict__ tq,
    const int* __restrict__ fc, const int* __restrict__ tc,
    int* __restrict__ from_idx, int* __restrict__ to_idx)
{
  int i = blockIdx.x * blockDim.x + threadIdx.x;
  if (i >= ETOT_) return;
  int b = i / EPB_, j = i - b * EPB_;
  int f, t;
  if (j < EQ_) {
    f = fq[b*EQ_ + j] + b*NPB_;
    t = tq[b*EQ_ + j] + b*NPB_;
  } else {
    int jj = j - EQ_;
    f = fc[b*EC_ + jj] + b*NPB_ + NQ_;
    t = tc[b*EC_ + jj] + b*NPB_ + NQ_;
  }
  from_idx[i] = f;
  to_idx[i]   = t;
}

// ---------------- per-node edge lists (deterministic ascending order) ----------------
__global__ __launch_bounds__(256) void k_build_lists(
    const int* __restrict__ fq, const int* __restrict__ tq,
    const int* __restrict__ fc, const int* __restrict__ tc,
    int* __restrict__ in_cnt, int* __restrict__ in_list,
    int* __restrict__ out_cnt, int* __restrict__ out_list)
{
  const int b = blockIdx.x, tid = threadIdx.x;
  __shared__ short sf[EPB_], st[EPB_];
  for (int j = tid; j < EPB_; j += 256) {
    int f, t;
    if (j < EQ_) { f = fq[b*EQ_ + j];              t = tq[b*EQ_ + j]; }
    else         { f = fc[b*EC_ + (j-EQ_)] + NQ_;  t = tc[b*EC_ + (j-EQ_)] + NQ_; }
    sf[j] = (short)f; st[j] = (short)t;
  }
  __syncthreads();
  if (tid < NPB_) {
    const int g = b*NPB_ + tid;
    int ic = 0, oc = 0;
    for (int j = 0; j < EPB_; ++j) {
      if ((int)st[j] == tid && ic < DEGCAP_) in_list[g*DEGCAP_ + (ic++)] = j;
      if ((int)sf[j] == tid && oc < DEGCAP_) out_list[g*DEGCAP_ + (oc++)] = j;
    }
    in_cnt[g] = ic; out_cnt[g] = oc;
  }
}

// ---------------- weight prep ----------------
__global__ __launch_bounds__(256) void k_prep_w(
    const float* __restrict__ Wm1, const float* __restrict__ Wr1,
    const float* __restrict__ Wm2, const float* __restrict__ Wr2,
    const float* __restrict__ bm1, const float* __restrict__ br1,
    _Float16* __restrict__ W1Tn, _Float16* __restrict__ W1Te,
    _Float16* __restrict__ W2cT, float* __restrict__ bcat1)
{
  int i = blockIdx.x * 256 + threadIdx.x;
  if (i < 1024*128) {
    int n = i >> 7, k = i & 127;
    float v;
    if (n < 512) {            // F-part: W1 row k
      v = (n < 256) ? Wm1[(size_t)k*256 + n]
                    : Wr1[(size_t)(k + 128)*256 + (n - 256)];
    } else {                  // T-part: W1 row 128+k
      int n2 = n - 512;
      v = (n2 < 256) ? Wm1[(size_t)(128 + k)*256 + n2]
                     : Wr1[(size_t)k*256 + (n2 - 256)];
    }
    W1Tn[i] = (_Float16)v;
  }
  int j = i - 1024*128;
  if (j >= 0 && j < 512*128) {
    int n = j >> 7, k = j & 127;   // W1 row 256+k
    float v = (n < 256) ? Wm1[(size_t)(256 + k)*256 + n]
                        : Wr1[(size_t)(256 + k)*256 + (n - 256)];
    W1Te[j] = (_Float16)v;
  }
  int l = i - 1024*128 - 512*128;
  if (l >= 0 && l < 256*512) {
    int n = l >> 9, k = l & 511;
    float v = (k < 256) ? Wm2[(size_t)k*256 + n] : Wr2[(size_t)(k-256)*256 + n];
    W2cT[l] = (_Float16)v;
  }
  if (i < 512) bcat1[i] = (i < 256) ? bm1[i] : br1[i - 256];
}

// WceTh[16][512] = fp16((W2cat @ We1)^T) ; bce[16] = (bm2+br2)@We1 + be1
__global__ __launch_bounds__(256) void k_prep_wce(
    const float* __restrict__ Wm2, const float* __restrict__ Wr2,
    const float* __restrict__ We1, const float* __restrict__ bm2,
    const float* __restrict__ br2, const float* __restrict__ be1,
    _Float16* __restrict__ WceTh, float* __restrict__ bce)
{
  int i = blockIdx.x * 256 + threadIdx.x;
  if (i < 16*512) {
    int j = i >> 9, k = i & 511;
    float a = 0.f;
    for (int m = 0; m < 256; ++m) {
      const float w2 = (k < 256) ? Wm2[(size_t)k*256 + m] : Wr2[(size_t)(k-256)*256 + m];
      a = fmaf(w2, We1[(size_t)m*TD_ + j], a);
    }
    WceTh[(size_t)j*512 + k] = (_Float16)a;
  }
  if (i < 16) {
    float a = be1[i];
    for (int m = 0; m < 256; ++m) a = fmaf(bm2[m] + br2[m], We1[(size_t)m*TD_ + i], a);
    bce[i] = a;
  }
}

// ---------------- encoders ----------------
__global__ __launch_bounds__(128) void k_node_enc(
    const float* __restrict__ nf, const float* __restrict__ Wn,
    const float* __restrict__ bn, float* __restrict__ h, _Float16* __restrict__ hb)
{
  int n = blockIdx.x, j = threadIdx.x;
  __shared__ float xs[NF_];
  if (j < NF_) xs[j] = nf[(size_t)n*NF_ + j];
  __syncthreads();
  float a = bn[j];
  #pragma unroll
  for (int k = 0; k < NF_; ++k) a = fmaf(xs[k], Wn[(size_t)k*D_ + j], a);
  h[(size_t)n*D_ + j] = a;
  hb[(size_t)n*D_ + j] = (_Float16)a;
}

__global__ __launch_bounds__(128) void k_edge_enc(
    const float* __restrict__ ef, const float* __restrict__ We,
    const float* __restrict__ be, _Float16* __restrict__ eb)
{
  int i = blockIdx.x, j = threadIdx.x;
  __shared__ float xs[EF_];
  if (j < EF_) xs[j] = ef[(size_t)i*EF_ + j];
  __syncthreads();
  float a = be[j];
  #pragma unroll
  for (int k = 0; k < EF_; ++k) a = fmaf(xs[k], We[(size_t)k*D_ + j], a);
  eb[(size_t)i*D_ + j] = (_Float16)a;
}

// ---------------- GEMM: FT = hb @ W1Tn  (M=9216, N=1024, K=128) ----------------
__global__ __launch_bounds__(256) void k_gemm_FT(
    const _Float16* __restrict__ A, const _Float16* __restrict__ Bm,
    _Float16* __restrict__ FT)
{
  const int m0 = blockIdx.x * 128, n0 = blockIdx.y * 128;
  __shared__ _Float16 As[128*64], Bs[128*64];
  const int tid = threadIdx.x;
  const int srow = tid >> 3, slot = tid & 7;
  const int wave = tid >> 6, lane = tid & 63;
  const int wm = wave >> 1, wn = wave & 1;
  const int lr = lane & 15, lk = lane >> 4;
  f32x4 acc[4][4] = {};
  for (int kt = 0; kt < 2; ++kt) {
    __syncthreads();
    #pragma unroll
    for (int i = 0; i < 4; ++i) {
      const int r = srow + 32*i;
      const int ss = slot ^ (r & 7);
      gload16(A + (size_t)(m0 + r)*128 + kt*64 + ss*8, &As[r*64 + slot*8]);
      gload16(Bm + (size_t)(n0 + r)*128 + kt*64 + ss*8, &Bs[r*64 + slot*8]);
    }
    __syncthreads();
    #pragma unroll
    for (int ks = 0; ks < 2; ++ks) {
      f16x8 af[4], bfr[4];
      #pragma unroll
      for (int mf = 0; mf < 4; ++mf) {
        const int r = wm*64 + mf*16 + lr;
        const int ch = (ks*4 + lk) ^ (r & 7);
        af[mf] = *(const f16x8*)&As[r*64 + ch*8];
      }
      #pragma unroll
      for (int nf = 0; nf < 4; ++nf) {
        const int n = wn*64 + nf*16 + lr;
        const int ch = (ks*4 + lk) ^ (n & 7);
        bfr[nf] = *(const f16x8*)&Bs[n*64 + ch*8];
      }
      #pragma unroll
      for (int mf = 0; mf < 4; ++mf)
        #pragma unroll
        for (int nf = 0; nf < 4; ++nf)
          acc[mf][nf] = __builtin_amdgcn_mfma_f32_16x16x32_f16(af[mf], bfr[nf], acc[mf][nf], 0, 0, 0);
    }
  }
  #pragma unroll
  for (int nf = 0; nf < 4; ++nf) {
    const int c = n0 + wn*64 + nf*16 + lr;
    #pragma unroll
    for (int mf = 0; mf < 4; ++mf)
      #pragma unroll
      for (int v = 0; v < 4; ++v) {
        const int r = m0 + wm*64 + mf*16 + lk*4 + v;
        FT[(size_t)r*1024 + c] = (_Float16)acc[mf][nf][v];
      }
  }
}

// ---------------- GEMM: E = eb @ W1Te + bcat1  (M=51200, N=512, K=128) ----------------
__global__ __launch_bounds__(256) void k_gemm_E(
    const _Float16* __restrict__ A, const _Float16* __restrict__ Bm,
    const float* __restrict__ bcat1, _Float16* __restrict__ E)
{
  const int m0 = blockIdx.x * 128, n0 = blockIdx.y * 128;
  __shared__ _Float16 As[128*64], Bs[128*64];
  const int tid = threadIdx.x;
  const int srow = tid >> 3, slot = tid & 7;
  const int wave = tid >> 6, lane = tid & 63;
  const int wm = wave >> 1, wn = wave & 1;
  const int lr = lane & 15, lk = lane >> 4;
  f32x4 acc[4][4] = {};
  for (int kt = 0; kt < 2; ++kt) {
    __syncthreads();
    #pragma unroll
    for (int i = 0; i < 4; ++i) {
      const int r = srow + 32*i;
      const int ss = slot ^ (r & 7);
      gload16(A + (size_t)(m0 + r)*128 + kt*64 + ss*8, &As[r*64 + slot*8]);
      gload16(Bm + (size_t)(n0 + r)*128 + kt*64 + ss*8, &Bs[r*64 + slot*8]);
    }
    __syncthreads();
    #pragma unroll
    for (int ks = 0; ks < 2; ++ks) {
      f16x8 af[4], bfr[4];
      #pragma unroll
      for (int mf = 0; mf < 4; ++mf) {
        const int r = wm*64 + mf*16 + lr;
        const int ch = (ks*4 + lk) ^ (r & 7);
        af[mf] = *(const f16x8*)&As[r*64 + ch*8];
      }
      #pragma unroll
      for (int nf = 0; nf < 4; ++nf) {
        const int n = wn*64 + nf*16 + lr;
        const int ch = (ks*4 + lk) ^ (n & 7);
        bfr[nf] = *(const f16x8*)&Bs[n*64 + ch*8];
      }
      #pragma unroll
      for (int mf = 0; mf < 4; ++mf)
        #pragma unroll
        for (int nf = 0; nf < 4; ++nf)
          acc[mf][nf] = __builtin_amdgcn_mfma_f32_16x16x32_f16(af[mf], bfr[nf], acc[mf][nf], 0, 0, 0);
    }
  }
  #pragma unroll
  for (int nf = 0; nf < 4; ++nf) {
    const int c = n0 + wn*64 + nf*16 + lr;
    const float bias = bcat1[c];
    #pragma unroll
    for (int mf = 0; mf < 4; ++mf)
      #pragma unroll
      for (int v = 0; v < 4; ++v) {
        const int r = m0 + wm*64 + mf*16 + lk*4 + v;
        E[(size_t)r*512 + c] = (_Float16)(acc[mf][nf][v] + bias);
      }
  }
}

// ---------------- fused hidden + deterministic segment-sum (1 wave/node, f16x8) ----------------
__global__ __launch_bounds__(64) void k_agg_fused(
    const _Float16* __restrict__ FT, const _Float16* __restrict__ E,
    const int* __restrict__ from_idx, const int* __restrict__ to_idx,
    const int* __restrict__ in_cnt, const int* __restrict__ in_list,
    const int* __restrict__ out_cnt, const int* __restrict__ out_list,
    _Float16* __restrict__ Hsum)
{
  const int g = blockIdx.x;
  const int b = g / NPB_;
  const int lane = threadIdx.x;
  const int half = lane >> 5;          // 0 = in, 1 = out
  const int c8 = (lane & 31) * 8;      // element offset within 256
  const int ebase = b * EPB_;
  const size_t ftg = (size_t)g * 1024;

  const f16x8 base = (half == 0) ? *(const f16x8*)&FT[ftg + 512 + c8]    // T[n]
                                 : *(const f16x8*)&FT[ftg + 256 + c8];   // F[n] (r-part)
  const int cnt = (half == 0) ? in_cnt[g] : out_cnt[g];
  const int* lst = (half == 0) ? &in_list[(size_t)g*DEGCAP_] : &out_list[(size_t)g*DEGCAP_];
  const int eoff = half * 256;
  const int foff = (half == 0) ? 0 : 768;

  float acc[8] = {};
  for (int i = 0; i < cnt; ++i) {
    const int ge = ebase + lst[i];
    const int other = (half == 0) ? from_idx[ge] : to_idx[ge];
    const f16x8 fo = *(const f16x8*)&FT[(size_t)other*1024 + foff + c8];
    const f16x8 ev = *(const f16x8*)&E[(size_t)ge*512 + eoff + c8];
    #pragma unroll
    for (int k = 0; k < 8; ++k)
      acc[k] += fmaxf((float)base[k] + (float)fo[k] + (float)ev[k], 0.f);
  }
  f16x8 o;
  #pragma unroll
  for (int k = 0; k < 8; ++k) o[k] = (_Float16)acc[k];
  *(f16x8*)&Hsum[(size_t)g*512 + eoff + c8] = o;
}

// ---------------- GEMM: agg = Hsum @ W2cT + ic*bm2 + oc*br2  (M=9216, N=256, K=512) ----------------
__global__ __launch_bounds__(256) void k_gemm_agg(
    const _Float16* __restrict__ A, const _Float16* __restrict__ Bm,
    const int* __restrict__ in_cnt, const int* __restrict__ out_cnt,
    const float* __restrict__ bm2, const float* __restrict__ br2,
    float* __restrict__ agg)
{
  const int m0 = blockIdx.x * 128, n0 = blockIdx.y * 128;
  __shared__ _Float16 As[128*64], Bs[128*64];
  const int tid = threadIdx.x;
  const int srow = tid >> 3, slot = tid & 7;
  const int wave = tid >> 6, lane = tid & 63;
  const int wm = wave >> 1, wn = wave & 1;
  const int lr = lane & 15, lk = lane >> 4;
  f32x4 acc[4][4] = {};
  for (int kt = 0; kt < 8; ++kt) {
    __syncthreads();
    #pragma unroll
    for (int i = 0; i < 4; ++i) {
      const int r = srow + 32*i;
      const int ss = slot ^ (r & 7);
      gload16(A + (size_t)(m0 + r)*512 + kt*64 + ss*8, &As[r*64 + slot*8]);
      gload16(Bm + (size_t)(n0 + r)*512 + kt*64 + ss*8, &Bs[r*64 + slot*8]);
    }
    __syncthreads();
    #pragma unroll
    for (int ks = 0; ks < 2; ++ks) {
      f16x8 af[4], bfr[4];
      #pragma unroll
      for (int mf = 0; mf < 4; ++mf) {
        const int r = wm*64 + mf*16 + lr;
        const int ch = (ks*4 + lk) ^ (r & 7);
        af[mf] = *(const f16x8*)&As[r*64 + ch*8];
      }
      #pragma unroll
      for (int nf = 0; nf < 4; ++nf) {
        const int n = wn*64 + nf*16 + lr;
        const int ch = (ks*4 + lk) ^ (n & 7);
        bfr[nf] = *(const f16x8*)&Bs[n*64 + ch*8];
      }
      #pragma unroll
      for (int mf = 0; mf < 4; ++mf)
        #pragma unroll
        for (int nf = 0; nf < 4; ++nf)
          acc[mf][nf] = __builtin_amdgcn_mfma_f32_16x16x32_f16(af[mf], bfr[nf], acc[mf][nf], 0, 0, 0);
    }
  }
  #pragma unroll
  for (int nf = 0; nf < 4; ++nf) {
    const int c = n0 + wn*64 + nf*16 + lr;
    const float b2m = bm2[c], b2r = br2[c];
    #pragma unroll
    for (int mf = 0; mf < 4; ++mf)
      #pragma unroll
      for (int v = 0; v < 4; ++v) {
        const int r = m0 + wm*64 + mf*16 + lk*4 + v;
        agg[(size_t)r*256 + c] = acc[mf][nf][v] + in_cnt[r]*b2m + out_cnt[r]*b2r;
      }
  }
}

// ---------------- node update: h = [h, agg] @ Wu + bu  (+ fp16 copy) ----------------
__global__ __launch_bounds__(256) void k_update(
    const float* __restrict__ h, const float* __restrict__ agg,
    const float* __restrict__ Wu, const float* __restrict__ bu,
    float* __restrict__ hn, _Float16* __restrict__ hbn)
{
  const int n0 = blockIdx.x * 8;
  const int j = threadIdx.x & 127, half = threadIdx.x >> 7;
  __shared__ float xs[8][3*D_];
  for (int idx = threadIdx.x; idx < 8*3*D_; idx += 256) {
    int t = idx / (3*D_), k = idx - t*(3*D_);
    xs[t][k] = (k < D_) ? h[(size_t)(n0 + t)*D_ + k]
                        : agg[(size_t)(n0 + t)*(2*D_) + (k - D_)];
  }
  __syncthreads();
  float acc[4];
  const float b0 = bu[j];
  #pragma unroll
  for (int t = 0; t < 4; ++t) acc[t] = b0;
  for (int k = 0; k < 3*D_; k += 4) {
    const float w0 = Wu[(size_t)(k+0)*D_ + j];
    const float w1 = Wu[(size_t)(k+1)*D_ + j];
    const float w2 = Wu[(size_t)(k+2)*D_ + j];
    const float w3 = Wu[(size_t)(k+3)*D_ + j];
    #pragma unroll
    for (int t = 0; t < 4; ++t) {
      const float4 xv = *reinterpret_cast<const float4*>(&xs[half*4 + t][k]);
      acc[t] = fmaf(xv.w, w3, fmaf(xv.z, w2, fmaf(xv.y, w1, fmaf(xv.x, w0, acc[t]))));
    }
  }
  #pragma unroll
  for (int t = 0; t < 4; ++t) {
    const int r = n0 + half*4 + t;
    hn[(size_t)r*D_ + j] = acc[t];
    hbn[(size_t)r*D_ + j] = (_Float16)acc[t];
  }
}

// ---------------- node target embeddings ----------------
__global__ __launch_bounds__(128) void k_node_emb(
    const float* __restrict__ h,
    const float* __restrict__ Wq1, const float* __restrict__ bq1,
    const float* __restrict__ Wq2, const float* __restrict__ bq2,
    float* __restrict__ tq_emb, float* __restrict__ tc_emb)
{
  const int bid = blockIdx.x;
  const int b = bid / (2*NMAX_), s = bid - b*(2*NMAX_);
  const bool isQ = s < NMAX_;
  const int r = isQ ? s : s - NMAX_;
  float* outp = (isQ ? tq_emb : tc_emb) + ((size_t)b*NMAX_ + r)*TD_;
  const int tid = threadIdx.x;
  if (isQ && r >= NQ_) {
    if (tid < TD_) outp[tid] = 0.f;
    return;
  }
  const int node = b*NPB_ + (isQ ? r : NQ_ + r);
  __shared__ float xs[D_];
  __shared__ float l1[TD_];
  xs[tid] = h[(size_t)node*D_ + tid];
  __syncthreads();
  if (tid < TD_) {
    float a = bq1[tid];
    for (int k = 0; k < D_; ++k) a = fmaf(xs[k], Wq1[(size_t)k*TD_ + tid], a);
    l1[tid] = fmaxf(a, 0.f);
  }
  __syncthreads();
  if (tid < TD_) {
    float a = bq2[tid];
    #pragma unroll
    for (int k = 0; k < TD_; ++k) a = fmaf(l1[k], Wq2[(size_t)k*TD_ + tid], a);
    outp[tid] = a;
  }
}

// ---------------- sinkhorn over 40x40 node plans ----------------
__global__ __launch_bounds__(256) void k_sinkhorn_n(
    const float* __restrict__ tq_emb, const float* __restrict__ tc_emb,
    float* __restrict__ plan_n)
{
  const int b = blockIdx.x, tid = threadIdx.x;
  __shared__ float la[NMAX_][NMAX_];
  __shared__ float qe[NMAX_][TD_], ce[NMAX_][TD_];
  for (int idx = tid; idx < NMAX_*TD_; idx += 256) {
    qe[idx / TD_][idx % TD_] = tq_emb[(size_t)b*NMAX_*TD_ + idx];
    ce[idx / TD_][idx % TD_] = tc_emb[(size_t)b*NMAX_*TD_ + idx];
  }
  __syncthreads();
  for (int idx = tid; idx < NMAX_*NMAX_; idx += 256) {
    int q = idx / NMAX_, c = idx - q*NMAX_;
    float a = 0.f;
    #pragma unroll
    for (int d = 0; d < TD_; ++d) a = fmaf(qe[q][d], ce[c][d], a);
    la[q][c] = a * L2E10_;
  }
  __syncthreads();
  for (int it = 0; it < ITERS_; ++it) {
    if (tid < NMAX_) {
      float m = -INFINITY;
      for (int c = 0; c < NMAX_; ++c) m = fmaxf(m, la[tid][c]);
      float s = 0.f;
      for (int c = 0; c < NMAX_; ++c) s += ex2(la[tid][c] - m);
      const float lse = m + lg2(s);
      for (int c = 0; c < NMAX_; ++c) la[tid][c] -= lse;
    }
    __syncthreads();
    if (tid < NMAX_) {
      float m = -INFINITY;
      for (int q = 0; q < NMAX_; ++q) m = fmaxf(m, la[q][tid]);
      float s = 0.f;
      for (int q = 0; q < NMAX_; ++q) s += ex2(la[q][tid] - m);
      const float lse = m + lg2(s);
      for (int q = 0; q < NMAX_; ++q) la[q][tid] -= lse;
    }
    __syncthreads();
  }
  for (int idx = tid; idx < NMAX_*NMAX_; idx += 256)
    plan_n[(size_t)b*NMAX_*NMAX_ + idx] = ex2(la[idx / NMAX_][idx % NMAX_]);
}

// ---------------- final edge embed via MFMA ----------------
// 64 edges/block, 4 waves; wave w owns 16 edges in a private 16KB LDS slab.
// es fp16 [16 rows][64 chunks of 8], chunk XOR-swizzled (pos = c ^ (row&7)).
// l1 = relu(es @ WceTh^T + bce) via 16x mfma_16x16x32_f16 (B in 64 VGPRs).
// te = l1 @ We2 + be2 scalar via 1KB l1 overlay.
__global__ __launch_bounds__(256) void k_edge_emb_f(
    const _Float16* __restrict__ FT, const _Float16* __restrict__ E,
    const int* __restrict__ from_idx, const int* __restrict__ to_idx,
    const _Float16* __restrict__ WceTh, const float* __restrict__ bce,
    const float* __restrict__ We2, const float* __restrict__ be2,
    float* __restrict__ teq, float* __restrict__ tec)
{
  __shared__ _Float16 smem[64 * 512];   // 64 KB; wave w owns smem + w*8192
  const int tid = threadIdx.x;
  const int w = tid >> 6, lane = tid & 63;
  const int lr = lane & 15, lk = lane >> 4;
  _Float16* esw = smem + w * 8192;      // 16 rows x 512 (64 chunks x 8)
  const int e0 = blockIdx.x * 64 + w * 16;

  // B-fragments: WceTh[col=lr][k chunk ks*4+lk], 16 x f16x8 = 64 VGPRs
  f16x8 bfrag[16];
  #pragma unroll
  for (int ks = 0; ks < 16; ++ks)
    bfrag[ks] = *(const f16x8*)&WceTh[(size_t)lr*512 + (size_t)(ks*4 + lk)*8];

  // stage 16 edges; iter i = row i; lane covers chunk `lane`, stored at lane^(i&7)
  for (int i = 0; i < 16; ++i) {
    const int ge = e0 + i;
    const int sf = from_idx[ge], st = to_idx[ge];
    const int c8 = lane * 8;
    const f16x8 fa = *(const f16x8*)&FT[(size_t)sf*1024 + c8];
    const f16x8 fb = *(const f16x8*)&FT[(size_t)st*1024 + 512 + c8];
    const f16x8 ev = *(const f16x8*)&E[(size_t)ge*512 + c8];
    f16x8 o;
    #pragma unroll
    for (int k = 0; k < 8; ++k)
      o[k] = (_Float16)fmaxf((float)fa[k] + (float)fb[k] + (float)ev[k], 0.f);
    *(f16x8*)&esw[i*512 + ((lane ^ (i & 7)) * 8)] = o;
  }
  __syncthreads();

  // MFMA: C[16 edges][16 outs] over K=512
  f32x4 acc = {};
  #pragma unroll
  for (int ks = 0; ks < 16; ++ks) {
    const int ch = (ks*4 + lk) ^ (lr & 7);
    const f16x8 af = *(const f16x8*)&esw[lr*512 + ch*8];
    acc = __builtin_amdgcn_mfma_f32_16x16x32_f16(af, bfrag[ks], acc, 0, 0, 0);
  }
  __syncthreads();   // all es reads done; safe to overlay l1

  // l1 = relu(acc + bce): C layout col=lane&15 (jj), row=(lane>>4)*4+v (edge)
  float* l1f = (float*)esw;             // [16 edges][16]
  const float bc = bce[lr];
  #pragma unroll
  for (int v = 0; v < 4; ++v)
    l1f[(lk*4 + v)*16 + lr] = fmaxf(acc[v] + bc, 0.f);
  __syncthreads();

  // te[e][jj] = be2[jj] + sum_k l1[e][k] * We2[k][jj]; lane does e=lk*4+v, jj=lr
  const float b2 = be2[lr];
  #pragma unroll
  for (int v = 0; v < 4; ++v) {
    const int e = lk*4 + v;
    float a = b2;
    #pragma unroll
    for (int k = 0; k < TD_; ++k) a = fmaf(l1f[e*16 + k], We2[(size_t)k*TD_ + lr], a);
    const int ei = e0 + e;
    const int bb = ei / EPB_, jl = ei - bb*EPB_;
    if (jl < EQ_) teq[((size_t)bb*EMAX_ + jl)*TD_ + lr] = a;
    else          tec[((size_t)bb*EMAX_ + (jl - EQ_))*TD_ + lr] = a;
  }
}

// ---------------- fused: escore + sinkhorn_e (registers, base-2) + final score ----------------
__global__ __launch_bounds__(1024) void k_plan_score(
    const float* __restrict__ teq, const float* __restrict__ tec,
    const float* __restrict__ plan_n,
    const float* __restrict__ tq_emb, const float* __restrict__ tc_emb,
    const int* __restrict__ fq, const int* __restrict__ tq,
    const int* __restrict__ fc, const int* __restrict__ tc,
    const float* __restrict__ Wa, const float* __restrict__ ba,
    float* __restrict__ out)
{
  const int b = blockIdx.x, t = threadIdx.x;
  const int tr = t >> 4, tcg = t & 15, lane = t & 63, w = t >> 6;

  __shared__ float shm[8704];    // overlay: {sq,sc} | {wovm,wovs} | epilogue tables
  __shared__ float bcast[256];

  {
    float* sq = shm;             // 256*17
    float* sc = shm + 4352;      // 256*17
    for (int idx = t; idx < 4096; idx += 1024) {
      const int r = idx >> 4, k = idx & 15;
      sq[r*17 + k] = teq[(size_t)b*4096 + idx];
      sc[r*17 + k] = tec[(size_t)b*4096 + idx];
    }
  }
  __syncthreads();

  float la[4][16];
  {
    const float* sq = shm;
    const float* sc = shm + 4352;
    #pragma unroll
    for (int i = 0; i < 4; ++i)
      #pragma unroll
      for (int j = 0; j < 16; ++j) la[i][j] = 0.f;
    for (int k = 0; k < 16; ++k) {
      float qk[4];
      #pragma unroll
      for (int i = 0; i < 4; ++i) qk[i] = sq[(tr*4 + i)*17 + k];
      #pragma unroll
      for (int j = 0; j < 16; ++j) {
        const float sck = sc[(j*16 + tcg)*17 + k];
        #pragma unroll
        for (int i = 0; i < 4; ++i) la[i][j] = fmaf(qk[i], sck, la[i][j]);
      }
    }
    #pragma unroll
    for (int i = 0; i < 4; ++i)
      #pragma unroll
      for (int j = 0; j < 16; ++j) la[i][j] *= L2E10_;
  }
  __syncthreads();

  float* wovm = shm;           // 4096
  float* wovs = shm + 4096;    // 4096

  for (int it = 0; it < ITERS_; ++it) {
    #pragma unroll
    for (int i = 0; i < 4; ++i) {
      float m = la[i][0];
      #pragma unroll
      for (int j = 1; j < 16; ++j) m = fmaxf(m, la[i][j]);
      m = fmaxf(m, __shfl_xor(m, 1)); m = fmaxf(m, __shfl_xor(m, 2));
      m = fmaxf(m, __shfl_xor(m, 4)); m = fmaxf(m, __shfl_xor(m, 8));
      float s = 0.f;
      #pragma unroll
      for (int j = 0; j < 16; ++j) s += ex2(la[i][j] - m);
      s += __shfl_xor(s, 1); s += __shfl_xor(s, 2);
      s += __shfl_xor(s, 4); s += __shfl_xor(s, 8);
      const float lse = m + lg2(s);
      #pragma unroll
      for (int j = 0; j < 16; ++j) la[i][j] -= lse;
    }
    #pragma unroll
    for (int j = 0; j < 16; ++j) {
      float m = fmaxf(fmaxf(la[0][j], la[1][j]), fmaxf(la[2][j], la[3][j]));
      m = fmaxf(m, __shfl_xor(m, 16));
      m = fmaxf(m, __shfl_xor(m, 32));
      float s = ex2(la[0][j] - m) + ex2(la[1][j] - m)
              + ex2(la[2][j] - m) + ex2(la[3][j] - m);
      s += __shfl_xor(s, 16);
      s += __shfl_xor(s, 32);
      if (lane < 16) { wovm[w*256 + j*16 + lane] = m; wovs[w*256 + j*16 + lane] = s; }
    }
    __syncthreads();
    if (t < 256) {
      float M = wovm[t];
      #pragma unroll
      for (int ww = 1; ww < 16; ++ww) M = fmaxf(M, wovm[ww*256 + t]);
      float S = 0.f;
      #pragma unroll
      for (int ww = 0; ww < 16; ++ww) S += wovs[ww*256 + t] * ex2(wovm[ww*256 + t] - M);
      bcast[t] = M + lg2(S);
    }
    __syncthreads();
    #pragma unroll
    for (int j = 0; j < 16; ++j) {
      const float lse = bcast[j*16 + tcg];
      #pragma unroll
      for (int i = 0; i < 4; ++i) la[i][j] -= lse;
    }
  }
  __syncthreads();

  float* pn = shm;                 // 1600
  float* qe = shm + 1600;          // 640
  float* ce = shm + 2240;          // 640
  int*   ib = (int*)(shm + 2880);  // 800 ints
  int* sfq = ib, *stq = ib + 160, *sfc = ib + 320, *stc = ib + 560;
  for (int i = t; i < 1600; i += 1024) pn[i] = plan_n[(size_t)b*1600 + i];
  if (t < 640) { qe[t] = tq_emb[(size_t)b*640 + t]; ce[t] = tc_emb[(size_t)b*640 + t]; }
  if (t < 160) { sfq[t] = fq[b*160 + t]; stq[t] = tq[b*160 + t]; }
  if (t >= 512 && t < 752) { sfc[t-512] = fc[b*240 + (t-512)]; stc[t-512] = tc[b*240 + (t-512)]; }
  __syncthreads();

  float csum = 0.f;
  if (tr < 40) {
    #pragma unroll
    for (int i = 0; i < 4; ++i) {
      const int q = tr*4 + i;
      const int g0 = sfq[q]*NMAX_, g1 = stq[q]*NMAX_;
      #pragma unroll
      for (int j = 0; j < 15; ++j) {
        const int c = j*16 + tcg;
        const float pe = ex2(la[i][j]);
        const float a0 = pn[g0 + sfc[c]] * pn[g1 + stc[c]];
        const float a1 = pn[g0 + stc[c]] * pn[g1 + sfc[c]];
        csum += pe * fmaxf(a0, a1);
      }
    }
  }
  float hsum = 0.f;
  if (t < NMAX_*TD_) {
    const int q = t >> 4, d2 = t & 15;
    float a = 0.f;
    for (int c = 0; c < NMAX_; ++c) a = fmaf(pn[q*NMAX_ + c], ce[c*TD_ + d2], a);
    hsum = fmaxf(qe[t] - a, 0.f);
  }
  #pragma unroll
  for (int off = 32; off; off >>= 1) {
    csum += __shfl_xor(csum, off);
    hsum += __shfl_xor(hsum, off);
  }
  if (lane == 0) { bcast[w] = csum; bcast[32 + w] = hsum; }
  __syncthreads();
  if (t == 0) {
    float C = 0.f, H = 0.f;
    #pragma unroll
    for (int ww = 0; ww < 16; ++ww) { C += bcast[ww]; H += bcast[32 + ww]; }
    out[b] = (-H) * Wa[0] + C * Wa[1] + ba[0];
  }
}

// ---------------- host launcher ----------------
extern "C" void kernel_launch(void* const* d_in, const int* in_sizes, int n_in,
                              void* d_out, int out_size, void* d_ws, size_t ws_size,
                              hipStream_t stream) {
  const float* node_features = (const float*)d_in[0];
  const float* edge_features = (const float*)d_in[1];
  const float* Wn  = (const float*)d_in[2];
  const float* bn  = (const float*)d_in[3];
  const float* We  = (const float*)d_in[4];
  const float* be  = (const float*)d_in[5];
  const float* Wm1 = (const float*)d_in[6];
  const float* bm1 = (const float*)d_in[7];
  const float* Wm2 = (const float*)d_in[8];
  const float* bm2 = (const float*)d_in[9];
  const float* Wr1 = (const float*)d_in[10];
  const float* br1 = (const float*)d_in[11];
  const float* Wr2 = (const float*)d_in[12];
  const float* br2 = (const float*)d_in[13];
  const float* Wu  = (const float*)d_in[14];
  const float* bu  = (const float*)d_in[15];
  const float* Wq1 = (const float*)d_in[16];
  const float* bq1 = (const float*)d_in[17];
  const float* Wq2 = (const float*)d_in[18];
  const float* bq2 = (const float*)d_in[19];
  const float* We1 = (const float*)d_in[20];
  const float* be1 = (const float*)d_in[21];
  const float* We2 = (const float*)d_in[22];
  const float* be2 = (const float*)d_in[23];
  const float* Wa  = (const float*)d_in[24];
  const float* ba  = (const float*)d_in[25];
  const int* fq = (const int*)d_in[26];
  const int* tq = (const int*)d_in[27];
  const int* fc = (const int*)d_in[28];
  const int* tc = (const int*)d_in[29];
  (void)in_sizes; (void)n_in; (void)out_size; (void)ws_size;

  char* ws = (char*)d_ws;
  size_t off = 0;
  auto take = [&](size_t bytes) -> void* {
    void* p = ws + off;
    off = (off + bytes + 255) & ~(size_t)255;
    return p;
  };
  int*   from_idx = (int*)  take((size_t)ETOT_*4);
  int*   to_idx   = (int*)  take((size_t)ETOT_*4);
  int*   in_cnt   = (int*)  take((size_t)NTOT_*4);
  int*   out_cnt  = (int*)  take((size_t)NTOT_*4);
  int*   in_list  = (int*)  take((size_t)NTOT_*DEGCAP_*4);
  int*   out_list = (int*)  take((size_t)NTOT_*DEGCAP_*4);
  float* h0       = (float*)take((size_t)NTOT_*D_*4);
  float* h1       = (float*)take((size_t)NTOT_*D_*4);
  _Float16* hb    = (_Float16*)take((size_t)NTOT_*D_*2);
  _Float16* eb    = (_Float16*)take((size_t)ETOT_*D_*2);
  _Float16* FT    = (_Float16*)take((size_t)NTOT_*1024*2);
  _Float16* Ebuf  = (_Float16*)take((size_t)ETOT_*512*2);
  _Float16* Hsum  = (_Float16*)take((size_t)NTOT_*512*2);
  float* agg      = (float*)take((size_t)NTOT_*256*4);
  float* tq_emb   = (float*)take((size_t)B_*NMAX_*TD_*4);
  float* tc_emb   = (float*)take((size_t)B_*NMAX_*TD_*4);
  float* plan_n   = (float*)take((size_t)B_*NMAX_*NMAX_*4);
  float* teq      = (float*)take((size_t)B_*EMAX_*TD_*4);
  float* tec      = (float*)take((size_t)B_*EMAX_*TD_*4);
  _Float16* W1Tn  = (_Float16*)take((size_t)1024*128*2);
  _Float16* W1Te  = (_Float16*)take((size_t)512*128*2);
  _Float16* W2cT  = (_Float16*)take((size_t)256*512*2);
  float* bcat1    = (float*)take(512*4);
  _Float16* WceTh = (_Float16*)take((size_t)16*512*2);
  float* bce      = (float*)take(16*4);

  k_build_idx<<<(ETOT_ + 255)/256, 256, 0, stream>>>(fq, tq, fc, tc, from_idx, to_idx);
  k_build_lists<<<B_, 256, 0, stream>>>(fq, tq, fc, tc, in_cnt, in_list, out_cnt, out_list);
  k_prep_w<<<(1024*128 + 512*128 + 256*512 + 255)/256, 256, 0, stream>>>(
      Wm1, Wr1, Wm2, Wr2, bm1, br1, W1Tn, W1Te, W2cT, bcat1);
  k_prep_wce<<<32, 256, 0, stream>>>(Wm2, Wr2, We1, bm2, br2, be1, WceTh, bce);
  k_node_enc<<<NTOT_, D_, 0, stream>>>(node_features, Wn, bn, h0, hb);
  k_edge_enc<<<ETOT_, D_, 0, stream>>>(edge_features, We, be, eb);

  dim3 gE(ETOT_/128, 4);
  k_gemm_E<<<gE, 256, 0, stream>>>(eb, W1Te, bcat1, Ebuf);

  dim3 gFT(NTOT_/128, 8);
  dim3 gAG(NTOT_/128, 2);
  float* hc = h0;
  float* hn = h1;
  for (int p = 0; p < NPROP_; ++p) {
    k_gemm_FT<<<gFT, 256, 0, stream>>>(hb, W1Tn, FT);
    k_agg_fused<<<NTOT_, 64, 0, stream>>>(FT, Ebuf, from_idx, to_idx,
                                          in_cnt, in_list, out_cnt, out_list, Hsum);
    k_gemm_agg<<<gAG, 256, 0, stream>>>(Hsum, W2cT, in_cnt, out_cnt, bm2, br2, agg);
    k_update<<<NTOT_/8, 256, 0, stream>>>(hc, agg, Wu, bu, hn, hb);
    float* t_ = hc; hc = hn; hn = t_;
  }

  k_node_emb<<<B_*2*NMAX_, D_, 0, stream>>>(hc, Wq1, bq1, Wq2, bq2, tq_emb, tc_emb);
  k_sinkhorn_n<<<B_, 256, 0, stream>>>(tq_emb, tc_emb, plan_n);

  k_gemm_FT<<<gFT, 256, 0, stream>>>(hb, W1Tn, FT);
  hipMemsetAsync(teq, 0, (size_t)B_*EMAX_*TD_*4, stream);
  hipMemsetAsync(tec, 0, (size_t)B_*EMAX_*TD_*4, stream);
  k_edge_emb_f<<<ETOT_/64, 256, 0, stream>>>(FT, Ebuf, from_idx, to_idx,
                                             WceTh, bce, We2, be2, teq, tec);

  k_plan_score<<<B_, 1024, 0, stream>>>(teq, tec, plan_n, tq_emb, tc_emb,
                                        fq, tq, fc, tc, Wa, ba, (float*)d_out);
}

// Round 10
// 630.232 us; speedup vs baseline: 10.7163x; 1.2685x over previous
//
#include <hip/hip_runtime.h>
#include <cstddef>
#include <cstdint>

// ---------------- problem constants ----------------
constexpr int B_    = 128;
constexpr int NQ_   = 32;
constexpr int NC_   = 40;
constexpr int NMAX_ = 40;
constexpr int EQ_   = 160;
constexpr int EC_   = 240;
constexpr int EMAX_ = 256;
constexpr int D_    = 128;
constexpr int TD_   = 16;
constexpr int NPROP_ = 5;
constexpr int ITERS_ = 20;
constexpr float TEMP_ = 0.1f;
constexpr int NF_   = 32;
constexpr int EF_   = 16;
constexpr int NPB_  = NQ_ + NC_;   // 72 nodes / batch
constexpr int EPB_  = EQ_ + EC_;   // 400 edges / batch
constexpr int NTOT_ = B_ * NPB_;   // 9216
constexpr int ETOT_ = B_ * EPB_;   // 51200
constexpr int DEGCAP_ = 64;
constexpr float L2E10_ = 14.4269504088896f;  // 10 * log2(e)

typedef _Float16 f16x8 __attribute__((ext_vector_type(8)));
typedef _Float16 f16x4 __attribute__((ext_vector_type(4)));
typedef float f32x4 __attribute__((ext_vector_type(4)));

__device__ __forceinline__ void gload16(const void* g, void* l) {
  __builtin_amdgcn_global_load_lds(
      (const __attribute__((address_space(1))) unsigned int*)g,
      (__attribute__((address_space(3))) unsigned int*)l, 16, 0, 0);
}
__device__ __forceinline__ float ex2(float x) { return __builtin_amdgcn_exp2f(x); }
__device__ __forceinline__ float lg2(float x) { return __builtin_amdgcn_logf(x); }

// ---------------- index building ----------------
__global__ __launch_bounds__(256) void k_build_idx(
    const int* __restrict__ fq, const int* __restrict__ tq,
    const int* __restrict__ fc, const int* __restrict__ tc,
    int* __restrict__ from_idx, int* __restrict__ to_idx)
{
  int i = blockIdx.x * blockDim.x + threadIdx.x;
  if (i >= ETOT_) return;
  int b = i / EPB_, j = i - b * EPB_;
  int f, t;
  if (j < EQ_) {
    f = fq[b*EQ_ + j] + b*NPB_;
    t = tq[b*EQ_ + j] + b*NPB_;
  } else {
    int jj = j - EQ_;
    f = fc[b*EC_ + jj] + b*NPB_ + NQ_;
    t = tc[b*EC_ + jj] + b*NPB_ + NQ_;
  }
  from_idx[i] = f;
  to_idx[i]   = t;
}

// ---------------- per-node edge lists (deterministic ascending order) ----------------
__global__ __launch_bounds__(256) void k_build_lists(
    const int* __restrict__ fq, const int* __restrict__ tq,
    const int* __restrict__ fc, const int* __restrict__ tc,
    int* __restrict__ in_cnt, int* __restrict__ in_list,
    int* __restrict__ out_cnt, int* __restrict__ out_list)
{
  const int b = blockIdx.x, tid = threadIdx.x;
  __shared__ short sf[EPB_], st[EPB_];
  for (int j = tid; j < EPB_; j += 256) {
    int f, t;
    if (j < EQ_) { f = fq[b*EQ_ + j];              t = tq[b*EQ_ + j]; }
    else         { f = fc[b*EC_ + (j-EQ_)] + NQ_;  t = tc[b*EC_ + (j-EQ_)] + NQ_; }
    sf[j] = (short)f; st[j] = (short)t;
  }
  __syncthreads();
  if (tid < NPB_) {
    const int g = b*NPB_ + tid;
    int ic = 0, oc = 0;
    for (int j = 0; j < EPB_; ++j) {
      if ((int)st[j] == tid && ic < DEGCAP_) in_list[g*DEGCAP_ + (ic++)] = j;
      if ((int)sf[j] == tid && oc < DEGCAP_) out_list[g*DEGCAP_ + (oc++)] = j;
    }
    in_cnt[g] = ic; out_cnt[g] = oc;
  }
}

// ---------------- weight prep: W1Tn, W1Te, bcat1 ----------------
__global__ __launch_bounds__(256) void k_prep_w(
    const float* __restrict__ Wm1, const float* __restrict__ Wr1,
    const float* __restrict__ bm1, const float* __restrict__ br1,
    _Float16* __restrict__ W1Tn, _Float16* __restrict__ W1Te,
    float* __restrict__ bcat1)
{
  int i = blockIdx.x * 256 + threadIdx.x;
  if (i < 1024*128) {
    int n = i >> 7, k = i & 127;
    float v;
    if (n < 512) {            // F-part: W1 row k
      v = (n < 256) ? Wm1[(size_t)k*256 + n]
                    : Wr1[(size_t)(k + 128)*256 + (n - 256)];
    } else {                  // T-part: W1 row 128+k
      int n2 = n - 512;
      v = (n2 < 256) ? Wm1[(size_t)(128 + k)*256 + n2]
                     : Wr1[(size_t)k*256 + (n2 - 256)];
    }
    W1Tn[i] = (_Float16)v;
  }
  int j = i - 1024*128;
  if (j >= 0 && j < 512*128) {
    int n = j >> 7, k = j & 127;   // W1 row 256+k
    float v = (n < 256) ? Wm1[(size_t)(256 + k)*256 + n]
                        : Wr1[(size_t)(256 + k)*256 + (n - 256)];
    W1Te[j] = (_Float16)v;
  }
  if (i < 512) bcat1[i] = (i < 256) ? bm1[i] : br1[i - 256];
}

// ---------------- fused update-weight prep ----------------
// WuT[n][640]: k<128 -> Wu[k][n]; k>=128 -> W2u[j=k-128][n] = sum_m W2c[j][m]*Wu[128+m][n]
// c1[n] = bm2 @ Wu_bot[:,n]; c2[n] = br2 @ Wu_bot[:,n]
__global__ __launch_bounds__(256) void k_prep_wu(
    const float* __restrict__ Wm2, const float* __restrict__ Wr2,
    const float* __restrict__ Wu,
    const float* __restrict__ bm2, const float* __restrict__ br2,
    _Float16* __restrict__ WuT, float* __restrict__ c1, float* __restrict__ c2)
{
  int i = blockIdx.x * 256 + threadIdx.x;
  if (i < 128*640) {
    int n = i / 640, k = i - n*640;
    float v;
    if (k < 128) {
      v = Wu[(size_t)k*128 + n];
    } else {
      const int j = k - 128;
      v = 0.f;
      if (j < 256) {
        for (int m = 0; m < 256; ++m)
          v = fmaf(Wm2[(size_t)j*256 + m], Wu[(size_t)(128+m)*128 + n], v);
      } else {
        for (int m = 0; m < 256; ++m)
          v = fmaf(Wr2[(size_t)(j-256)*256 + m], Wu[(size_t)(128+m)*128 + n], v);
      }
    }
    WuT[i] = (_Float16)v;
  }
  if (i < 128) {
    float a1 = 0.f, a2 = 0.f;
    for (int m = 0; m < 256; ++m) {
      const float wu = Wu[(size_t)(128+m)*128 + i];
      a1 = fmaf(bm2[m], wu, a1);
      a2 = fmaf(br2[m], wu, a2);
    }
    c1[i] = a1; c2[i] = a2;
  }
}

// WceTh[16][512] = fp16((W2cat @ We1)^T) ; bce[16] = (bm2+br2)@We1 + be1
__global__ __launch_bounds__(256) void k_prep_wce(
    const float* __restrict__ Wm2, const float* __restrict__ Wr2,
    const float* __restrict__ We1, const float* __restrict__ bm2,
    const float* __restrict__ br2, const float* __restrict__ be1,
    _Float16* __restrict__ WceTh, float* __restrict__ bce)
{
  int i = blockIdx.x * 256 + threadIdx.x;
  if (i < 16*512) {
    int j = i >> 9, k = i & 511;
    float a = 0.f;
    for (int m = 0; m < 256; ++m) {
      const float w2 = (k < 256) ? Wm2[(size_t)k*256 + m] : Wr2[(size_t)(k-256)*256 + m];
      a = fmaf(w2, We1[(size_t)m*TD_ + j], a);
    }
    WceTh[(size_t)j*512 + k] = (_Float16)a;
  }
  if (i < 16) {
    float a = be1[i];
    for (int m = 0; m < 256; ++m) a = fmaf(bm2[m] + br2[m], We1[(size_t)m*TD_ + i], a);
    bce[i] = a;
  }
}

// ---------------- encoders ----------------
__global__ __launch_bounds__(128) void k_node_enc(
    const float* __restrict__ nf, const float* __restrict__ Wn,
    const float* __restrict__ bn, float* __restrict__ h, _Float16* __restrict__ hb)
{
  int n = blockIdx.x, j = threadIdx.x;
  __shared__ float xs[NF_];
  if (j < NF_) xs[j] = nf[(size_t)n*NF_ + j];
  __syncthreads();
  float a = bn[j];
  #pragma unroll
  for (int k = 0; k < NF_; ++k) a = fmaf(xs[k], Wn[(size_t)k*D_ + j], a);
  h[(size_t)n*D_ + j] = a;
  hb[(size_t)n*D_ + j] = (_Float16)a;
}

__global__ __launch_bounds__(128) void k_edge_enc(
    const float* __restrict__ ef, const float* __restrict__ We,
    const float* __restrict__ be, _Float16* __restrict__ eb)
{
  int i = blockIdx.x, j = threadIdx.x;
  __shared__ float xs[EF_];
  if (j < EF_) xs[j] = ef[(size_t)i*EF_ + j];
  __syncthreads();
  float a = be[j];
  #pragma unroll
  for (int k = 0; k < EF_; ++k) a = fmaf(xs[k], We[(size_t)k*D_ + j], a);
  eb[(size_t)i*D_ + j] = (_Float16)a;
}

// ---------------- GEMM: FT = hb @ W1Tn  (M=9216, N=1024, K=128) ----------------
__global__ __launch_bounds__(256) void k_gemm_FT(
    const _Float16* __restrict__ A, const _Float16* __restrict__ Bm,
    _Float16* __restrict__ FT)
{
  const int m0 = blockIdx.x * 128, n0 = blockIdx.y * 128;
  __shared__ _Float16 As[128*64], Bs[128*64];
  const int tid = threadIdx.x;
  const int srow = tid >> 3, slot = tid & 7;
  const int wave = tid >> 6, lane = tid & 63;
  const int wm = wave >> 1, wn = wave & 1;
  const int lr = lane & 15, lk = lane >> 4;
  f32x4 acc[4][4] = {};
  for (int kt = 0; kt < 2; ++kt) {
    __syncthreads();
    #pragma unroll
    for (int i = 0; i < 4; ++i) {
      const int r = srow + 32*i;
      const int ss = slot ^ (r & 7);
      gload16(A + (size_t)(m0 + r)*128 + kt*64 + ss*8, &As[r*64 + slot*8]);
      gload16(Bm + (size_t)(n0 + r)*128 + kt*64 + ss*8, &Bs[r*64 + slot*8]);
    }
    __syncthreads();
    #pragma unroll
    for (int ks = 0; ks < 2; ++ks) {
      f16x8 af[4], bfr[4];
      #pragma unroll
      for (int mf = 0; mf < 4; ++mf) {
        const int r = wm*64 + mf*16 + lr;
        const int ch = (ks*4 + lk) ^ (r & 7);
        af[mf] = *(const f16x8*)&As[r*64 + ch*8];
      }
      #pragma unroll
      for (int nf = 0; nf < 4; ++nf) {
        const int n = wn*64 + nf*16 + lr;
        const int ch = (ks*4 + lk) ^ (n & 7);
        bfr[nf] = *(const f16x8*)&Bs[n*64 + ch*8];
      }
      #pragma unroll
      for (int mf = 0; mf < 4; ++mf)
        #pragma unroll
        for (int nf = 0; nf < 4; ++nf)
          acc[mf][nf] = __builtin_amdgcn_mfma_f32_16x16x32_f16(af[mf], bfr[nf], acc[mf][nf], 0, 0, 0);
    }
  }
  #pragma unroll
  for (int nf = 0; nf < 4; ++nf) {
    const int c = n0 + wn*64 + nf*16 + lr;
    #pragma unroll
    for (int mf = 0; mf < 4; ++mf)
      #pragma unroll
      for (int v = 0; v < 4; ++v) {
        const int r = m0 + wm*64 + mf*16 + lk*4 + v;
        FT[(size_t)r*1024 + c] = (_Float16)acc[mf][nf][v];
      }
  }
}

// ---------------- GEMM: E = eb @ W1Te + bcat1  (M=51200, N=512, K=128) ----------------
__global__ __launch_bounds__(256) void k_gemm_E(
    const _Float16* __restrict__ A, const _Float16* __restrict__ Bm,
    const float* __restrict__ bcat1, _Float16* __restrict__ E)
{
  const int m0 = blockIdx.x * 128, n0 = blockIdx.y * 128;
  __shared__ _Float16 As[128*64], Bs[128*64];
  const int tid = threadIdx.x;
  const int srow = tid >> 3, slot = tid & 7;
  const int wave = tid >> 6, lane = tid & 63;
  const int wm = wave >> 1, wn = wave & 1;
  const int lr = lane & 15, lk = lane >> 4;
  f32x4 acc[4][4] = {};
  for (int kt = 0; kt < 2; ++kt) {
    __syncthreads();
    #pragma unroll
    for (int i = 0; i < 4; ++i) {
      const int r = srow + 32*i;
      const int ss = slot ^ (r & 7);
      gload16(A + (size_t)(m0 + r)*128 + kt*64 + ss*8, &As[r*64 + slot*8]);
      gload16(Bm + (size_t)(n0 + r)*128 + kt*64 + ss*8, &Bs[r*64 + slot*8]);
    }
    __syncthreads();
    #pragma unroll
    for (int ks = 0; ks < 2; ++ks) {
      f16x8 af[4], bfr[4];
      #pragma unroll
      for (int mf = 0; mf < 4; ++mf) {
        const int r = wm*64 + mf*16 + lr;
        const int ch = (ks*4 + lk) ^ (r & 7);
        af[mf] = *(const f16x8*)&As[r*64 + ch*8];
      }
      #pragma unroll
      for (int nf = 0; nf < 4; ++nf) {
        const int n = wn*64 + nf*16 + lr;
        const int ch = (ks*4 + lk) ^ (n & 7);
        bfr[nf] = *(const f16x8*)&Bs[n*64 + ch*8];
      }
      #pragma unroll
      for (int mf = 0; mf < 4; ++mf)
        #pragma unroll
        for (int nf = 0; nf < 4; ++nf)
          acc[mf][nf] = __builtin_amdgcn_mfma_f32_16x16x32_f16(af[mf], bfr[nf], acc[mf][nf], 0, 0, 0);
    }
  }
  #pragma unroll
  for (int nf = 0; nf < 4; ++nf) {
    const int c = n0 + wn*64 + nf*16 + lr;
    const float bias = bcat1[c];
    #pragma unroll
    for (int mf = 0; mf < 4; ++mf)
      #pragma unroll
      for (int v = 0; v < 4; ++v) {
        const int r = m0 + wm*64 + mf*16 + lk*4 + v;
        E[(size_t)r*512 + c] = (_Float16)(acc[mf][nf][v] + bias);
      }
  }
}

// ---------------- fused hidden + deterministic segment-sum (1 wave/node, f16x8) ----------------
__global__ __launch_bounds__(64) void k_agg_fused(
    const _Float16* __restrict__ FT, const _Float16* __restrict__ E,
    const int* __restrict__ from_idx, const int* __restrict__ to_idx,
    const int* __restrict__ in_cnt, const int* __restrict__ in_list,
    const int* __restrict__ out_cnt, const int* __restrict__ out_list,
    _Float16* __restrict__ Hsum)
{
  const int g = blockIdx.x;
  const int b = g / NPB_;
  const int lane = threadIdx.x;
  const int half = lane >> 5;          // 0 = in, 1 = out
  const int c8 = (lane & 31) * 8;      // element offset within 256
  const int ebase = b * EPB_;
  const size_t ftg = (size_t)g * 1024;

  const f16x8 base = (half == 0) ? *(const f16x8*)&FT[ftg + 512 + c8]    // T[n]
                                 : *(const f16x8*)&FT[ftg + 256 + c8];   // F[n] (r-part)
  const int cnt = (half == 0) ? in_cnt[g] : out_cnt[g];
  const int* lst = (half == 0) ? &in_list[(size_t)g*DEGCAP_] : &out_list[(size_t)g*DEGCAP_];
  const int eoff = half * 256;
  const int foff = (half == 0) ? 0 : 768;

  float acc[8] = {};
  for (int i = 0; i < cnt; ++i) {
    const int ge = ebase + lst[i];
    const int other = (half == 0) ? from_idx[ge] : to_idx[ge];
    const f16x8 fo = *(const f16x8*)&FT[(size_t)other*1024 + foff + c8];
    const f16x8 ev = *(const f16x8*)&E[(size_t)ge*512 + eoff + c8];
    #pragma unroll
    for (int k = 0; k < 8; ++k)
      acc[k] += fmaxf((float)base[k] + (float)fo[k] + (float)ev[k], 0.f);
  }
  f16x8 o;
  #pragma unroll
  for (int k = 0; k < 8; ++k) o[k] = (_Float16)acc[k];
  *(f16x8*)&Hsum[(size_t)g*512 + eoff + c8] = o;
}

// ---------------- fused GEMM: hn = [hb | Hsum] @ WuT + ic*c1 + oc*c2 + bu ----------------
// M=9216, N=128, K=640.  Replaces gemm_agg + update.
__global__ __launch_bounds__(256) void k_gemm_upd(
    const _Float16* __restrict__ hb, const _Float16* __restrict__ Hsum,
    const _Float16* __restrict__ WuT,
    const int* __restrict__ in_cnt, const int* __restrict__ out_cnt,
    const float* __restrict__ c1, const float* __restrict__ c2,
    const float* __restrict__ bu,
    float* __restrict__ hn, _Float16* __restrict__ hbn)
{
  const int m0 = blockIdx.x * 128;
  __shared__ _Float16 As[128*64], Bs[128*64];
  const int tid = threadIdx.x;
  const int srow = tid >> 3, slot = tid & 7;
  const int wave = tid >> 6, lane = tid & 63;
  const int wm = wave >> 1, wn = wave & 1;
  const int lr = lane & 15, lk = lane >> 4;
  f32x4 acc[4][4] = {};
  for (int kt = 0; kt < 10; ++kt) {
    __syncthreads();
    #pragma unroll
    for (int i = 0; i < 4; ++i) {
      const int r = srow + 32*i;
      const int ss = slot ^ (r & 7);
      const _Float16* asrc = (kt < 2)
          ? hb   + (size_t)(m0 + r)*128 + kt*64 + ss*8
          : Hsum + (size_t)(m0 + r)*512 + (kt - 2)*64 + ss*8;
      gload16(asrc, &As[r*64 + slot*8]);
      gload16(WuT + (size_t)r*640 + kt*64 + ss*8, &Bs[r*64 + slot*8]);
    }
    __syncthreads();
    #pragma unroll
    for (int ks = 0; ks < 2; ++ks) {
      f16x8 af[4], bfr[4];
      #pragma unroll
      for (int mf = 0; mf < 4; ++mf) {
        const int r = wm*64 + mf*16 + lr;
        const int ch = (ks*4 + lk) ^ (r & 7);
        af[mf] = *(const f16x8*)&As[r*64 + ch*8];
      }
      #pragma unroll
      for (int nf = 0; nf < 4; ++nf) {
        const int n = wn*64 + nf*16 + lr;
        const int ch = (ks*4 + lk) ^ (n & 7);
        bfr[nf] = *(const f16x8*)&Bs[n*64 + ch*8];
      }
      #pragma unroll
      for (int mf = 0; mf < 4; ++mf)
        #pragma unroll
        for (int nf = 0; nf < 4; ++nf)
          acc[mf][nf] = __builtin_amdgcn_mfma_f32_16x16x32_f16(af[mf], bfr[nf], acc[mf][nf], 0, 0, 0);
    }
  }
  // epilogue: N=128 -> cols (wn*64 + nf*16 + lr) in [0,128)
  #pragma unroll
  for (int nf = 0; nf < 4; ++nf) {
    const int c = wn*64 + nf*16 + lr;
    const float b1 = c1[c], b2 = c2[c], b0 = bu[c];
    #pragma unroll
    for (int mf = 0; mf < 4; ++mf)
      #pragma unroll
      for (int v = 0; v < 4; ++v) {
        const int r = m0 + wm*64 + mf*16 + lk*4 + v;
        const float o = acc[mf][nf][v] + in_cnt[r]*b1 + out_cnt[r]*b2 + b0;
        hn[(size_t)r*128 + c] = o;
        hbn[(size_t)r*128 + c] = (_Float16)o;
      }
  }
}

// ---------------- node target embeddings ----------------
__global__ __launch_bounds__(128) void k_node_emb(
    const float* __restrict__ h,
    const float* __restrict__ Wq1, const float* __restrict__ bq1,
    const float* __restrict__ Wq2, const float* __restrict__ bq2,
    float* __restrict__ tq_emb, float* __restrict__ tc_emb)
{
  const int bid = blockIdx.x;
  const int b = bid / (2*NMAX_), s = bid - b*(2*NMAX_);
  const bool isQ = s < NMAX_;
  const int r = isQ ? s : s - NMAX_;
  float* outp = (isQ ? tq_emb : tc_emb) + ((size_t)b*NMAX_ + r)*TD_;
  const int tid = threadIdx.x;
  if (isQ && r >= NQ_) {
    if (tid < TD_) outp[tid] = 0.f;
    return;
  }
  const int node = b*NPB_ + (isQ ? r : NQ_ + r);
  __shared__ float xs[D_];
  __shared__ float l1[TD_];
  xs[tid] = h[(size_t)node*D_ + tid];
  __syncthreads();
  if (tid < TD_) {
    float a = bq1[tid];
    for (int k = 0; k < D_; ++k) a = fmaf(xs[k], Wq1[(size_t)k*TD_ + tid], a);
    l1[tid] = fmaxf(a, 0.f);
  }
  __syncthreads();
  if (tid < TD_) {
    float a = bq2[tid];
    #pragma unroll
    for (int k = 0; k < TD_; ++k) a = fmaf(l1[k], Wq2[(size_t)k*TD_ + tid], a);
    outp[tid] = a;
  }
}

// ---------------- sinkhorn over 40x40 node plans ----------------
__global__ __launch_bounds__(256) void k_sinkhorn_n(
    const float* __restrict__ tq_emb, const float* __restrict__ tc_emb,
    float* __restrict__ plan_n)
{
  const int b = blockIdx.x, tid = threadIdx.x;
  __shared__ float la[NMAX_][NMAX_];
  __shared__ float qe[NMAX_][TD_], ce[NMAX_][TD_];
  for (int idx = tid; idx < NMAX_*TD_; idx += 256) {
    qe[idx / TD_][idx % TD_] = tq_emb[(size_t)b*NMAX_*TD_ + idx];
    ce[idx / TD_][idx % TD_] = tc_emb[(size_t)b*NMAX_*TD_ + idx];
  }
  __syncthreads();
  for (int idx = tid; idx < NMAX_*NMAX_; idx += 256) {
    int q = idx / NMAX_, c = idx - q*NMAX_;
    float a = 0.f;
    #pragma unroll
    for (int d = 0; d < TD_; ++d) a = fmaf(qe[q][d], ce[c][d], a);
    la[q][c] = a * L2E10_;
  }
  __syncthreads();
  for (int it = 0; it < ITERS_; ++it) {
    if (tid < NMAX_) {
      float m = -INFINITY;
      for (int c = 0; c < NMAX_; ++c) m = fmaxf(m, la[tid][c]);
      float s = 0.f;
      for (int c = 0; c < NMAX_; ++c) s += ex2(la[tid][c] - m);
      const float lse = m + lg2(s);
      for (int c = 0; c < NMAX_; ++c) la[tid][c] -= lse;
    }
    __syncthreads();
    if (tid < NMAX_) {
      float m = -INFINITY;
      for (int q = 0; q < NMAX_; ++q) m = fmaxf(m, la[q][tid]);
      float s = 0.f;
      for (int q = 0; q < NMAX_; ++q) s += ex2(la[q][tid] - m);
      const float lse = m + lg2(s);
      for (int q = 0; q < NMAX_; ++q) la[q][tid] -= lse;
    }
    __syncthreads();
  }
  for (int idx = tid; idx < NMAX_*NMAX_; idx += 256)
    plan_n[(size_t)b*NMAX_*NMAX_ + idx] = ex2(la[idx / NMAX_][idx % NMAX_]);
}

// ---------------- final edge embed via MFMA ----------------
__global__ __launch_bounds__(256) void k_edge_emb_f(
    const _Float16* __restrict__ FT, const _Float16* __restrict__ E,
    const int* __restrict__ from_idx, const int* __restrict__ to_idx,
    const _Float16* __restrict__ WceTh, const float* __restrict__ bce,
    const float* __restrict__ We2, const float* __restrict__ be2,
    float* __restrict__ teq, float* __restrict__ tec)
{
  __shared__ _Float16 smem[64 * 512];   // 64 KB; wave w owns smem + w*8192
  const int tid = threadIdx.x;
  const int w = tid >> 6, lane = tid & 63;
  const int lr = lane & 15, lk = lane >> 4;
  _Float16* esw = smem + w * 8192;      // 16 rows x 512 (64 chunks x 8)
  const int e0 = blockIdx.x * 64 + w * 16;

  f16x8 bfrag[16];
  #pragma unroll
  for (int ks = 0; ks < 16; ++ks)
    bfrag[ks] = *(const f16x8*)&WceTh[(size_t)lr*512 + (size_t)(ks*4 + lk)*8];

  for (int i = 0; i < 16; ++i) {
    const int ge = e0 + i;
    const int sf = from_idx[ge], st = to_idx[ge];
    const int c8 = lane * 8;
    const f16x8 fa = *(const f16x8*)&FT[(size_t)sf*1024 + c8];
    const f16x8 fb = *(const f16x8*)&FT[(size_t)st*1024 + 512 + c8];
    const f16x8 ev = *(const f16x8*)&E[(size_t)ge*512 + c8];
    f16x8 o;
    #pragma unroll
    for (int k = 0; k < 8; ++k)
      o[k] = (_Float16)fmaxf((float)fa[k] + (float)fb[k] + (float)ev[k], 0.f);
    *(f16x8*)&esw[i*512 + ((lane ^ (i & 7)) * 8)] = o;
  }
  __syncthreads();

  f32x4 acc = {};
  #pragma unroll
  for (int ks = 0; ks < 16; ++ks) {
    const int ch = (ks*4 + lk) ^ (lr & 7);
    const f16x8 af = *(const f16x8*)&esw[lr*512 + ch*8];
    acc = __builtin_amdgcn_mfma_f32_16x16x32_f16(af, bfrag[ks], acc, 0, 0, 0);
  }
  __syncthreads();

  float* l1f = (float*)esw;
  const float bc = bce[lr];
  #pragma unroll
  for (int v = 0; v < 4; ++v)
    l1f[(lk*4 + v)*16 + lr] = fmaxf(acc[v] + bc, 0.f);
  __syncthreads();

  const float b2 = be2[lr];
  #pragma unroll
  for (int v = 0; v < 4; ++v) {
    const int e = lk*4 + v;
    float a = b2;
    #pragma unroll
    for (int k = 0; k < TD_; ++k) a = fmaf(l1f[e*16 + k], We2[(size_t)k*TD_ + lr], a);
    const int ei = e0 + e;
    const int bb = ei / EPB_, jl = ei - bb*EPB_;
    if (jl < EQ_) teq[((size_t)bb*EMAX_ + jl)*TD_ + lr] = a;
    else          tec[((size_t)bb*EMAX_ + (jl - EQ_))*TD_ + lr] = a;
  }
}

// ---------------- fused: escore + sinkhorn_e (registers, base-2, no col-max) + final score --------
__global__ __launch_bounds__(1024) void k_plan_score(
    const float* __restrict__ teq, const float* __restrict__ tec,
    const float* __restrict__ plan_n,
    const float* __restrict__ tq_emb, const float* __restrict__ tc_emb,
    const int* __restrict__ fq, const int* __restrict__ tq,
    const int* __restrict__ fc, const int* __restrict__ tc,
    const float* __restrict__ Wa, const float* __restrict__ ba,
    float* __restrict__ out)
{
  const int b = blockIdx.x, t = threadIdx.x;
  const int tr = t >> 4, tcg = t & 15, lane = t & 63, w = t >> 6;

  __shared__ float shm[8704];    // overlay: {sq,sc} | wovs | epilogue tables
  __shared__ float bcast[256];

  {
    float* sq = shm;             // 256*17
    float* sc = shm + 4352;      // 256*17
    for (int idx = t; idx < 4096; idx += 1024) {
      const int r = idx >> 4, k = idx & 15;
      sq[r*17 + k] = teq[(size_t)b*4096 + idx];
      sc[r*17 + k] = tec[(size_t)b*4096 + idx];
    }
  }
  __syncthreads();

  float la[4][16];
  {
    const float* sq = shm;
    const float* sc = shm + 4352;
    #pragma unroll
    for (int i = 0; i < 4; ++i)
      #pragma unroll
      for (int j = 0; j < 16; ++j) la[i][j] = 0.f;
    for (int k = 0; k < 16; ++k) {
      float qk[4];
      #pragma unroll
      for (int i = 0; i < 4; ++i) qk[i] = sq[(tr*4 + i)*17 + k];
      #pragma unroll
      for (int j = 0; j < 16; ++j) {
        const float sck = sc[(j*16 + tcg)*17 + k];
        #pragma unroll
        for (int i = 0; i < 4; ++i) la[i][j] = fmaf(qk[i], sck, la[i][j]);
      }
    }
    #pragma unroll
    for (int i = 0; i < 4; ++i)
      #pragma unroll
      for (int j = 0; j < 16; ++j) la[i][j] *= L2E10_;
  }
  __syncthreads();   // sq/sc dead; shm reused as wovs

  float* wovs = shm;           // 4096

  for (int it = 0; it < ITERS_; ++it) {
    // ---- row LSE (16 consecutive lanes per row); tree reductions ----
    #pragma unroll
    for (int i = 0; i < 4; ++i) {
      float m = fmaxf(
        fmaxf(fmaxf(fmaxf(la[i][0],la[i][1]), fmaxf(la[i][2],la[i][3])),
              fmaxf(fmaxf(la[i][4],la[i][5]), fmaxf(la[i][6],la[i][7]))),
        fmaxf(fmaxf(fmaxf(la[i][8],la[i][9]), fmaxf(la[i][10],la[i][11])),
              fmaxf(fmaxf(la[i][12],la[i][13]), fmaxf(la[i][14],la[i][15]))));
      m = fmaxf(m, __shfl_xor(m, 1)); m = fmaxf(m, __shfl_xor(m, 2));
      m = fmaxf(m, __shfl_xor(m, 4)); m = fmaxf(m, __shfl_xor(m, 8));
      float p[16];
      #pragma unroll
      for (int j = 0; j < 16; ++j) p[j] = ex2(la[i][j] - m);
      float s = (((p[0]+p[1]) + (p[2]+p[3])) + ((p[4]+p[5]) + (p[6]+p[7])))
              + (((p[8]+p[9]) + (p[10]+p[11])) + ((p[12]+p[13]) + (p[14]+p[15])));
      s += __shfl_xor(s, 1); s += __shfl_xor(s, 2);
      s += __shfl_xor(s, 4); s += __shfl_xor(s, 8);
      const float lse = m + lg2(s);
      #pragma unroll
      for (int j = 0; j < 16; ++j) la[i][j] -= lse;
    }
    // ---- col sums: la <= 0 after row norm -> no max needed ----
    #pragma unroll
    for (int j = 0; j < 16; ++j) {
      float s = (ex2(la[0][j]) + ex2(la[1][j])) + (ex2(la[2][j]) + ex2(la[3][j]));
      s += __shfl_xor(s, 16);
      s += __shfl_xor(s, 32);
      if (lane < 16) wovs[w*256 + j*16 + lane] = s;
    }
    __syncthreads();
    if (t < 256) {
      float s0 = 0.f, s1 = 0.f, s2 = 0.f, s3 = 0.f;
      #pragma unroll
      for (int ww = 0; ww < 16; ww += 4) {
        s0 += wovs[(ww+0)*256 + t];
        s1 += wovs[(ww+1)*256 + t];
        s2 += wovs[(ww+2)*256 + t];
        s3 += wovs[(ww+3)*256 + t];
      }
      bcast[t] = lg2(fmaxf((s0 + s1) + (s2 + s3), 1e-30f));
    }
    __syncthreads();
    #pragma unroll
    for (int j = 0; j < 16; ++j) {
      const float lse = bcast[j*16 + tcg];
      #pragma unroll
      for (int i = 0; i < 4; ++i) la[i][j] -= lse;
    }
  }
  __syncthreads();

  // ---- epilogue: overlay pn/qe/ce/indices into shm ----
  float* pn = shm;                 // 1600
  float* qe = shm + 1600;          // 640
  float* ce = shm + 2240;          // 640
  int*   ib = (int*)(shm + 2880);  // 800 ints
  int* sfq = ib, *stq = ib + 160, *sfc = ib + 320, *stc = ib + 560;
  for (int i = t; i < 1600; i += 1024) pn[i] = plan_n[(size_t)b*1600 + i];
  if (t < 640) { qe[t] = tq_emb[(size_t)b*640 + t]; ce[t] = tc_emb[(size_t)b*640 + t]; }
  if (t < 160) { sfq[t] = fq[b*160 + t]; stq[t] = tq[b*160 + t]; }
  if (t >= 512 && t < 752) { sfc[t-512] = fc[b*240 + (t-512)]; stc[t-512] = tc[b*240 + (t-512)]; }
  __syncthreads();

  float csum = 0.f;
  if (tr < 40) {
    #pragma unroll
    for (int i = 0; i < 4; ++i) {
      const int q = tr*4 + i;
      const int g0 = sfq[q]*NMAX_, g1 = stq[q]*NMAX_;
      #pragma unroll
      for (int j = 0; j < 15; ++j) {
        const int c = j*16 + tcg;
        const float pe = ex2(la[i][j]);
        const float a0 = pn[g0 + sfc[c]] * pn[g1 + stc[c]];
        const float a1 = pn[g0 + stc[c]] * pn[g1 + sfc[c]];
        csum += pe * fmaxf(a0, a1);
      }
    }
  }
  float hsum = 0.f;
  if (t < NMAX_*TD_) {
    const int q = t >> 4, d2 = t & 15;
    float a = 0.f;
    for (int c = 0; c < NMAX_; ++c) a = fmaf(pn[q*NMAX_ + c], ce[c*TD_ + d2], a);
    hsum = fmaxf(qe[t] - a, 0.f);
  }
  #pragma unroll
  for (int off = 32; off; off >>= 1) {
    csum += __shfl_xor(csum, off);
    hsum += __shfl_xor(hsum, off);
  }
  if (lane == 0) { bcast[w] = csum; bcast[32 + w] = hsum; }
  __syncthreads();
  if (t == 0) {
    float C = 0.f, H = 0.f;
    #pragma unroll
    for (int ww = 0; ww < 16; ++ww) { C += bcast[ww]; H += bcast[32 + ww]; }
    out[b] = (-H) * Wa[0] + C * Wa[1] + ba[0];
  }
}

// ---------------- host launcher ----------------
extern "C" void kernel_launch(void* const* d_in, const int* in_sizes, int n_in,
                              void* d_out, int out_size, void* d_ws, size_t ws_size,
                              hipStream_t stream) {
  const float* node_features = (const float*)d_in[0];
  const float* edge_features = (const float*)d_in[1];
  const float* Wn  = (const float*)d_in[2];
  const float* bn  = (const float*)d_in[3];
  const float* We  = (const float*)d_in[4];
  const float* be  = (const float*)d_in[5];
  const float* Wm1 = (const float*)d_in[6];
  const float* bm1 = (const float*)d_in[7];
  const float* Wm2 = (const float*)d_in[8];
  const float* bm2 = (const float*)d_in[9];
  const float* Wr1 = (const float*)d_in[10];
  const float* br1 = (const float*)d_in[11];
  const float* Wr2 = (const float*)d_in[12];
  const float* br2 = (const float*)d_in[13];
  const float* Wu  = (const float*)d_in[14];
  const float* bu  = (const float*)d_in[15];
  const float* Wq1 = (const float*)d_in[16];
  const float* bq1 = (const float*)d_in[17];
  const float* Wq2 = (const float*)d_in[18];
  const float* bq2 = (const float*)d_in[19];
  const float* We1 = (const float*)d_in[20];
  const float* be1 = (const float*)d_in[21];
  const float* We2 = (const float*)d_in[22];
  const float* be2 = (const float*)d_in[23];
  const float* Wa  = (const float*)d_in[24];
  const float* ba  = (const float*)d_in[25];
  const int* fq = (const int*)d_in[26];
  const int* tq = (const int*)d_in[27];
  const int* fc = (const int*)d_in[28];
  const int* tc = (const int*)d_in[29];
  (void)in_sizes; (void)n_in; (void)out_size; (void)ws_size;

  char* ws = (char*)d_ws;
  size_t off = 0;
  auto take = [&](size_t bytes) -> void* {
    void* p = ws + off;
    off = (off + bytes + 255) & ~(size_t)255;
    return p;
  };
  int*   from_idx = (int*)  take((size_t)ETOT_*4);
  int*   to_idx   = (int*)  take((size_t)ETOT_*4);
  int*   in_cnt   = (int*)  take((size_t)NTOT_*4);
  int*   out_cnt  = (int*)  take((size_t)NTOT_*4);
  int*   in_list  = (int*)  take((size_t)NTOT_*DEGCAP_*4);
  int*   out_list = (int*)  take((size_t)NTOT_*DEGCAP_*4);
  float* h0       = (float*)take((size_t)NTOT_*D_*4);
  float* h1       = (float*)take((size_t)NTOT_*D_*4);
  _Float16* hbA   = (_Float16*)take((size_t)NTOT_*D_*2);
  _Float16* hbB   = (_Float16*)take((size_t)NTOT_*D_*2);
  _Float16* eb    = (_Float16*)take((size_t)ETOT_*D_*2);
  _Float16* FT    = (_Float16*)take((size_t)NTOT_*1024*2);
  _Float16* Ebuf  = (_Float16*)take((size_t)ETOT_*512*2);
  _Float16* Hsum  = (_Float16*)take((size_t)NTOT_*512*2);
  float* tq_emb   = (float*)take((size_t)B_*NMAX_*TD_*4);
  float* tc_emb   = (float*)take((size_t)B_*NMAX_*TD_*4);
  float* plan_n   = (float*)take((size_t)B_*NMAX_*NMAX_*4);
  float* teq      = (float*)take((size_t)B_*EMAX_*TD_*4);
  float* tec      = (float*)take((size_t)B_*EMAX_*TD_*4);
  _Float16* W1Tn  = (_Float16*)take((size_t)1024*128*2);
  _Float16* W1Te  = (_Float16*)take((size_t)512*128*2);
  _Float16* WuT   = (_Float16*)take((size_t)128*640*2);
  float* bcat1    = (float*)take(512*4);
  float* c1       = (float*)take(128*4);
  float* c2       = (float*)take(128*4);
  _Float16* WceTh = (_Float16*)take((size_t)16*512*2);
  float* bce      = (float*)take(16*4);

  k_build_idx<<<(ETOT_ + 255)/256, 256, 0, stream>>>(fq, tq, fc, tc, from_idx, to_idx);
  k_build_lists<<<B_, 256, 0, stream>>>(fq, tq, fc, tc, in_cnt, in_list, out_cnt, out_list);
  k_prep_w<<<(1024*128 + 512*128)/256, 256, 0, stream>>>(
      Wm1, Wr1, bm1, br1, W1Tn, W1Te, bcat1);
  k_prep_wu<<<(128*640 + 255)/256, 256, 0, stream>>>(Wm2, Wr2, Wu, bm2, br2, WuT, c1, c2);
  k_prep_wce<<<32, 256, 0, stream>>>(Wm2, Wr2, We1, bm2, br2, be1, WceTh, bce);
  k_node_enc<<<NTOT_, D_, 0, stream>>>(node_features, Wn, bn, h0, hbA);
  k_edge_enc<<<ETOT_, D_, 0, stream>>>(edge_features, We, be, eb);

  dim3 gE(ETOT_/128, 4);
  k_gemm_E<<<gE, 256, 0, stream>>>(eb, W1Te, bcat1, Ebuf);

  dim3 gFT(NTOT_/128, 8);
  float* hc = h0;  float* hn = h1;
  _Float16* hbc = hbA;  _Float16* hbn = hbB;
  for (int p = 0; p < NPROP_; ++p) {
    k_gemm_FT<<<gFT, 256, 0, stream>>>(hbc, W1Tn, FT);
    k_agg_fused<<<NTOT_, 64, 0, stream>>>(FT, Ebuf, from_idx, to_idx,
                                          in_cnt, in_list, out_cnt, out_list, Hsum);
    k_gemm_upd<<<NTOT_/128, 256, 0, stream>>>(hbc, Hsum, WuT, in_cnt, out_cnt,
                                              c1, c2, bu, hn, hbn);
    float* tf = hc; hc = hn; hn = tf;
    _Float16* th = hbc; hbc = hbn; hbn = th;
  }

  k_node_emb<<<B_*2*NMAX_, D_, 0, stream>>>(hc, Wq1, bq1, Wq2, bq2, tq_emb, tc_emb);
  k_sinkhorn_n<<<B_, 256, 0, stream>>>(tq_emb, tc_emb, plan_n);

  k_gemm_FT<<<gFT, 256, 0, stream>>>(hbc, W1Tn, FT);
  hipMemsetAsync(teq, 0, (size_t)B_*EMAX_*TD_*4, stream);
  hipMemsetAsync(tec, 0, (size_t)B_*EMAX_*TD_*4, stream);
  k_edge_emb_f<<<ETOT_/64, 256, 0, stream>>>(FT, Ebuf, from_idx, to_idx,
                                             WceTh, bce, We2, be2, teq, tec);

  k_plan_score<<<B_, 1024, 0, stream>>>(teq, tec, plan_n, tq_emb, tc_emb,
                                        fq, tq, fc, tc, Wa, ba, (float*)d_out);
}